// Round 4
// baseline (9240.276 us; speedup 1.0000x reference)
//
#include <hip/hip_runtime.h>

// Model_81956565942963: TCN + low-rank dynamic graph + linear head.
// B=16, L=512, N=64, D=128, S=32 x 16, r=8, P=96.
// R4: runtime input-dtype detection (bf16 vs f32) — R2/R3 NaNs are consistent
// with f32 inputs misread as bf16. All input loads/output stores go through
// gload/gstore keyed on a device-side flag. e1/e2 size bug fixed (1MB each).

#define BATCH 16
#define SEQ 512
#define NVAR 64
#define DM 128
#define SEG 32
#define SCL 16
#define RNK 8
#define PRED 96
#define BN (BATCH * NVAR)   // 1024
#define LD (SEQ * DM)       // 65536

typedef unsigned short ushort_t;

__device__ inline float bf2f(ushort_t u) {
    union { unsigned int i; float f; } x;
    x.i = ((unsigned int)u) << 16;
    return x.f;
}
__device__ inline ushort_t f2bf(float f) {
    union { float f; unsigned int i; } u;
    u.f = f;
    unsigned int x = u.i;
    return (ushort_t)((x + 0x7fffu + ((x >> 16) & 1u)) >> 16);  // RNE
}
__device__ inline float gload(const void* p, size_t i, int f32m) {
    return f32m ? ((const float*)p)[i] : bf2f(((const ushort_t*)p)[i]);
}
__device__ inline void gstore(void* p, size_t i, float v, int f32m) {
    if (f32m) ((float*)p)[i] = v;
    else ((ushort_t*)p)[i] = f2bf(v);
}
__device__ inline float gelu_tanh(float x) {
    float x3 = x * x * x;
    float t = 0.7978845608028654f * (x + 0.044715f * x3);
    return 0.5f * x * (1.0f + tanhf(t));
}

// ---------------- dtype detector -------------------------------------------
// bf16 N(0,1)-ish data: exponent field in ~[100,131]. f32 data read as
// ushorts: even indices are low mantissa halves -> uniform bits -> ~50%
// of bf16-view exponents land outside [64,192]. Count over 4096 samples.
__global__ void detect_kernel(const ushort_t* __restrict__ xs,
                              int* __restrict__ flag) {
    __shared__ int cnt;
    if (threadIdx.x == 0) cnt = 0;
    __syncthreads();
    int local = 0;
    for (int t = threadIdx.x; t < 4096; t += 256) {
        ushort_t u = xs[2 * t];  // even index
        if (u & 0x7FFFu) {
            int e = (u >> 7) & 0xFF;
            if (e < 64 || e > 192) local++;
        }
    }
    atomicAdd(&cnt, local);
    __syncthreads();
    if (threadIdx.x == 0) flag[0] = (cnt >= 16) ? 1 : 0;
}

// ---------------- head_w transpose -> f32: head_wT[p][ci] -------------------
__global__ __launch_bounds__(256) void transpose_head(
    const void* __restrict__ head_w, float* __restrict__ head_wT,
    const int* __restrict__ flag) {
    const int m = flag[0];
    int ci0 = blockIdx.x * 256;
    int p = threadIdx.x;
    if (p < PRED) {
        for (int i = 0; i < 256; ++i) {
            int ci = ci0 + i;
            head_wT[(size_t)p * LD + ci] = gload(head_w, (size_t)ci * PRED + p, m);
        }
    }
}

// ---------------- fused: embed + conv1 + conv2 + z/e + G --------------------
__global__ __launch_bounds__(256) void tcn_fused(
    const void* __restrict__ x, const void* __restrict__ w_emb,
    const void* __restrict__ b_emb, const void* __restrict__ conv_w,
    const void* __restrict__ conv_b,
    const void* __restrict__ gw1, const void* __restrict__ gb1,
    const void* __restrict__ gw2, const void* __restrict__ gb2,
    const float* __restrict__ head_wT,
    float* __restrict__ e1, float* __restrict__ e2, float* __restrict__ G,
    const int* __restrict__ flag) {
    __shared__ ushort_t h0[74 * DM];  // embedded, row = li+6; rows 70..73 zero
    __shared__ float    h1[68 * DM];  // conv1 out, row = li+4; reused as h2
    __shared__ float    zb[4 * DM];   // segment means
    const int fm = flag[0];

    int bn = blockIdx.x;
    int b = bn >> 6, n = bn & 63;
    int chunk = blockIdx.y;
    int l0 = chunk * 64;

    // ---- embed ----
    for (int idx = threadIdx.x; idx < 70 * DM; idx += 256) {
        int r = idx >> 7, d = idx & 127;
        int l = l0 + r - 6;
        float v = 0.0f;
        if (l >= 0)
            v = gload(x, ((size_t)(b * SEQ + l)) * NVAR + n, fm) *
                    gload(w_emb, d, fm) + gload(b_emb, d, fm);
        h0[idx] = f2bf(v);
    }
    for (int idx = 70 * DM + threadIdx.x; idx < 74 * DM; idx += 256) h0[idx] = 0;
    __syncthreads();

    int tc = threadIdx.x & 31;   // channel group: co = tc*4
    int lg = threadIdx.x >> 5;   // position group
    int co = tc * 4;

    // ---- conv1 (dil=1): h1[li], li in [-4,64), row = li+4 ----
    {
        int li0 = lg * 9 - 4;
        float b0 = gload(conv_b, co + 0, fm), b1 = gload(conv_b, co + 1, fm);
        float b2 = gload(conv_b, co + 2, fm), b3 = gload(conv_b, co + 3, fm);
        float acc[9][4];
#pragma unroll
        for (int j = 0; j < 9; ++j) {
            acc[j][0] = b0; acc[j][1] = b1; acc[j][2] = b2; acc[j][3] = b3;
        }
        for (int ci = 0; ci < DM; ++ci) {
            float hv[11];  // h0 rows li0+4 .. li0+14
#pragma unroll
            for (int t = 0; t < 11; ++t)
                hv[t] = bf2f(h0[(li0 + 4 + t) * DM + ci]);
#pragma unroll
            for (int k = 0; k < 3; ++k) {
                size_t wb = ((size_t)k * DM + ci) * DM + co;
                float w0 = gload(conv_w, wb + 0, fm);
                float w1 = gload(conv_w, wb + 1, fm);
                float w2 = gload(conv_w, wb + 2, fm);
                float w3 = gload(conv_w, wb + 3, fm);
#pragma unroll
                for (int j = 0; j < 9; ++j) {
                    float h = hv[j + k];  // tap h[li-(2-k)]
                    acc[j][0] += h * w0; acc[j][1] += h * w1;
                    acc[j][2] += h * w2; acc[j][3] += h * w3;
                }
            }
        }
#pragma unroll
        for (int j = 0; j < 9; ++j) {
            int li = li0 + j;
            if (li < 64) {
                float4 o;
                if (l0 + li < 0) {
                    o.x = 0.f; o.y = 0.f; o.z = 0.f; o.w = 0.f;  // causal pad
                } else {
                    const ushort_t* res = &h0[(li + 6) * DM + co];
                    o.x = gelu_tanh(acc[j][0]) + bf2f(res[0]);
                    o.y = gelu_tanh(acc[j][1]) + bf2f(res[1]);
                    o.z = gelu_tanh(acc[j][2]) + bf2f(res[2]);
                    o.w = gelu_tanh(acc[j][3]) + bf2f(res[3]);
                }
                *reinterpret_cast<float4*>(&h1[(li + 4) * DM + co]) = o;
            }
        }
    }
    __syncthreads();

    // ---- conv2 (dil=2): out2[li], li in [0,64) ----
    float out2[8][4];
    {
        int li0 = lg * 8;
        float b0 = gload(conv_b, DM + co + 0, fm), b1 = gload(conv_b, DM + co + 1, fm);
        float b2 = gload(conv_b, DM + co + 2, fm), b3 = gload(conv_b, DM + co + 3, fm);
        float acc[8][4];
#pragma unroll
        for (int j = 0; j < 8; ++j) {
            acc[j][0] = b0; acc[j][1] = b1; acc[j][2] = b2; acc[j][3] = b3;
        }
        for (int ci = 0; ci < DM; ++ci) {
            float hv[12];  // h1 rows li0 .. li0+11
#pragma unroll
            for (int t = 0; t < 12; ++t)
                hv[t] = h1[(li0 + t) * DM + ci];
#pragma unroll
            for (int k = 0; k < 3; ++k) {
                size_t wb = (size_t)3 * DM * DM + ((size_t)k * DM + ci) * DM + co;
                float w0 = gload(conv_w, wb + 0, fm);
                float w1 = gload(conv_w, wb + 1, fm);
                float w2 = gload(conv_w, wb + 2, fm);
                float w3 = gload(conv_w, wb + 3, fm);
#pragma unroll
                for (int j = 0; j < 8; ++j) {
                    float h = hv[j + 2 * k];  // tap h1[li-4+2k]
                    acc[j][0] += h * w0; acc[j][1] += h * w1;
                    acc[j][2] += h * w2; acc[j][3] += h * w3;
                }
            }
        }
#pragma unroll
        for (int j = 0; j < 8; ++j) {
            int li = li0 + j;
            const float* res = &h1[(li + 4) * DM + co];
            out2[j][0] = gelu_tanh(acc[j][0]) + res[0];
            out2[j][1] = gelu_tanh(acc[j][1]) + res[1];
            out2[j][2] = gelu_tanh(acc[j][2]) + res[2];
            out2[j][3] = gelu_tanh(acc[j][3]) + res[3];
        }
    }
    __syncthreads();  // all h1 reads done

    // ---- write h2 (f32) over h1 ----
    {
        int li0 = lg * 8;
#pragma unroll
        for (int j = 0; j < 8; ++j) {
            float4 o;
            o.x = out2[j][0]; o.y = out2[j][1]; o.z = out2[j][2]; o.w = out2[j][3];
            *reinterpret_cast<float4*>(&h1[(li0 + j) * DM + co]) = o;
        }
    }
    __syncthreads();

    // ---- z: segment means ----
    {
        int d = threadIdx.x & 127, sg = threadIdx.x >> 7;
#pragma unroll
        for (int t = 0; t < 2; ++t) {
            int sl = sg + 2 * t;
            float a = 0.0f;
#pragma unroll
            for (int c = 0; c < SCL; ++c) a += h1[(sl * SCL + c) * DM + d];
            zb[sl * DM + d] = a * (1.0f / 16.0f);
        }
    }
    __syncthreads();

    // ---- e1/e2 ----
    if (threadIdx.x < 64) {
        int sl = threadIdx.x >> 4;
        int which = (threadIdx.x >> 3) & 1;
        int r = threadIdx.x & 7;
        const void* w = which ? gw2 : gw1;
        const void* bb = which ? gb2 : gb1;
        float a = 0.0f;
        for (int d = 0; d < DM; ++d)
            a += zb[sl * DM + d] * gload(w, (size_t)d * RNK + r, fm);
        a += gload(bb, r, fm);
        int s = chunk * 4 + sl;
        float* dst = which ? e2 : e1;
        dst[(((size_t)b * SEG + s) * NVAR + n) * RNK + r] = a;
    }

    // ---- G[bn][s][p] = sum_ci h2[seg][ci] * head_wT[p][s*2048+ci] ----
    {
        int p = threadIdx.x & 127;
        int half = threadIdx.x >> 7;
        if (p < PRED) {
#pragma unroll
            for (int t = 0; t < 2; ++t) {
                int sl = half + 2 * t;
                int s = chunk * 4 + sl;
                const float* wrow = head_wT + (size_t)p * LD + (size_t)s * 2048;
                const float* hseg = &h1[sl * 2048];
                float a = 0.0f;
#pragma unroll 8
                for (int ci = 0; ci < 2048; ++ci) a += hseg[ci] * wrow[ci];
                G[(size_t)bn * (SEG * PRED) + (size_t)s * PRED + p] = a;
            }
        }
    }
}

// ---------------- scores + softmax -> adj[b][s][n][m] -----------------------
__global__ __launch_bounds__(64) void softmax_kernel(
    const float* __restrict__ e1, const float* __restrict__ e2,
    float* __restrict__ adj) {
    int n = blockIdx.x & 63;
    int bs = blockIdx.x >> 6;  // b*SEG+s
    int m = threadIdx.x;
    const float* e1p = e1 + ((size_t)bs * NVAR + n) * RNK;
    const float* e2p = e2 + ((size_t)bs * NVAR + m) * RNK;
    float sc = 0.0f;
#pragma unroll
    for (int r = 0; r < RNK; ++r) sc += e1p[r] * e2p[r];
    sc *= 0.35355339059327373f;  // 1/sqrt(8)
    float mx = sc;
    for (int off = 32; off; off >>= 1) mx = fmaxf(mx, __shfl_xor(mx, off, 64));
    float ex = expf(sc - mx);
    float sm = ex;
    for (int off = 32; off; off >>= 1) sm += __shfl_xor(sm, off, 64);
    adj[((size_t)bs * NVAR + n) * NVAR + m] = ex / sm;
}

// ---------------- regularizer ----------------------------------------------
__global__ void zero_kernel(float* p) {
    if (threadIdx.x == 0 && blockIdx.x == 0) p[0] = 0.0f;
}

__global__ __launch_bounds__(256) void reg_kernel(
    const float* __restrict__ adj, float* __restrict__ regacc) {
    const int total = BATCH * (SEG - 1) * NVAR * NVAR;
    float sum = 0.0f;
    for (int idx = blockIdx.x * 256 + threadIdx.x; idx < total;
         idx += gridDim.x * 256) {
        int m = idx & 63;
        int n = (idx >> 6) & 63;
        int rest = idx >> 12;
        int sm1 = rest % 31;
        int b = rest / 31;
        int s = sm1 + 1;
        size_t i1 = (((size_t)b * SEG + s) * NVAR + n) * NVAR + m;
        sum += fabsf(adj[i1] - adj[i1 - NVAR * NVAR]);
    }
    for (int off = 32; off; off >>= 1) sum += __shfl_xor(sum, off, 64);
    __shared__ float wsum[4];
    int lane = threadIdx.x & 63, w = threadIdx.x >> 6;
    if (lane == 0) wsum[w] = sum;
    __syncthreads();
    if (threadIdx.x == 0)
        atomicAdd(regacc, wsum[0] + wsum[1] + wsum[2] + wsum[3]);
}

__global__ void finalize_reg(const float* __restrict__ regacc,
                             void* __restrict__ out, int out_size,
                             const int* __restrict__ flag) {
    if (threadIdx.x == 0 && blockIdx.x == 0)
        gstore(out, out_size - 1, regacc[0] * (1.0f / 65536.0f), flag[0]);
}

// ---------------- out[b][p][n] = head_b[p] + sum_{s,m} adj*G ----------------
__global__ __launch_bounds__(128) void out_kernel(
    const float* __restrict__ adj, const float* __restrict__ G,
    const void* __restrict__ head_b, void* __restrict__ out,
    const int* __restrict__ flag) {
    __shared__ float adjn[SEG * NVAR];
    __shared__ int badA;
    const int fm = flag[0];
    int b = blockIdx.x >> 6, n = blockIdx.x & 63;
    if (threadIdx.x == 0) badA = 0;
    __syncthreads();
    int abadl = 0;
    for (int idx = threadIdx.x; idx < SEG * NVAR; idx += 128) {
        int s = idx >> 6, mm = idx & 63;
        float v = adj[(((size_t)b * SEG + s) * NVAR + n) * NVAR + mm];
        if (!isfinite(v)) abadl = 1;
        adjn[idx] = v;
    }
    if (abadl) atomicOr(&badA, 1);
    __syncthreads();
    int p = threadIdx.x;
    if (p < PRED) {
        float acc = gload(head_b, p, fm);
        int gbad = 0;
        const float* Gb = G + (size_t)b * NVAR * SEG * PRED + p;
        for (int s = 0; s < SEG; ++s) {
#pragma unroll 8
            for (int mm = 0; mm < NVAR; ++mm) {
                float g = Gb[(size_t)mm * (SEG * PRED) + s * PRED];
                if (!isfinite(g)) gbad = 1;
                acc += adjn[s * NVAR + mm] * g;
            }
        }
        float res;
        if (badA) res = 30000.0f;          // e/softmax stage non-finite
        else if (gbad) res = 20000.0f;     // conv/h2/head stage non-finite
        else if (!isfinite(acc)) res = 10000.0f;
        else res = acc;
        gstore(out, ((size_t)b * PRED + p) * NVAR + n, res, fm);
    }
}

extern "C" void kernel_launch(void* const* d_in, const int* in_sizes, int n_in,
                              void* d_out, int out_size, void* d_ws,
                              size_t ws_size, hipStream_t stream) {
    const void* x_enc  = d_in[0];
    const void* w_emb  = d_in[4];
    const void* b_emb  = d_in[5];
    const void* conv_w = d_in[6];
    const void* conv_b = d_in[7];
    const void* gg_w1  = d_in[8];
    const void* gg_b1  = d_in[9];
    const void* gg_w2  = d_in[10];
    const void* gg_b2  = d_in[11];
    const void* head_w = d_in[12];
    const void* head_b = d_in[13];

    // workspace layout, total 48,234,504 B (~46 MB; 157MB known to fit)
    char* ws = (char*)d_ws;
    float* head_wT = (float*)(ws);                      // 25,165,824 B
    float* G       = (float*)(ws + 25165824);           // 12,582,912 B
    float* e1      = (float*)(ws + 37748736);           //  1,048,576 B
    float* e2      = (float*)(ws + 38797312);           //  1,048,576 B
    float* adj     = (float*)(ws + 39845888);           //  8,388,608 B
    float* regacc  = (float*)(ws + 48234496);           //          4 B
    int*   flag    = (int*)  (ws + 48234500);           //          4 B

    detect_kernel<<<1, 256, 0, stream>>>((const ushort_t*)x_enc, flag);
    transpose_head<<<LD / 256, 256, 0, stream>>>(head_w, head_wT, flag);
    tcn_fused<<<dim3(BN, SEQ / 64), 256, 0, stream>>>(
        x_enc, w_emb, b_emb, conv_w, conv_b,
        gg_w1, gg_b1, gg_w2, gg_b2, head_wT, e1, e2, G, flag);
    softmax_kernel<<<BATCH * SEG * NVAR, 64, 0, stream>>>(e1, e2, adj);
    zero_kernel<<<1, 64, 0, stream>>>(regacc);
    reg_kernel<<<512, 256, 0, stream>>>(adj, regacc);
    finalize_reg<<<1, 64, 0, stream>>>(regacc, d_out, out_size, flag);
    out_kernel<<<BATCH * NVAR, 128, 0, stream>>>(adj, G, head_b, d_out, flag);
}

// Round 5
// 2036.266 us; speedup vs baseline: 4.5379x; 4.5379x over previous
//
#include <hip/hip_runtime.h>

// Model_81956565942963: TCN + low-rank dynamic graph + linear head.
// B=16, L=512, N=64, D=128, S=32 x 16, r=8, P=96. f32 in/out (confirmed R4).
// R5: restructured for memory-pattern sanity:
//   tcn_conv (dense f32 FMA, coalesced float4 weights, f32 LDS broadcast)
//   -> h2 bf16 global (134 MB; 157 MB layout proven to fit)
//   g_gemm: tiled GEMM per (s, bn-tile), conflict-free LDS mappings
//   out_final: batched small GEMM with G in [s][b][p][m] layout.

#define BATCH 16
#define SEQ 512
#define NVAR 64
#define DM 128
#define SEG 32
#define SCL 16
#define RNK 8
#define PRED 96
#define BN (BATCH * NVAR)   // 1024
#define ROWLEN (SEQ * DM)   // 65536

typedef unsigned short ushort_t;

__device__ inline float bf2f(ushort_t u) {
    union { unsigned int i; float f; } x;
    x.i = ((unsigned int)u) << 16;
    return x.f;
}
__device__ inline ushort_t f2bf(float f) {
    union { float f; unsigned int i; } u;
    u.f = f;
    unsigned int x = u.i;
    return (ushort_t)((x + 0x7fffu + ((x >> 16) & 1u)) >> 16);  // RNE
}
__device__ inline float gelu_tanh(float x) {
    float x3 = x * x * x;
    float t = 0.7978845608028654f * (x + 0.044715f * x3);
    return 0.5f * x * (1.0f + tanhf(t));
}

// ---------------- phase 1: embed + conv1(dil=1) + conv2(dil=2) -> h2 bf16 ---
__global__ __launch_bounds__(256) void tcn_conv(
    const float* __restrict__ x, const float* __restrict__ w_emb,
    const float* __restrict__ b_emb, const float* __restrict__ conv_w,
    const float* __restrict__ conv_b, ushort_t* __restrict__ h2) {
    __shared__ float h0[74 * DM];  // embedded, row = li+6; rows 70..73 zero
    __shared__ float h1[68 * DM];  // conv1 out, row = li+4

    int bn = blockIdx.x;
    int b = bn >> 6, n = bn & 63;
    int l0 = blockIdx.y * 64;

    // ---- embed (x load is wave-broadcast; w/b coalesced, L1-hot) ----
    const float* xb = x + (size_t)b * SEQ * NVAR + n;
    for (int idx = threadIdx.x; idx < 70 * DM; idx += 256) {
        int r = idx >> 7, d = idx & 127;
        int l = l0 + r - 6;
        float v = 0.0f;
        if (l >= 0) v = xb[(size_t)l * NVAR] * w_emb[d] + b_emb[d];
        h0[idx] = v;
    }
    for (int idx = 70 * DM + threadIdx.x; idx < 74 * DM; idx += 256)
        h0[idx] = 0.0f;
    __syncthreads();

    int tc = threadIdx.x & 31;   // channel group: co = tc*4
    int lg = threadIdx.x >> 5;   // position group
    int co = tc * 4;

    // ---- conv1: h1[li], li in [-4,64), row = li+4 ----
    {
        int li0 = lg * 9 - 4;
        float4 bias = *reinterpret_cast<const float4*>(&conv_b[co]);
        float acc[9][4];
#pragma unroll
        for (int j = 0; j < 9; ++j) {
            acc[j][0] = bias.x; acc[j][1] = bias.y;
            acc[j][2] = bias.z; acc[j][3] = bias.w;
        }
        for (int ci = 0; ci < DM; ++ci) {
            float hv[11];  // h0 rows lg*9 .. lg*9+10  (li0+4 = lg*9)
#pragma unroll
            for (int t = 0; t < 11; ++t)
                hv[t] = h0[(lg * 9 + t) * DM + ci];
#pragma unroll
            for (int k = 0; k < 3; ++k) {
                float4 w = *reinterpret_cast<const float4*>(
                    &conv_w[((size_t)k * DM + ci) * DM + co]);
#pragma unroll
                for (int j = 0; j < 9; ++j) {
                    float h = hv[j + k];  // tap h[li-(2-k)]
                    acc[j][0] += h * w.x; acc[j][1] += h * w.y;
                    acc[j][2] += h * w.z; acc[j][3] += h * w.w;
                }
            }
        }
#pragma unroll
        for (int j = 0; j < 9; ++j) {
            int li = li0 + j;
            if (li < 64) {
                float4 o;
                if (l0 + li < 0) {
                    o.x = 0.f; o.y = 0.f; o.z = 0.f; o.w = 0.f;  // causal pad
                } else {
                    const float* res = &h0[(li + 6) * DM + co];
                    o.x = gelu_tanh(acc[j][0]) + res[0];
                    o.y = gelu_tanh(acc[j][1]) + res[1];
                    o.z = gelu_tanh(acc[j][2]) + res[2];
                    o.w = gelu_tanh(acc[j][3]) + res[3];
                }
                *reinterpret_cast<float4*>(&h1[(li + 4) * DM + co]) = o;
            }
        }
    }
    __syncthreads();

    // ---- conv2 (dil=2): li in [0,64) -> gelu + residual -> h2 global bf16 ----
    {
        int li0 = lg * 8;
        float4 bias = *reinterpret_cast<const float4*>(&conv_b[DM + co]);
        float acc[8][4];
#pragma unroll
        for (int j = 0; j < 8; ++j) {
            acc[j][0] = bias.x; acc[j][1] = bias.y;
            acc[j][2] = bias.z; acc[j][3] = bias.w;
        }
        const float* W1 = conv_w + 3 * DM * DM;
        for (int ci = 0; ci < DM; ++ci) {
            float hv[12];  // h1 rows li0 .. li0+11
#pragma unroll
            for (int t = 0; t < 12; ++t)
                hv[t] = h1[(li0 + t) * DM + ci];
#pragma unroll
            for (int k = 0; k < 3; ++k) {
                float4 w = *reinterpret_cast<const float4*>(
                    &W1[((size_t)k * DM + ci) * DM + co]);
#pragma unroll
                for (int j = 0; j < 8; ++j) {
                    float h = hv[j + 2 * k];  // tap h1[li-4+2k]
                    acc[j][0] += h * w.x; acc[j][1] += h * w.y;
                    acc[j][2] += h * w.z; acc[j][3] += h * w.w;
                }
            }
        }
        ushort_t* orow = h2 + (size_t)bn * ROWLEN;
#pragma unroll
        for (int j = 0; j < 8; ++j) {
            int li = li0 + j;
            const float* res = &h1[(li + 4) * DM + co];
            ushort4 pk;
            pk.x = f2bf(gelu_tanh(acc[j][0]) + res[0]);
            pk.y = f2bf(gelu_tanh(acc[j][1]) + res[1]);
            pk.z = f2bf(gelu_tanh(acc[j][2]) + res[2]);
            pk.w = f2bf(gelu_tanh(acc[j][3]) + res[3]);
            *reinterpret_cast<ushort4*>(
                &orow[(size_t)(l0 + li) * DM + co]) = pk;
        }
    }
}

// ---------------- segment mean -> e1/e2 -------------------------------------
__global__ __launch_bounds__(128) void seg_e(
    const ushort_t* __restrict__ h2,
    const float* __restrict__ gw1, const float* __restrict__ gb1,
    const float* __restrict__ gw2, const float* __restrict__ gb2,
    float* __restrict__ e1, float* __restrict__ e2) {
    __shared__ float z[DM];
    int s = blockIdx.x & 31;
    int bn = blockIdx.x >> 5;
    int b = bn >> 6, n = bn & 63;
    int d = threadIdx.x;
    const ushort_t* hp = h2 + (size_t)bn * ROWLEN + (size_t)s * (SCL * DM) + d;
    float a = 0.0f;
#pragma unroll
    for (int c = 0; c < SCL; ++c) a += bf2f(hp[c * DM]);
    z[d] = a * (1.0f / 16.0f);
    __syncthreads();
    if (threadIdx.x < 16) {
        int r = threadIdx.x & 7;
        bool first = threadIdx.x < 8;
        const float* w = first ? gw1 : gw2;
        float acc = 0.0f;
        for (int dd = 0; dd < DM; ++dd) acc += z[dd] * w[dd * RNK + r];
        acc += (first ? gb1 : gb2)[r];
        (first ? e1 : e2)[(((size_t)b * SEG + s) * NVAR + n) * RNK + r] = acc;
    }
}

// ---------------- scores + softmax -> adj[b][s][n][m] -----------------------
__global__ __launch_bounds__(64) void softmax_kernel(
    const float* __restrict__ e1, const float* __restrict__ e2,
    float* __restrict__ adj) {
    int n = blockIdx.x & 63;
    int bs = blockIdx.x >> 6;  // b*SEG+s
    int m = threadIdx.x;
    const float* e1p = e1 + ((size_t)bs * NVAR + n) * RNK;
    const float* e2p = e2 + ((size_t)bs * NVAR + m) * RNK;
    float sc = 0.0f;
#pragma unroll
    for (int r = 0; r < RNK; ++r) sc += e1p[r] * e2p[r];
    sc *= 0.35355339059327373f;  // 1/sqrt(8)
    float mx = sc;
    for (int off = 32; off; off >>= 1) mx = fmaxf(mx, __shfl_xor(mx, off, 64));
    float ex = expf(sc - mx);
    float sm = ex;
    for (int off = 32; off; off >>= 1) sm += __shfl_xor(sm, off, 64);
    adj[((size_t)bs * NVAR + n) * NVAR + m] = ex / sm;
}

// ---------------- regularizer ----------------------------------------------
__global__ void zero_kernel(float* p) {
    if (threadIdx.x == 0 && blockIdx.x == 0) p[0] = 0.0f;
}

__global__ __launch_bounds__(256) void reg_kernel(
    const float* __restrict__ adj, float* __restrict__ regacc) {
    const int total = BATCH * (SEG - 1) * NVAR * NVAR;  // 2,031,616
    float sum = 0.0f;
    for (int idx = blockIdx.x * 256 + threadIdx.x; idx < total;
         idx += gridDim.x * 256) {
        int m = idx & 63;
        int n = (idx >> 6) & 63;
        int rest = idx >> 12;
        int sm1 = rest % 31;
        int b = rest / 31;
        int s = sm1 + 1;
        size_t i1 = (((size_t)b * SEG + s) * NVAR + n) * NVAR + m;
        sum += fabsf(adj[i1] - adj[i1 - NVAR * NVAR]);
    }
    for (int off = 32; off; off >>= 1) sum += __shfl_xor(sum, off, 64);
    __shared__ float wsum[4];
    int lane = threadIdx.x & 63, w = threadIdx.x >> 6;
    if (lane == 0) wsum[w] = sum;
    __syncthreads();
    if (threadIdx.x == 0)
        atomicAdd(regacc, wsum[0] + wsum[1] + wsum[2] + wsum[3]);
}

__global__ void finalize_reg(const float* __restrict__ regacc,
                             float* __restrict__ out, int out_size) {
    if (threadIdx.x == 0 && blockIdx.x == 0)
        out[out_size - 1] = regacc[0] * (1.0f / 65536.0f);
}

// ---------------- G GEMM: per (s, bn-tile of 128): [128 x 2048]x[2048 x 96] -
// A = h2[bn][s*2048 + k] (bf16), B = head_w[(s*2048+k)*96 + p] (f32).
// G layout: [s][b][p][m]  (m = bn & 63)
__global__ __launch_bounds__(256) void g_gemm(
    const ushort_t* __restrict__ h2, const float* __restrict__ head_w,
    float* __restrict__ G) {
    __shared__ float As[128][65];  // [bn][k], pad 65 -> conflict-free reads
    __shared__ float Bs[64][96];   // [k][p]
    int s = blockIdx.x;
    int bn0 = blockIdx.y * 128;
    int tx = threadIdx.x & 15;   // p-group: p = tx*6..+5
    int ty = threadIdx.x >> 4;   // bn-group: bn = bn0 + ty*8..+7

    float acc[8][6];
#pragma unroll
    for (int i = 0; i < 8; ++i)
#pragma unroll
        for (int j = 0; j < 6; ++j) acc[i][j] = 0.0f;

    for (int kt = 0; kt < 2048; kt += 64) {
        // stage A: 128 rows x 64 k (bf16 -> f32); 8 ushort4 per thread
#pragma unroll
        for (int i = 0; i < 8; ++i) {
            int q = threadIdx.x + 256 * i;          // 0..2047
            int row = q >> 4, kq = (q & 15) * 4;
            ushort4 v = *reinterpret_cast<const ushort4*>(
                &h2[(size_t)(bn0 + row) * ROWLEN + (size_t)s * 2048 + kt + kq]);
            As[row][kq + 0] = bf2f(v.x);
            As[row][kq + 1] = bf2f(v.y);
            As[row][kq + 2] = bf2f(v.z);
            As[row][kq + 3] = bf2f(v.w);
        }
        // stage B: 64 rows x 96 p; 6 float4 per thread
#pragma unroll
        for (int i = 0; i < 6; ++i) {
            int q = threadIdx.x + 256 * i;          // 0..1535
            int row = q / 24, pq = (q % 24) * 4;
            float4 v = *reinterpret_cast<const float4*>(
                &head_w[((size_t)s * 2048 + kt + row) * PRED + pq]);
            *reinterpret_cast<float4*>(&Bs[row][pq]) = v;
        }
        __syncthreads();
#pragma unroll 4
        for (int k = 0; k < 64; ++k) {
            float a[8], bb[6];
#pragma unroll
            for (int i = 0; i < 8; ++i) a[i] = As[ty * 8 + i][k];
#pragma unroll
            for (int j = 0; j < 6; ++j) bb[j] = Bs[k][tx * 6 + j];
#pragma unroll
            for (int i = 0; i < 8; ++i)
#pragma unroll
                for (int j = 0; j < 6; ++j) acc[i][j] += a[i] * bb[j];
        }
        __syncthreads();
    }
    // store G[s][b][p][m]
#pragma unroll
    for (int i = 0; i < 8; ++i) {
        int bn = bn0 + ty * 8 + i;
        int b = bn >> 6, m = bn & 63;
#pragma unroll
        for (int j = 0; j < 6; ++j) {
            int p = tx * 6 + j;
            G[(((size_t)s * BATCH + b) * PRED + p) * NVAR + m] = acc[i][j];
        }
    }
}

// ---------------- out[b][p][n] = head_b[p] + sum_{s,m} adj[b,s,n,m]*G[s,b,p,m]
__global__ __launch_bounds__(256) void out_final(
    const float* __restrict__ adj, const float* __restrict__ G,
    const float* __restrict__ head_b, float* __restrict__ out) {
    __shared__ float adjn[32][65];  // [n_local][m]
    __shared__ float Gs[96][65];    // [p][m]
    int b = blockIdx.x, nh = blockIdx.y;
    int tx = threadIdx.x & 15;   // p = tx*6..+5
    int ty = threadIdx.x >> 4;   // n_local = ty*2..+1
    int p0 = tx * 6;

    float acc[2][6];
#pragma unroll
    for (int j = 0; j < 6; ++j) {
        float hb = head_b[p0 + j];
        acc[0][j] = hb; acc[1][j] = hb;
    }

    for (int s = 0; s < SEG; ++s) {
        // stage adj slice: 32 x 64 (2 float4 per thread)
#pragma unroll
        for (int i = 0; i < 2; ++i) {
            int q = threadIdx.x + 256 * i;  // 0..511
            int row = q >> 4, mq = (q & 15) * 4;
            float4 v = *reinterpret_cast<const float4*>(
                &adj[(((size_t)b * SEG + s) * NVAR + nh * 32 + row) * NVAR + mq]);
            adjn[row][mq + 0] = v.x; adjn[row][mq + 1] = v.y;
            adjn[row][mq + 2] = v.z; adjn[row][mq + 3] = v.w;
        }
        // stage G slice: 96 x 64 (6 float4 per thread)
#pragma unroll
        for (int i = 0; i < 6; ++i) {
            int q = threadIdx.x + 256 * i;  // 0..1535
            int row = q >> 4, mq = (q & 15) * 4;
            float4 v = *reinterpret_cast<const float4*>(
                &G[(((size_t)s * BATCH + b) * PRED + row) * NVAR + mq]);
            Gs[row][mq + 0] = v.x; Gs[row][mq + 1] = v.y;
            Gs[row][mq + 2] = v.z; Gs[row][mq + 3] = v.w;
        }
        __syncthreads();
#pragma unroll 4
        for (int m = 0; m < 64; ++m) {
            float a0 = adjn[ty * 2 + 0][m];
            float a1 = adjn[ty * 2 + 1][m];
#pragma unroll
            for (int j = 0; j < 6; ++j) {
                float g = Gs[p0 + j][m];
                acc[0][j] += a0 * g;
                acc[1][j] += a1 * g;
            }
        }
        __syncthreads();
    }
#pragma unroll
    for (int i = 0; i < 2; ++i) {
        int n = nh * 32 + ty * 2 + i;
#pragma unroll
        for (int j = 0; j < 6; ++j)
            out[((size_t)b * PRED + p0 + j) * NVAR + n] = acc[i][j];
    }
}

extern "C" void kernel_launch(void* const* d_in, const int* in_sizes, int n_in,
                              void* d_out, int out_size, void* d_ws,
                              size_t ws_size, hipStream_t stream) {
    const float* x_enc  = (const float*)d_in[0];
    const float* w_emb  = (const float*)d_in[4];
    const float* b_emb  = (const float*)d_in[5];
    const float* conv_w = (const float*)d_in[6];
    const float* conv_b = (const float*)d_in[7];
    const float* gg_w1  = (const float*)d_in[8];
    const float* gg_b1  = (const float*)d_in[9];
    const float* gg_w2  = (const float*)d_in[10];
    const float* gg_b2  = (const float*)d_in[11];
    const float* head_w = (const float*)d_in[12];
    const float* head_b = (const float*)d_in[13];
    float* out = (float*)d_out;

    // workspace: 157,286,404 B total (R2-proven size)
    char* ws = (char*)d_ws;
    ushort_t* h2  = (ushort_t*)(ws);                    // 134,217,728
    float* G      = (float*)(ws + 134217728);           //  12,582,912
    float* e1     = (float*)(ws + 146800640);           //   1,048,576
    float* e2     = (float*)(ws + 147849216);           //   1,048,576
    float* adj    = (float*)(ws + 148897792);           //   8,388,608
    float* regacc = (float*)(ws + 157286400);           //           4

    tcn_conv<<<dim3(BN, SEQ / 64), 256, 0, stream>>>(
        x_enc, w_emb, b_emb, conv_w, conv_b, h2);
    seg_e<<<BN * SEG, 128, 0, stream>>>(h2, gg_w1, gg_b1, gg_w2, gg_b2, e1, e2);
    softmax_kernel<<<BATCH * SEG * NVAR, 64, 0, stream>>>(e1, e2, adj);
    zero_kernel<<<1, 64, 0, stream>>>(regacc);
    reg_kernel<<<512, 256, 0, stream>>>(adj, regacc);
    finalize_reg<<<1, 64, 0, stream>>>(regacc, out, out_size);
    g_gemm<<<dim3(SEG, BN / 128), 256, 0, stream>>>(h2, head_w, G);
    out_final<<<dim3(BATCH, 2), 256, 0, stream>>>(adj, G, head_b, out);
}

// Round 6
// 950.466 us; speedup vs baseline: 9.7218x; 2.1424x over previous
//
#include <hip/hip_runtime.h>

// Model_81956565942963: TCN + low-rank dynamic graph + linear head.
// B=16, L=512, N=64, D=128, S=32 x 16, r=8, P=96. f32 in/out.
// R6: TCN via bf16 MFMA (16x16x32). Weights pre-transposed to bf16
// WT[lt][co][ci] (stored in G's ws slot - used before G is written).
// h1 kept f32 in LDS for the residual path to bound bf16 error growth.

#define BATCH 16
#define SEQ 512
#define NVAR 64
#define DM 128
#define SEG 32
#define SCL 16
#define RNK 8
#define PRED 96
#define BN (BATCH * NVAR)   // 1024
#define ROWLEN (SEQ * DM)   // 65536

typedef unsigned short ushort_t;
typedef __attribute__((ext_vector_type(8))) short short8;   // 8 bf16
typedef __attribute__((ext_vector_type(4))) float f32x4;

__device__ inline float bf2f(ushort_t u) {
    union { unsigned int i; float f; } x;
    x.i = ((unsigned int)u) << 16;
    return x.f;
}
__device__ inline ushort_t f2bf(float f) {
    union { float f; unsigned int i; } u;
    u.f = f;
    unsigned int x = u.i;
    return (ushort_t)((x + 0x7fffu + ((x >> 16) & 1u)) >> 16);  // RNE
}
__device__ inline float gelu_tanh(float x) {
    float x3 = x * x * x;
    float t = 0.7978845608028654f * (x + 0.044715f * x3);
    return 0.5f * x * (1.0f + tanhf(t));
}

// ---------------- weight prep: WT[lt][co][ci] = bf16(conv_w[lt][ci][co]) ----
__global__ __launch_bounds__(128) void wt_prep(
    const float* __restrict__ conv_w, ushort_t* __restrict__ WT) {
    int lt = blockIdx.x;    // 0..5 (layer*3+tap)
    int co = blockIdx.y;    // 0..127
    int ci = threadIdx.x;   // 0..127
    WT[((size_t)lt * 128 + co) * 128 + ci] =
        f2bf(conv_w[(size_t)lt * 16384 + (size_t)ci * 128 + co]);
}

// ---------------- fused TCN via MFMA ---------------------------------------
// Block = (bn, chunk of 64 positions). Layer1: M=80 (li=-16..63, only
// li>=-4 kept), Layer2: M=64. N=128 split as 32 co per wave. K=3 taps x 128.
__global__ __launch_bounds__(256) void tcn_mfma(
    const float* __restrict__ x, const float* __restrict__ w_emb,
    const float* __restrict__ b_emb, const ushort_t* __restrict__ WT,
    const float* __restrict__ conv_b, ushort_t* __restrict__ h2) {
    __shared__ __align__(16) ushort_t h0s[84 * 136];  // bf16, row = li+18
    __shared__ __align__(16) ushort_t h1b[68 * 136];  // bf16, row = li+4
    __shared__ float h1f[68 * 132];                   // f32 residual copy

    int bn = blockIdx.x;
    int b = bn >> 6, n = bn & 63;
    int l0 = blockIdx.y * 64;

    // ---- embed: h0[li][d] bf16, li in [-18,64) ----
    {
        const float* xb = x + (size_t)b * SEQ * NVAR + n;
        int d = threadIdx.x & 127;
        float wd = w_emb[d], bd = b_emb[d];
#pragma unroll 4
        for (int i = 0; i < 41; ++i) {
            int idx = threadIdx.x + 256 * i;  // covers 82*128 exactly
            int row = idx >> 7;
            int l = l0 + row - 18;
            float v = 0.0f;
            if (l >= 0) v = xb[(size_t)l * NVAR] * wd + bd;
            h0s[row * 136 + d] = f2bf(v);
        }
    }
    __syncthreads();

    int lane = threadIdx.x & 63;
    int wv = threadIdx.x >> 6;     // wave 0..3 -> co base 32*wv
    int quad = lane >> 4;
    int col = lane & 15;
    int cobase = wv * 32;

    // ---- layer 1 GEMM: A row r <-> li = r-16; tap k reads h0 row r+k ----
    f32x4 acc1[5][2];
#pragma unroll
    for (int mt = 0; mt < 5; ++mt)
#pragma unroll
        for (int nt = 0; nt < 2; ++nt)
            acc1[mt][nt] = (f32x4){0.f, 0.f, 0.f, 0.f};

    for (int tap = 0; tap < 3; ++tap) {
#pragma unroll
        for (int kt = 0; kt < 4; ++kt) {
            int kc = kt * 32 + quad * 8;
            short8 bf0 = *(const short8*)&WT[((size_t)(tap * 128) + cobase + col) * 128 + kc];
            short8 bf1 = *(const short8*)&WT[((size_t)(tap * 128) + cobase + 16 + col) * 128 + kc];
#pragma unroll
            for (int mt = 0; mt < 5; ++mt) {
                short8 af = *(const short8*)&h0s[(mt * 16 + col + tap) * 136 + kc];
                acc1[mt][0] = __builtin_amdgcn_mfma_f32_16x16x32_bf16(af, bf0, acc1[mt][0], 0, 0, 0);
                acc1[mt][1] = __builtin_amdgcn_mfma_f32_16x16x32_bf16(af, bf1, acc1[mt][1], 0, 0, 0);
            }
        }
    }
    // epilogue 1: h1 = gelu(y+bias) + h0 (0 for causal pad); keep f32 + bf16
    {
        float bias[2] = {conv_b[cobase + col], conv_b[cobase + 16 + col]};
#pragma unroll
        for (int mt = 0; mt < 5; ++mt)
#pragma unroll
            for (int nt = 0; nt < 2; ++nt) {
                int co = cobase + nt * 16 + col;
#pragma unroll
                for (int r = 0; r < 4; ++r) {
                    int li = mt * 16 - 16 + quad * 4 + r;
                    if (li >= -4) {
                        float hv = 0.0f;
                        if (l0 + li >= 0)
                            hv = gelu_tanh(acc1[mt][nt][r] + bias[nt]) +
                                 bf2f(h0s[(li + 18) * 136 + co]);
                        h1f[(li + 4) * 132 + co] = hv;
                        h1b[(li + 4) * 136 + co] = f2bf(hv);
                    }
                }
            }
    }
    __syncthreads();

    // ---- layer 2 GEMM: A row r <-> li = r; tap k reads h1 row r+2k ----
    f32x4 acc2[4][2];
#pragma unroll
    for (int mt = 0; mt < 4; ++mt)
#pragma unroll
        for (int nt = 0; nt < 2; ++nt)
            acc2[mt][nt] = (f32x4){0.f, 0.f, 0.f, 0.f};

    for (int tap = 0; tap < 3; ++tap) {
#pragma unroll
        for (int kt = 0; kt < 4; ++kt) {
            int kc = kt * 32 + quad * 8;
            short8 bf0 = *(const short8*)&WT[((size_t)((3 + tap) * 128) + cobase + col) * 128 + kc];
            short8 bf1 = *(const short8*)&WT[((size_t)((3 + tap) * 128) + cobase + 16 + col) * 128 + kc];
#pragma unroll
            for (int mt = 0; mt < 4; ++mt) {
                short8 af = *(const short8*)&h1b[(mt * 16 + col + 2 * tap) * 136 + kc];
                acc2[mt][0] = __builtin_amdgcn_mfma_f32_16x16x32_bf16(af, bf0, acc2[mt][0], 0, 0, 0);
                acc2[mt][1] = __builtin_amdgcn_mfma_f32_16x16x32_bf16(af, bf1, acc2[mt][1], 0, 0, 0);
            }
        }
    }
    // epilogue 2: h2 = gelu(y+bias) + h1f -> stage bf16 in h0s area
    {
        float bias[2] = {conv_b[DM + cobase + col], conv_b[DM + cobase + 16 + col]};
#pragma unroll
        for (int mt = 0; mt < 4; ++mt)
#pragma unroll
            for (int nt = 0; nt < 2; ++nt) {
                int co = cobase + nt * 16 + col;
#pragma unroll
                for (int r = 0; r < 4; ++r) {
                    int li = mt * 16 + quad * 4 + r;
                    float hv = gelu_tanh(acc2[mt][nt][r] + bias[nt]) +
                               h1f[(li + 4) * 132 + co];
                    h0s[li * 136 + co] = f2bf(hv);
                }
            }
    }
    __syncthreads();

    // ---- coalesced h2 store: 64 rows x 128 bf16 ----
    {
        ushort_t* orow = h2 + (size_t)bn * ROWLEN + (size_t)l0 * 128;
#pragma unroll
        for (int i = 0; i < 4; ++i) {
            int q = threadIdx.x + 256 * i;  // 0..1023
            int row = q >> 4, c8 = (q & 15) * 8;
            *(short8*)&orow[row * 128 + c8] =
                *(const short8*)&h0s[row * 136 + c8];
        }
    }
}

// ---------------- segment mean -> e1/e2 -------------------------------------
__global__ __launch_bounds__(128) void seg_e(
    const ushort_t* __restrict__ h2,
    const float* __restrict__ gw1, const float* __restrict__ gb1,
    const float* __restrict__ gw2, const float* __restrict__ gb2,
    float* __restrict__ e1, float* __restrict__ e2) {
    __shared__ float z[DM];
    int s = blockIdx.x & 31;
    int bn = blockIdx.x >> 5;
    int b = bn >> 6, n = bn & 63;
    int d = threadIdx.x;
    const ushort_t* hp = h2 + (size_t)bn * ROWLEN + (size_t)s * (SCL * DM) + d;
    float a = 0.0f;
#pragma unroll
    for (int c = 0; c < SCL; ++c) a += bf2f(hp[c * DM]);
    z[d] = a * (1.0f / 16.0f);
    __syncthreads();
    if (threadIdx.x < 16) {
        int r = threadIdx.x & 7;
        bool first = threadIdx.x < 8;
        const float* w = first ? gw1 : gw2;
        float acc = 0.0f;
        for (int dd = 0; dd < DM; ++dd) acc += z[dd] * w[dd * RNK + r];
        acc += (first ? gb1 : gb2)[r];
        (first ? e1 : e2)[(((size_t)b * SEG + s) * NVAR + n) * RNK + r] = acc;
    }
}

// ---------------- scores + softmax -> adj[b][s][n][m] -----------------------
__global__ __launch_bounds__(64) void softmax_kernel(
    const float* __restrict__ e1, const float* __restrict__ e2,
    float* __restrict__ adj) {
    int n = blockIdx.x & 63;
    int bs = blockIdx.x >> 6;
    int m = threadIdx.x;
    const float* e1p = e1 + ((size_t)bs * NVAR + n) * RNK;
    const float* e2p = e2 + ((size_t)bs * NVAR + m) * RNK;
    float sc = 0.0f;
#pragma unroll
    for (int r = 0; r < RNK; ++r) sc += e1p[r] * e2p[r];
    sc *= 0.35355339059327373f;  // 1/sqrt(8)
    float mx = sc;
    for (int off = 32; off; off >>= 1) mx = fmaxf(mx, __shfl_xor(mx, off, 64));
    float ex = expf(sc - mx);
    float sm = ex;
    for (int off = 32; off; off >>= 1) sm += __shfl_xor(sm, off, 64);
    adj[((size_t)bs * NVAR + n) * NVAR + m] = ex / sm;
}

// ---------------- regularizer ----------------------------------------------
__global__ void zero_kernel(float* p) {
    if (threadIdx.x == 0 && blockIdx.x == 0) p[0] = 0.0f;
}

__global__ __launch_bounds__(256) void reg_kernel(
    const float* __restrict__ adj, float* __restrict__ regacc) {
    const int total = BATCH * (SEG - 1) * NVAR * NVAR;
    float sum = 0.0f;
    for (int idx = blockIdx.x * 256 + threadIdx.x; idx < total;
         idx += gridDim.x * 256) {
        int m = idx & 63;
        int n = (idx >> 6) & 63;
        int rest = idx >> 12;
        int sm1 = rest % 31;
        int b = rest / 31;
        int s = sm1 + 1;
        size_t i1 = (((size_t)b * SEG + s) * NVAR + n) * NVAR + m;
        sum += fabsf(adj[i1] - adj[i1 - NVAR * NVAR]);
    }
    for (int off = 32; off; off >>= 1) sum += __shfl_xor(sum, off, 64);
    __shared__ float wsum[4];
    int lane = threadIdx.x & 63, w = threadIdx.x >> 6;
    if (lane == 0) wsum[w] = sum;
    __syncthreads();
    if (threadIdx.x == 0)
        atomicAdd(regacc, wsum[0] + wsum[1] + wsum[2] + wsum[3]);
}

__global__ void finalize_reg(const float* __restrict__ regacc,
                             float* __restrict__ out, int out_size) {
    if (threadIdx.x == 0 && blockIdx.x == 0)
        out[out_size - 1] = regacc[0] * (1.0f / 65536.0f);
}

// ---------------- G GEMM (f32): per (s, 128-bn tile) ------------------------
__global__ __launch_bounds__(256) void g_gemm(
    const ushort_t* __restrict__ h2, const float* __restrict__ head_w,
    float* __restrict__ G) {
    __shared__ float As[128][65];
    __shared__ float Bs[64][96];
    int s = blockIdx.x;
    int bn0 = blockIdx.y * 128;
    int tx = threadIdx.x & 15;
    int ty = threadIdx.x >> 4;

    float acc[8][6];
#pragma unroll
    for (int i = 0; i < 8; ++i)
#pragma unroll
        for (int j = 0; j < 6; ++j) acc[i][j] = 0.0f;

    for (int kt = 0; kt < 2048; kt += 64) {
#pragma unroll
        for (int i = 0; i < 8; ++i) {
            int q = threadIdx.x + 256 * i;
            int row = q >> 4, kq = (q & 15) * 4;
            ushort4 v = *reinterpret_cast<const ushort4*>(
                &h2[(size_t)(bn0 + row) * ROWLEN + (size_t)s * 2048 + kt + kq]);
            As[row][kq + 0] = bf2f(v.x);
            As[row][kq + 1] = bf2f(v.y);
            As[row][kq + 2] = bf2f(v.z);
            As[row][kq + 3] = bf2f(v.w);
        }
#pragma unroll
        for (int i = 0; i < 6; ++i) {
            int q = threadIdx.x + 256 * i;
            int row = q / 24, pq = (q % 24) * 4;
            float4 v = *reinterpret_cast<const float4*>(
                &head_w[((size_t)s * 2048 + kt + row) * PRED + pq]);
            *reinterpret_cast<float4*>(&Bs[row][pq]) = v;
        }
        __syncthreads();
#pragma unroll 4
        for (int k = 0; k < 64; ++k) {
            float a[8], bb[6];
#pragma unroll
            for (int i = 0; i < 8; ++i) a[i] = As[ty * 8 + i][k];
#pragma unroll
            for (int j = 0; j < 6; ++j) bb[j] = Bs[k][tx * 6 + j];
#pragma unroll
            for (int i = 0; i < 8; ++i)
#pragma unroll
                for (int j = 0; j < 6; ++j) acc[i][j] += a[i] * bb[j];
        }
        __syncthreads();
    }
#pragma unroll
    for (int i = 0; i < 8; ++i) {
        int bn = bn0 + ty * 8 + i;
        int b = bn >> 6, m = bn & 63;
#pragma unroll
        for (int j = 0; j < 6; ++j) {
            int p = tx * 6 + j;
            G[(((size_t)s * BATCH + b) * PRED + p) * NVAR + m] = acc[i][j];
        }
    }
}

// ---------------- out[b][p][n] = head_b[p] + sum_{s,m} adj[b,s,n,m]*G[s,b,p,m]
__global__ __launch_bounds__(256) void out_final(
    const float* __restrict__ adj, const float* __restrict__ G,
    const float* __restrict__ head_b, float* __restrict__ out) {
    __shared__ float adjn[32][65];
    __shared__ float Gs[96][65];
    int b = blockIdx.x, nh = blockIdx.y;
    int tx = threadIdx.x & 15;
    int ty = threadIdx.x >> 4;
    int p0 = tx * 6;

    float acc[2][6];
#pragma unroll
    for (int j = 0; j < 6; ++j) {
        float hb = head_b[p0 + j];
        acc[0][j] = hb; acc[1][j] = hb;
    }

    for (int s = 0; s < SEG; ++s) {
#pragma unroll
        for (int i = 0; i < 2; ++i) {
            int q = threadIdx.x + 256 * i;
            int row = q >> 4, mq = (q & 15) * 4;
            float4 v = *reinterpret_cast<const float4*>(
                &adj[(((size_t)b * SEG + s) * NVAR + nh * 32 + row) * NVAR + mq]);
            adjn[row][mq + 0] = v.x; adjn[row][mq + 1] = v.y;
            adjn[row][mq + 2] = v.z; adjn[row][mq + 3] = v.w;
        }
#pragma unroll
        for (int i = 0; i < 6; ++i) {
            int q = threadIdx.x + 256 * i;
            int row = q >> 4, mq = (q & 15) * 4;
            float4 v = *reinterpret_cast<const float4*>(
                &G[(((size_t)s * BATCH + b) * PRED + row) * NVAR + mq]);
            Gs[row][mq + 0] = v.x; Gs[row][mq + 1] = v.y;
            Gs[row][mq + 2] = v.z; Gs[row][mq + 3] = v.w;
        }
        __syncthreads();
#pragma unroll 4
        for (int m = 0; m < 64; ++m) {
            float a0 = adjn[ty * 2 + 0][m];
            float a1 = adjn[ty * 2 + 1][m];
#pragma unroll
            for (int j = 0; j < 6; ++j) {
                float g = Gs[p0 + j][m];
                acc[0][j] += a0 * g;
                acc[1][j] += a1 * g;
            }
        }
        __syncthreads();
    }
#pragma unroll
    for (int i = 0; i < 2; ++i) {
        int n = nh * 32 + ty * 2 + i;
#pragma unroll
        for (int j = 0; j < 6; ++j)
            out[((size_t)b * PRED + p0 + j) * NVAR + n] = acc[i][j];
    }
}

extern "C" void kernel_launch(void* const* d_in, const int* in_sizes, int n_in,
                              void* d_out, int out_size, void* d_ws,
                              size_t ws_size, hipStream_t stream) {
    const float* x_enc  = (const float*)d_in[0];
    const float* w_emb  = (const float*)d_in[4];
    const float* b_emb  = (const float*)d_in[5];
    const float* conv_w = (const float*)d_in[6];
    const float* conv_b = (const float*)d_in[7];
    const float* gg_w1  = (const float*)d_in[8];
    const float* gg_b1  = (const float*)d_in[9];
    const float* gg_w2  = (const float*)d_in[10];
    const float* gg_b2  = (const float*)d_in[11];
    const float* head_w = (const float*)d_in[12];
    const float* head_b = (const float*)d_in[13];
    float* out = (float*)d_out;

    // workspace: 157,286,404 B total (R5-proven). WT borrows G's slot
    // (WT consumed by tcn_mfma BEFORE g_gemm writes G).
    char* ws = (char*)d_ws;
    ushort_t* h2  = (ushort_t*)(ws);                    // 134,217,728
    float* G      = (float*)(ws + 134217728);           //  12,582,912
    ushort_t* WT  = (ushort_t*)(ws + 134217728);        //     196,608 (overlaps G)
    float* e1     = (float*)(ws + 146800640);           //   1,048,576
    float* e2     = (float*)(ws + 147849216);           //   1,048,576
    float* adj    = (float*)(ws + 148897792);           //   8,388,608
    float* regacc = (float*)(ws + 157286400);           //           4

    wt_prep<<<dim3(6, 128), 128, 0, stream>>>(conv_w, WT);
    tcn_mfma<<<dim3(BN, SEQ / 64), 256, 0, stream>>>(
        x_enc, w_emb, b_emb, WT, conv_b, h2);
    seg_e<<<BN * SEG, 128, 0, stream>>>(h2, gg_w1, gg_b1, gg_w2, gg_b2, e1, e2);
    softmax_kernel<<<BATCH * SEG * NVAR, 64, 0, stream>>>(e1, e2, adj);
    zero_kernel<<<1, 64, 0, stream>>>(regacc);
    reg_kernel<<<512, 256, 0, stream>>>(adj, regacc);
    finalize_reg<<<1, 64, 0, stream>>>(regacc, out, out_size);
    g_gemm<<<dim3(SEG, BN / 128), 256, 0, stream>>>(h2, head_w, G);
    out_final<<<dim3(BATCH, 2), 256, 0, stream>>>(adj, G, head_b, out);
}

// Round 7
// 558.079 us; speedup vs baseline: 16.5573x; 1.7031x over previous
//
#include <hip/hip_runtime.h>

// Model_81956565942963: TCN + low-rank dynamic graph + linear head.
// B=16, L=512, N=64, D=128, S=32 x 16, r=8, P=96. f32 in/out.
// R7: fast gelu (sigmoid/__expf), frag-major coalesced conv weights (WTf),
// h1 residual from bf16 (drops 36KB LDS -> 3 blocks/CU), seg_e fused into
// tcn epilogue, g_gemm converted to bf16 MFMA with on-the-fly B conversion.

#define BATCH 16
#define SEQ 512
#define NVAR 64
#define DM 128
#define SEG 32
#define SCL 16
#define RNK 8
#define PRED 96
#define BN (BATCH * NVAR)   // 1024
#define ROWLEN (SEQ * DM)   // 65536

typedef unsigned short ushort_t;
typedef __attribute__((ext_vector_type(8))) short short8;   // 8 bf16
typedef __attribute__((ext_vector_type(4))) float f32x4;

__device__ inline float bf2f(ushort_t u) {
    union { unsigned int i; float f; } x;
    x.i = ((unsigned int)u) << 16;
    return x.f;
}
__device__ inline ushort_t f2bf(float f) {
    union { float f; unsigned int i; } u;
    u.f = f;
    unsigned int x = u.i;
    return (ushort_t)((x + 0x7fffu + ((x >> 16) & 1u)) >> 16);  // RNE
}
// gelu(x) = 0.5x(1+tanh(t)) = x * sigmoid(2t), t = 0.79788x(1+0.044715x^2)
__device__ inline float gelu_fast(float x) {
    float t = 0.7978845608028654f * x * (1.0f + 0.044715f * x * x);
    return x / (1.0f + __expf(-2.0f * t));
}

// ---------------- conv-weight prep: frag-major bf16 -------------------------
// WTf[lt][kt][ng][lane][j]: n = ng*16+(lane&15), k = kt*32+(lane>>4)*8+j
__global__ __launch_bounds__(128) void wt_prep(
    const float* __restrict__ conv_w, ushort_t* __restrict__ WTf) {
    int lt = blockIdx.x;    // 0..5 (layer*3+tap)
    int ci = blockIdx.y;    // 0..127
    int co = threadIdx.x;   // 0..127
    int kt = ci >> 5, quad = (ci >> 3) & 3, j = ci & 7;
    int ng = co >> 4, col = co & 15;
    int lane = quad * 16 + col;
    WTf[((((size_t)lt * 4 + kt) * 8 + ng) * 64 + lane) * 8 + j] =
        f2bf(conv_w[(size_t)lt * 16384 + (size_t)ci * 128 + co]);
}

// ---------------- fused TCN (MFMA) + segment means + e1/e2 ------------------
__global__ __launch_bounds__(256) void tcn_mfma(
    const float* __restrict__ x, const float* __restrict__ w_emb,
    const float* __restrict__ b_emb, const ushort_t* __restrict__ WTf,
    const float* __restrict__ conv_b,
    const float* __restrict__ gw1, const float* __restrict__ gb1,
    const float* __restrict__ gw2, const float* __restrict__ gb2,
    ushort_t* __restrict__ h2, float* __restrict__ e1, float* __restrict__ e2) {
    __shared__ __align__(16) ushort_t h0s[82 * 136];  // embed, row = li+18
    __shared__ __align__(16) ushort_t h1b[68 * 136];  // conv1 out, row = li+4
    __shared__ float zb[4 * 128];

    int bn = blockIdx.x;
    int b = bn >> 6, n = bn & 63;
    int chunk = blockIdx.y;
    int l0 = chunk * 64;

    // ---- embed: 82 rows x 128 d (bf16), packed ushort2 writes ----
    {
        const float* xb = x + (size_t)b * SEQ * NVAR + n;
#pragma unroll
        for (int i = 0; i < 21; ++i) {
            int q = threadIdx.x + 256 * i;
            if (q < 82 * 64) {
                int row = q >> 6, dp = (q & 63) * 2;
                int l = l0 + row - 18;
                ushort2 pk;
                if (l >= 0) {
                    float xv = xb[(size_t)l * NVAR];
                    float2 wv2 = *reinterpret_cast<const float2*>(&w_emb[dp]);
                    float2 bv2 = *reinterpret_cast<const float2*>(&b_emb[dp]);
                    pk.x = f2bf(xv * wv2.x + bv2.x);
                    pk.y = f2bf(xv * wv2.y + bv2.y);
                } else {
                    pk.x = 0; pk.y = 0;
                }
                *reinterpret_cast<ushort2*>(&h0s[row * 136 + dp]) = pk;
            }
        }
    }
    __syncthreads();

    int lane = threadIdx.x & 63;
    int wv = threadIdx.x >> 6;
    int quad = lane >> 4;
    int col = lane & 15;
    int cobase = wv * 32;

    // ---- layer 1: A row ar <-> li = ar-16; tap t reads h0s row ar+t ----
    f32x4 acc1[5][2];
#pragma unroll
    for (int mt = 0; mt < 5; ++mt)
#pragma unroll
        for (int nt = 0; nt < 2; ++nt)
            acc1[mt][nt] = (f32x4){0.f, 0.f, 0.f, 0.f};

#pragma unroll
    for (int tap = 0; tap < 3; ++tap) {
#pragma unroll
        for (int kt = 0; kt < 4; ++kt) {
            const ushort_t* bp =
                WTf + ((((size_t)tap * 4 + kt) * 8 + wv * 2) * 64 + lane) * 8;
            short8 bf0 = *(const short8*)bp;
            short8 bf1 = *(const short8*)(bp + 512);
            int kc = kt * 32 + quad * 8;
#pragma unroll
            for (int mt = 0; mt < 5; ++mt) {
                short8 af = *(const short8*)&h0s[(mt * 16 + col + tap) * 136 + kc];
                acc1[mt][0] = __builtin_amdgcn_mfma_f32_16x16x32_bf16(af, bf0, acc1[mt][0], 0, 0, 0);
                acc1[mt][1] = __builtin_amdgcn_mfma_f32_16x16x32_bf16(af, bf1, acc1[mt][1], 0, 0, 0);
            }
        }
    }
    // epilogue 1: h1 = gelu(y+bias) + h0 (0 for l<0), bf16
    {
        float bias[2] = {conv_b[cobase + col], conv_b[cobase + 16 + col]};
#pragma unroll
        for (int mt = 0; mt < 5; ++mt)
#pragma unroll
            for (int nt = 0; nt < 2; ++nt) {
                int co = cobase + nt * 16 + col;
#pragma unroll
                for (int r = 0; r < 4; ++r) {
                    int li = mt * 16 - 16 + quad * 4 + r;
                    if (li >= -4) {
                        float hv = 0.0f;
                        if (l0 + li >= 0)
                            hv = gelu_fast(acc1[mt][nt][r] + bias[nt]) +
                                 bf2f(h0s[(li + 18) * 136 + co]);
                        h1b[(li + 4) * 136 + co] = f2bf(hv);
                    }
                }
            }
    }
    __syncthreads();

    // ---- layer 2: A row ar <-> li = ar; tap t reads h1b row ar+2t ----
    f32x4 acc2[4][2];
#pragma unroll
    for (int mt = 0; mt < 4; ++mt)
#pragma unroll
        for (int nt = 0; nt < 2; ++nt)
            acc2[mt][nt] = (f32x4){0.f, 0.f, 0.f, 0.f};

#pragma unroll
    for (int tap = 0; tap < 3; ++tap) {
#pragma unroll
        for (int kt = 0; kt < 4; ++kt) {
            const ushort_t* bp =
                WTf + ((((size_t)(3 + tap) * 4 + kt) * 8 + wv * 2) * 64 + lane) * 8;
            short8 bf0 = *(const short8*)bp;
            short8 bf1 = *(const short8*)(bp + 512);
            int kc = kt * 32 + quad * 8;
#pragma unroll
            for (int mt = 0; mt < 4; ++mt) {
                short8 af = *(const short8*)&h1b[(mt * 16 + col + 2 * tap) * 136 + kc];
                acc2[mt][0] = __builtin_amdgcn_mfma_f32_16x16x32_bf16(af, bf0, acc2[mt][0], 0, 0, 0);
                acc2[mt][1] = __builtin_amdgcn_mfma_f32_16x16x32_bf16(af, bf1, acc2[mt][1], 0, 0, 0);
            }
        }
    }
    // epilogue 2: h2 = gelu(y+bias) + h1 -> stage into h0s rows 0..63
    {
        float bias[2] = {conv_b[DM + cobase + col], conv_b[DM + cobase + 16 + col]};
#pragma unroll
        for (int mt = 0; mt < 4; ++mt)
#pragma unroll
            for (int nt = 0; nt < 2; ++nt) {
                int co = cobase + nt * 16 + col;
#pragma unroll
                for (int r = 0; r < 4; ++r) {
                    int li = mt * 16 + quad * 4 + r;
                    float hv = gelu_fast(acc2[mt][nt][r] + bias[nt]) +
                               bf2f(h1b[(li + 4) * 136 + co]);
                    h0s[li * 136 + co] = f2bf(hv);
                }
            }
    }
    __syncthreads();

    // ---- coalesced h2 store ----
    {
        ushort_t* orow = h2 + (size_t)bn * ROWLEN + (size_t)l0 * 128;
#pragma unroll
        for (int i = 0; i < 4; ++i) {
            int q = threadIdx.x + 256 * i;
            int row = q >> 4, c8 = (q & 15) * 8;
            *(short8*)&orow[row * 128 + c8] = *(const short8*)&h0s[row * 136 + c8];
        }
    }
    // ---- z: 4 segment means over the staged h2 tile ----
    {
        int d = threadIdx.x & 127, sg = threadIdx.x >> 7;
#pragma unroll
        for (int t = 0; t < 2; ++t) {
            int sl = sg + 2 * t;
            float a = 0.0f;
#pragma unroll
            for (int c = 0; c < SCL; ++c)
                a += bf2f(h0s[(sl * 16 + c) * 136 + d]);
            zb[sl * 128 + d] = a * (1.0f / 16.0f);
        }
    }
    __syncthreads();
    // ---- e1/e2: 4 segs x 2 mats x 8 ranks ----
    if (threadIdx.x < 64) {
        int sl = threadIdx.x >> 4;
        int which = (threadIdx.x >> 3) & 1;
        int r = threadIdx.x & 7;
        const float* w = which ? gw2 : gw1;
        float a = 0.0f;
        for (int d = 0; d < DM; ++d) a += zb[sl * 128 + d] * w[d * RNK + r];
        a += (which ? gb2 : gb1)[r];
        int s = chunk * 4 + sl;
        (which ? e2 : e1)[(((size_t)b * SEG + s) * NVAR + n) * RNK + r] = a;
    }
}

// ---------------- scores + softmax -> adj[b][s][n][m] -----------------------
__global__ __launch_bounds__(64) void softmax_kernel(
    const float* __restrict__ e1, const float* __restrict__ e2,
    float* __restrict__ adj) {
    int n = blockIdx.x & 63;
    int bs = blockIdx.x >> 6;
    int m = threadIdx.x;
    const float* e1p = e1 + ((size_t)bs * NVAR + n) * RNK;
    const float* e2p = e2 + ((size_t)bs * NVAR + m) * RNK;
    float sc = 0.0f;
#pragma unroll
    for (int r = 0; r < RNK; ++r) sc += e1p[r] * e2p[r];
    sc *= 0.35355339059327373f;  // 1/sqrt(8)
    float mx = sc;
    for (int off = 32; off; off >>= 1) mx = fmaxf(mx, __shfl_xor(mx, off, 64));
    float ex = expf(sc - mx);
    float sm = ex;
    for (int off = 32; off; off >>= 1) sm += __shfl_xor(sm, off, 64);
    adj[((size_t)bs * NVAR + n) * NVAR + m] = ex / sm;
}

// ---------------- regularizer ----------------------------------------------
__global__ void zero_kernel(float* p) {
    if (threadIdx.x == 0 && blockIdx.x == 0) p[0] = 0.0f;
}

__global__ __launch_bounds__(256) void reg_kernel(
    const float* __restrict__ adj, float* __restrict__ regacc) {
    const int total = BATCH * (SEG - 1) * NVAR * NVAR;
    float sum = 0.0f;
    for (int idx = blockIdx.x * 256 + threadIdx.x; idx < total;
         idx += gridDim.x * 256) {
        int m = idx & 63;
        int n = (idx >> 6) & 63;
        int rest = idx >> 12;
        int sm1 = rest % 31;
        int b = rest / 31;
        int s = sm1 + 1;
        size_t i1 = (((size_t)b * SEG + s) * NVAR + n) * NVAR + m;
        sum += fabsf(adj[i1] - adj[i1 - NVAR * NVAR]);
    }
    for (int off = 32; off; off >>= 1) sum += __shfl_xor(sum, off, 64);
    __shared__ float wsum[4];
    int lane = threadIdx.x & 63, w = threadIdx.x >> 6;
    if (lane == 0) wsum[w] = sum;
    __syncthreads();
    if (threadIdx.x == 0)
        atomicAdd(regacc, wsum[0] + wsum[1] + wsum[2] + wsum[3]);
}

__global__ void finalize_reg(const float* __restrict__ regacc,
                             float* __restrict__ out, int out_size) {
    if (threadIdx.x == 0 && blockIdx.x == 0)
        out[out_size - 1] = regacc[0] * (1.0f / 65536.0f);
}

// ---------------- G GEMM (MFMA): per (bn-tile 128, s) -----------------------
// A = h2 tile (bf16), B = head_w (f32 -> bf16 at staging). K = 2048.
// G layout: [s][b][p][m]
__global__ __launch_bounds__(256) void g_gemm(
    const ushort_t* __restrict__ h2, const float* __restrict__ head_w,
    float* __restrict__ G) {
    __shared__ __align__(16) ushort_t As[128 * 72];
    __shared__ __align__(16) ushort_t Bs[96 * 72];
    int bn0 = blockIdx.x * 128;
    int s = blockIdx.y;
    int lane = threadIdx.x & 63, wv = threadIdx.x >> 6;
    int quad = lane >> 4, col = lane & 15;
    int mh = wv & 1, nh = wv >> 1;

    f32x4 acc[4][3];
#pragma unroll
    for (int mt = 0; mt < 4; ++mt)
#pragma unroll
        for (int nt = 0; nt < 3; ++nt)
            acc[mt][nt] = (f32x4){0.f, 0.f, 0.f, 0.f};

    for (int kt2 = 0; kt2 < 2048; kt2 += 64) {
        // stage A: 128 rows x 64 k bf16 (coalesced short8)
#pragma unroll
        for (int i = 0; i < 4; ++i) {
            int q = threadIdx.x + 256 * i;  // 0..1023
            int row = q >> 3, kq = (q & 7) * 8;
            *(short8*)&As[row * 72 + kq] = *(const short8*)&h2[
                (size_t)(bn0 + row) * ROWLEN + (size_t)s * 2048 + kt2 + kq];
        }
        // stage B: 96 p x 64 k, f32->bf16, ushort2 (k-pair) writes
#pragma unroll
        for (int i = 0; i < 3; ++i) {
            int q = threadIdx.x + 256 * i;  // 0..767
            int p0 = (q % 24) * 4, k2 = (q / 24) * 2;
            const float* src = &head_w[((size_t)s * 2048 + kt2 + k2) * PRED + p0];
            float4 v0 = *reinterpret_cast<const float4*>(src);
            float4 v1 = *reinterpret_cast<const float4*>(src + PRED);
            ushort2 w0; w0.x = f2bf(v0.x); w0.y = f2bf(v1.x);
            ushort2 w1; w1.x = f2bf(v0.y); w1.y = f2bf(v1.y);
            ushort2 w2; w2.x = f2bf(v0.z); w2.y = f2bf(v1.z);
            ushort2 w3; w3.x = f2bf(v0.w); w3.y = f2bf(v1.w);
            *reinterpret_cast<ushort2*>(&Bs[(p0 + 0) * 72 + k2]) = w0;
            *reinterpret_cast<ushort2*>(&Bs[(p0 + 1) * 72 + k2]) = w1;
            *reinterpret_cast<ushort2*>(&Bs[(p0 + 2) * 72 + k2]) = w2;
            *reinterpret_cast<ushort2*>(&Bs[(p0 + 3) * 72 + k2]) = w3;
        }
        __syncthreads();
#pragma unroll
        for (int kk = 0; kk < 2; ++kk) {
            int kc = kk * 32 + quad * 8;
            short8 bfr[3];
#pragma unroll
            for (int nt = 0; nt < 3; ++nt)
                bfr[nt] = *(const short8*)&Bs[(nh * 48 + nt * 16 + col) * 72 + kc];
#pragma unroll
            for (int mt = 0; mt < 4; ++mt) {
                short8 af = *(const short8*)&As[(mh * 64 + mt * 16 + col) * 72 + kc];
#pragma unroll
                for (int nt = 0; nt < 3; ++nt)
                    acc[mt][nt] = __builtin_amdgcn_mfma_f32_16x16x32_bf16(af, bfr[nt], acc[mt][nt], 0, 0, 0);
            }
        }
        __syncthreads();
    }
    // store G[s][b][p][m]
#pragma unroll
    for (int mt = 0; mt < 4; ++mt)
#pragma unroll
        for (int nt = 0; nt < 3; ++nt)
#pragma unroll
            for (int r = 0; r < 4; ++r) {
                int m_local = mh * 64 + mt * 16 + quad * 4 + r;
                int p = nh * 48 + nt * 16 + col;
                int bnl = bn0 + m_local;
                int bb = bnl >> 6, m = bnl & 63;
                G[(((size_t)s * BATCH + bb) * PRED + p) * NVAR + m] = acc[mt][nt][r];
            }
}

// ---------------- out[b][p][n] = head_b[p] + sum_{s,m} adj[b,s,n,m]*G[s,b,p,m]
__global__ __launch_bounds__(256) void out_final(
    const float* __restrict__ adj, const float* __restrict__ G,
    const float* __restrict__ head_b, float* __restrict__ out) {
    __shared__ float adjn[32][65];
    __shared__ float Gs[96][65];
    int b = blockIdx.x, nh = blockIdx.y;
    int tx = threadIdx.x & 15;
    int ty = threadIdx.x >> 4;
    int p0 = tx * 6;

    float acc[2][6];
#pragma unroll
    for (int j = 0; j < 6; ++j) {
        float hb = head_b[p0 + j];
        acc[0][j] = hb; acc[1][j] = hb;
    }

    for (int s = 0; s < SEG; ++s) {
#pragma unroll
        for (int i = 0; i < 2; ++i) {
            int q = threadIdx.x + 256 * i;
            int row = q >> 4, mq = (q & 15) * 4;
            float4 v = *reinterpret_cast<const float4*>(
                &adj[(((size_t)b * SEG + s) * NVAR + nh * 32 + row) * NVAR + mq]);
            adjn[row][mq + 0] = v.x; adjn[row][mq + 1] = v.y;
            adjn[row][mq + 2] = v.z; adjn[row][mq + 3] = v.w;
        }
#pragma unroll
        for (int i = 0; i < 6; ++i) {
            int q = threadIdx.x + 256 * i;
            int row = q >> 4, mq = (q & 15) * 4;
            float4 v = *reinterpret_cast<const float4*>(
                &G[(((size_t)s * BATCH + b) * PRED + row) * NVAR + mq]);
            Gs[row][mq + 0] = v.x; Gs[row][mq + 1] = v.y;
            Gs[row][mq + 2] = v.z; Gs[row][mq + 3] = v.w;
        }
        __syncthreads();
#pragma unroll 4
        for (int m = 0; m < 64; ++m) {
            float a0 = adjn[ty * 2 + 0][m];
            float a1 = adjn[ty * 2 + 1][m];
#pragma unroll
            for (int j = 0; j < 6; ++j) {
                float g = Gs[p0 + j][m];
                acc[0][j] += a0 * g;
                acc[1][j] += a1 * g;
            }
        }
        __syncthreads();
    }
#pragma unroll
    for (int i = 0; i < 2; ++i) {
        int n = nh * 32 + ty * 2 + i;
#pragma unroll
        for (int j = 0; j < 6; ++j)
            out[((size_t)b * PRED + p0 + j) * NVAR + n] = acc[i][j];
    }
}

extern "C" void kernel_launch(void* const* d_in, const int* in_sizes, int n_in,
                              void* d_out, int out_size, void* d_ws,
                              size_t ws_size, hipStream_t stream) {
    const float* x_enc  = (const float*)d_in[0];
    const float* w_emb  = (const float*)d_in[4];
    const float* b_emb  = (const float*)d_in[5];
    const float* conv_w = (const float*)d_in[6];
    const float* conv_b = (const float*)d_in[7];
    const float* gg_w1  = (const float*)d_in[8];
    const float* gg_b1  = (const float*)d_in[9];
    const float* gg_w2  = (const float*)d_in[10];
    const float* gg_b2  = (const float*)d_in[11];
    const float* head_w = (const float*)d_in[12];
    const float* head_b = (const float*)d_in[13];
    float* out = (float*)d_out;

    // workspace: 157,286,404 B total (R5/R6-proven). WTf borrows the adj
    // slot: consumed by tcn_mfma, which completes before softmax writes adj.
    char* ws = (char*)d_ws;
    ushort_t* h2  = (ushort_t*)(ws);                    // 134,217,728
    float* G      = (float*)(ws + 134217728);           //  12,582,912
    float* e1     = (float*)(ws + 146800640);           //   1,048,576
    float* e2     = (float*)(ws + 147849216);           //   1,048,576
    float* adj    = (float*)(ws + 148897792);           //   8,388,608
    ushort_t* WTf = (ushort_t*)(ws + 148897792);        //     196,608 (overlaps adj)
    float* regacc = (float*)(ws + 157286400);           //           4

    wt_prep<<<dim3(6, 128), 128, 0, stream>>>(conv_w, WTf);
    tcn_mfma<<<dim3(BN, SEQ / 64), 256, 0, stream>>>(
        x_enc, w_emb, b_emb, WTf, conv_b,
        gg_w1, gg_b1, gg_w2, gg_b2, h2, e1, e2);
    softmax_kernel<<<BATCH * SEG * NVAR, 64, 0, stream>>>(e1, e2, adj);
    zero_kernel<<<1, 64, 0, stream>>>(regacc);
    reg_kernel<<<512, 256, 0, stream>>>(adj, regacc);
    finalize_reg<<<1, 64, 0, stream>>>(regacc, out, out_size);
    g_gemm<<<dim3(BN / 128, SEG), 256, 0, stream>>>(h2, head_w, G);
    out_final<<<dim3(BATCH, 2), 256, 0, stream>>>(adj, G, head_b, out);
}

// Round 8
// 431.946 us; speedup vs baseline: 21.3922x; 1.2920x over previous
//
#include <hip/hip_runtime.h>
#include <hip/hip_bf16.h>

// Model_81956565942963: TCN + low-rank dynamic graph + linear head.
// B=16, L=512, N=64, D=128, S=32 x 16, r=8, P=96. f32 in/out.
// R8: MFMA operand swap (D[m=co][n=li]) -> packed b64 epilogues, conflict-
// free; zb aliased into h1b -> 40960B LDS = 4 blocks/CU; g_gemm swapped for
// coalesced G stores; out_final split into partial(split-s)+reduce.

#define BATCH 16
#define SEQ 512
#define NVAR 64
#define DM 128
#define SEG 32
#define SCL 16
#define RNK 8
#define PRED 96
#define BN (BATCH * NVAR)   // 1024
#define ROWLEN (SEQ * DM)   // 65536

typedef unsigned short ushort_t;
typedef __attribute__((ext_vector_type(8))) short short8;   // 8 bf16
typedef __attribute__((ext_vector_type(4))) float f32x4;

__device__ inline float bf2f(ushort_t u) {
    union { unsigned int i; float f; } x;
    x.i = ((unsigned int)u) << 16;
    return x.f;
}
__device__ inline ushort_t f2bf(float f) {
    union { float f; unsigned int i; } u;
    u.f = f;
    unsigned int x = u.i;
    return (ushort_t)((x + 0x7fffu + ((x >> 16) & 1u)) >> 16);  // RNE
}
__device__ inline unsigned int pkbf(float a, float b) {  // packed bf16 pair
    __hip_bfloat162 h = __float22bfloat162_rn(make_float2(a, b));
    union { __hip_bfloat162 h2; unsigned int u; } c;
    c.h2 = h;
    return c.u;
}
__device__ inline float blo(unsigned int u) {
    union { unsigned int i; float f; } x;
    x.i = u << 16;
    return x.f;
}
__device__ inline float bhi(unsigned int u) {
    union { unsigned int i; float f; } x;
    x.i = u & 0xFFFF0000u;
    return x.f;
}
// gelu(x) = x * sigmoid(2t), t = 0.79788x(1+0.044715x^2)
__device__ inline float gelu_fast(float x) {
    float t = 0.7978845608028654f * x * (1.0f + 0.044715f * x * x);
    return x / (1.0f + __expf(-2.0f * t));
}

// ---------------- conv-weight prep: frag-major bf16 (+ regacc zero) ---------
// WTf[lt][kt][ng][lane][j]: co = ng*16+(lane&15), k = kt*32+(lane>>4)*8+j
__global__ __launch_bounds__(128) void wt_prep(
    const float* __restrict__ conv_w, ushort_t* __restrict__ WTf,
    float* __restrict__ regacc) {
    if (blockIdx.x == 0 && blockIdx.y == 0 && threadIdx.x == 0) regacc[0] = 0.f;
    int lt = blockIdx.x;    // 0..5 (layer*3+tap)
    int ci = blockIdx.y;    // 0..127
    int co = threadIdx.x;   // 0..127
    int kt = ci >> 5, quad = (ci >> 3) & 3, j = ci & 7;
    int ng = co >> 4, col = co & 15;
    int lane = quad * 16 + col;
    WTf[((((size_t)lt * 4 + kt) * 8 + ng) * 64 + lane) * 8 + j] =
        f2bf(conv_w[(size_t)lt * 16384 + (size_t)ci * 128 + co]);
}

// ---------------- fused TCN (MFMA) + segment means + e1/e2 ------------------
__global__ __launch_bounds__(256) void tcn_mfma(
    const float* __restrict__ x, const float* __restrict__ w_emb,
    const float* __restrict__ b_emb, const ushort_t* __restrict__ WTf,
    const float* __restrict__ conv_b,
    const float* __restrict__ gw1, const float* __restrict__ gb1,
    const float* __restrict__ gw2, const float* __restrict__ gb2,
    ushort_t* __restrict__ h2, float* __restrict__ e1, float* __restrict__ e2) {
    __shared__ __align__(16) ushort_t h0s[82 * 136];  // embed, row = li+18
    __shared__ __align__(16) ushort_t h1b[68 * 136];  // conv1 out, row = li+4
    float* zb = reinterpret_cast<float*>(h1b);        // alias: h1b dead by then

    int bn = blockIdx.x;
    int b = bn >> 6, n = bn & 63;
    int chunk = blockIdx.y;
    int l0 = chunk * 64;

    // ---- embed: 82 rows x 128 d (bf16), packed ushort2 writes ----
    {
        const float* xb = x + (size_t)b * SEQ * NVAR + n;
#pragma unroll
        for (int i = 0; i < 21; ++i) {
            int q = threadIdx.x + 256 * i;
            if (q < 82 * 64) {
                int row = q >> 6, dp = (q & 63) * 2;
                int l = l0 + row - 18;
                unsigned int pk = 0;
                if (l >= 0) {
                    float xv = xb[(size_t)l * NVAR];
                    float2 wv2 = *reinterpret_cast<const float2*>(&w_emb[dp]);
                    float2 bv2 = *reinterpret_cast<const float2*>(&b_emb[dp]);
                    pk = pkbf(xv * wv2.x + bv2.x, xv * wv2.y + bv2.y);
                }
                *reinterpret_cast<unsigned int*>(&h0s[row * 136 + dp]) = pk;
            }
        }
    }
    __syncthreads();

    int lane = threadIdx.x & 63;
    int wv = threadIdx.x >> 6;
    int quad = lane >> 4;
    int col = lane & 15;
    int cobase = wv * 32;

    // ---- layer 1: D[m=co][n=li]; acc1[mt=li-tile][nt=co-tile] ----
    f32x4 acc1[5][2];
#pragma unroll
    for (int mt = 0; mt < 5; ++mt)
#pragma unroll
        for (int nt = 0; nt < 2; ++nt)
            acc1[mt][nt] = (f32x4){0.f, 0.f, 0.f, 0.f};

#pragma unroll
    for (int tap = 0; tap < 3; ++tap) {
#pragma unroll
        for (int kt = 0; kt < 4; ++kt) {
            const ushort_t* bp =
                WTf + ((((size_t)tap * 4 + kt) * 8 + wv * 2) * 64 + lane) * 8;
            short8 wf0 = *(const short8*)bp;
            short8 wf1 = *(const short8*)(bp + 512);
            int kc = kt * 32 + quad * 8;
#pragma unroll
            for (int mt = 0; mt < 5; ++mt) {
                short8 hf = *(const short8*)&h0s[(mt * 16 + col + tap) * 136 + kc];
                acc1[mt][0] = __builtin_amdgcn_mfma_f32_16x16x32_bf16(wf0, hf, acc1[mt][0], 0, 0, 0);
                acc1[mt][1] = __builtin_amdgcn_mfma_f32_16x16x32_bf16(wf1, hf, acc1[mt][1], 0, 0, 0);
            }
        }
    }
    // epilogue 1: lane holds li = mt*16+col-16, co = cobase+nt*16+quad*4+r
    {
        float4 bias[2];
        bias[0] = *reinterpret_cast<const float4*>(&conv_b[cobase + quad * 4]);
        bias[1] = *reinterpret_cast<const float4*>(&conv_b[cobase + 16 + quad * 4]);
#pragma unroll
        for (int mt = 0; mt < 5; ++mt) {
            int li = mt * 16 + col - 16;
            if (li >= -4) {
#pragma unroll
                for (int nt = 0; nt < 2; ++nt) {
                    int co = cobase + nt * 16 + quad * 4;
                    uint2 pk;
                    if (l0 + li < 0) {
                        pk.x = 0u; pk.y = 0u;
                    } else {
                        uint2 res = *reinterpret_cast<const uint2*>(
                            &h0s[(mt * 16 + col + 2) * 136 + co]);
                        float h0 = gelu_fast(acc1[mt][nt][0] + bias[nt].x) + blo(res.x);
                        float h1 = gelu_fast(acc1[mt][nt][1] + bias[nt].y) + bhi(res.x);
                        float h2v = gelu_fast(acc1[mt][nt][2] + bias[nt].z) + blo(res.y);
                        float h3 = gelu_fast(acc1[mt][nt][3] + bias[nt].w) + bhi(res.y);
                        pk.x = pkbf(h0, h1);
                        pk.y = pkbf(h2v, h3);
                    }
                    *reinterpret_cast<uint2*>(&h1b[(li + 4) * 136 + co]) = pk;
                }
            }
        }
    }
    __syncthreads();

    // ---- layer 2: li = mt*16+col; tap t reads h1b row li+2t ----
    f32x4 acc2[4][2];
#pragma unroll
    for (int mt = 0; mt < 4; ++mt)
#pragma unroll
        for (int nt = 0; nt < 2; ++nt)
            acc2[mt][nt] = (f32x4){0.f, 0.f, 0.f, 0.f};

#pragma unroll
    for (int tap = 0; tap < 3; ++tap) {
#pragma unroll
        for (int kt = 0; kt < 4; ++kt) {
            const ushort_t* bp =
                WTf + ((((size_t)(3 + tap) * 4 + kt) * 8 + wv * 2) * 64 + lane) * 8;
            short8 wf0 = *(const short8*)bp;
            short8 wf1 = *(const short8*)(bp + 512);
            int kc = kt * 32 + quad * 8;
#pragma unroll
            for (int mt = 0; mt < 4; ++mt) {
                short8 hf = *(const short8*)&h1b[(mt * 16 + col + 2 * tap) * 136 + kc];
                acc2[mt][0] = __builtin_amdgcn_mfma_f32_16x16x32_bf16(wf0, hf, acc2[mt][0], 0, 0, 0);
                acc2[mt][1] = __builtin_amdgcn_mfma_f32_16x16x32_bf16(wf1, hf, acc2[mt][1], 0, 0, 0);
            }
        }
    }
    // epilogue 2: h2 = gelu(y+bias)+h1 -> stage into h0s rows 0..63 (b64)
    {
        float4 bias[2];
        bias[0] = *reinterpret_cast<const float4*>(&conv_b[DM + cobase + quad * 4]);
        bias[1] = *reinterpret_cast<const float4*>(&conv_b[DM + cobase + 16 + quad * 4]);
#pragma unroll
        for (int mt = 0; mt < 4; ++mt) {
            int li = mt * 16 + col;
#pragma unroll
            for (int nt = 0; nt < 2; ++nt) {
                int co = cobase + nt * 16 + quad * 4;
                uint2 res = *reinterpret_cast<const uint2*>(
                    &h1b[(li + 4) * 136 + co]);
                float h0 = gelu_fast(acc2[mt][nt][0] + bias[nt].x) + blo(res.x);
                float h1 = gelu_fast(acc2[mt][nt][1] + bias[nt].y) + bhi(res.x);
                float h2v = gelu_fast(acc2[mt][nt][2] + bias[nt].z) + blo(res.y);
                float h3 = gelu_fast(acc2[mt][nt][3] + bias[nt].w) + bhi(res.y);
                uint2 pk;
                pk.x = pkbf(h0, h1);
                pk.y = pkbf(h2v, h3);
                *reinterpret_cast<uint2*>(&h0s[li * 136 + co]) = pk;
            }
        }
    }
    __syncthreads();

    // ---- coalesced h2 store ----
    {
        ushort_t* orow = h2 + (size_t)bn * ROWLEN + (size_t)l0 * 128;
#pragma unroll
        for (int i = 0; i < 4; ++i) {
            int q = threadIdx.x + 256 * i;
            int row = q >> 4, c8 = (q & 15) * 8;
            *(short8*)&orow[row * 128 + c8] = *(const short8*)&h0s[row * 136 + c8];
        }
    }
    // ---- z: 4 segment means over staged h2 tile (zb aliases h1b) ----
    {
        int d = threadIdx.x & 127, sg = threadIdx.x >> 7;
#pragma unroll
        for (int t = 0; t < 2; ++t) {
            int sl = sg + 2 * t;
            float a = 0.0f;
#pragma unroll
            for (int c = 0; c < SCL; ++c)
                a += bf2f(h0s[(sl * 16 + c) * 136 + d]);
            zb[sl * 128 + d] = a * (1.0f / 16.0f);
        }
    }
    __syncthreads();
    // ---- e1/e2: 4 segs x 2 mats x 8 ranks ----
    if (threadIdx.x < 64) {
        int sl = threadIdx.x >> 4;
        int which = (threadIdx.x >> 3) & 1;
        int r = threadIdx.x & 7;
        const float* w = which ? gw2 : gw1;
        float a = 0.0f;
        for (int d = 0; d < DM; ++d) a += zb[sl * 128 + d] * w[d * RNK + r];
        a += (which ? gb2 : gb1)[r];
        int s = chunk * 4 + sl;
        (which ? e2 : e1)[(((size_t)b * SEG + s) * NVAR + n) * RNK + r] = a;
    }
}

// ---------------- scores + softmax -> adj[b][s][n][m] -----------------------
__global__ __launch_bounds__(64) void softmax_kernel(
    const float* __restrict__ e1, const float* __restrict__ e2,
    float* __restrict__ adj) {
    int n = blockIdx.x & 63;
    int bs = blockIdx.x >> 6;
    int m = threadIdx.x;
    const float* e1p = e1 + ((size_t)bs * NVAR + n) * RNK;
    const float* e2p = e2 + ((size_t)bs * NVAR + m) * RNK;
    float sc = 0.0f;
#pragma unroll
    for (int r = 0; r < RNK; ++r) sc += e1p[r] * e2p[r];
    sc *= 0.35355339059327373f;  // 1/sqrt(8)
    float mx = sc;
    for (int off = 32; off; off >>= 1) mx = fmaxf(mx, __shfl_xor(mx, off, 64));
    float ex = expf(sc - mx);
    float sm = ex;
    for (int off = 32; off; off >>= 1) sm += __shfl_xor(sm, off, 64);
    adj[((size_t)bs * NVAR + n) * NVAR + m] = ex / sm;
}

// ---------------- regularizer ----------------------------------------------
__global__ __launch_bounds__(256) void reg_kernel(
    const float* __restrict__ adj, float* __restrict__ regacc) {
    const int total = BATCH * (SEG - 1) * NVAR * NVAR;
    float sum = 0.0f;
    for (int idx = blockIdx.x * 256 + threadIdx.x; idx < total;
         idx += gridDim.x * 256) {
        int m = idx & 63;
        int n = (idx >> 6) & 63;
        int rest = idx >> 12;
        int sm1 = rest % 31;
        int b = rest / 31;
        int s = sm1 + 1;
        size_t i1 = (((size_t)b * SEG + s) * NVAR + n) * NVAR + m;
        sum += fabsf(adj[i1] - adj[i1 - NVAR * NVAR]);
    }
    for (int off = 32; off; off >>= 1) sum += __shfl_xor(sum, off, 64);
    __shared__ float wsum[4];
    int lane = threadIdx.x & 63, w = threadIdx.x >> 6;
    if (lane == 0) wsum[w] = sum;
    __syncthreads();
    if (threadIdx.x == 0)
        atomicAdd(regacc, wsum[0] + wsum[1] + wsum[2] + wsum[3]);
}

// ---------------- G GEMM (MFMA, swapped): G[s][b][p][m], coalesced ----------
__global__ __launch_bounds__(256) void g_gemm(
    const ushort_t* __restrict__ h2, const float* __restrict__ head_w,
    float* __restrict__ G) {
    __shared__ __align__(16) ushort_t As[128 * 72];  // [bn][k]
    __shared__ __align__(16) ushort_t Bs[96 * 72];   // [p][k]
    int bn0 = blockIdx.x * 128;
    int s = blockIdx.y;
    int lane = threadIdx.x & 63, wv = threadIdx.x >> 6;
    int quad = lane >> 4, col = lane & 15;
    int mh = wv & 1;   // bn half (64)
    int ph = wv >> 1;  // p half (48)

    f32x4 acc[3][4];  // [p-tile][bn-tile]
#pragma unroll
    for (int i = 0; i < 3; ++i)
#pragma unroll
        for (int j = 0; j < 4; ++j) acc[i][j] = (f32x4){0.f, 0.f, 0.f, 0.f};

    for (int kt2 = 0; kt2 < 2048; kt2 += 64) {
        // stage A: 128 bn x 64 k bf16 (coalesced short8)
#pragma unroll
        for (int i = 0; i < 4; ++i) {
            int q = threadIdx.x + 256 * i;
            int row = q >> 3, kq = (q & 7) * 8;
            *(short8*)&As[row * 72 + kq] = *(const short8*)&h2[
                (size_t)(bn0 + row) * ROWLEN + (size_t)s * 2048 + kt2 + kq];
        }
        // stage B: 96 p x 64 k, f32->bf16 packed along k
#pragma unroll
        for (int i = 0; i < 3; ++i) {
            int q = threadIdx.x + 256 * i;
            int p0 = (q % 24) * 4, k2 = (q / 24) * 2;
            const float* src = &head_w[((size_t)s * 2048 + kt2 + k2) * PRED + p0];
            float4 v0 = *reinterpret_cast<const float4*>(src);
            float4 v1 = *reinterpret_cast<const float4*>(src + PRED);
            *reinterpret_cast<unsigned int*>(&Bs[(p0 + 0) * 72 + k2]) = pkbf(v0.x, v1.x);
            *reinterpret_cast<unsigned int*>(&Bs[(p0 + 1) * 72 + k2]) = pkbf(v0.y, v1.y);
            *reinterpret_cast<unsigned int*>(&Bs[(p0 + 2) * 72 + k2]) = pkbf(v0.z, v1.z);
            *reinterpret_cast<unsigned int*>(&Bs[(p0 + 3) * 72 + k2]) = pkbf(v0.w, v1.w);
        }
        __syncthreads();
#pragma unroll
        for (int kk = 0; kk < 2; ++kk) {
            int kc = kk * 32 + quad * 8;
            short8 pfr[3];
#pragma unroll
            for (int i = 0; i < 3; ++i)
                pfr[i] = *(const short8*)&Bs[(ph * 48 + i * 16 + col) * 72 + kc];
#pragma unroll
            for (int j = 0; j < 4; ++j) {
                short8 bnfr = *(const short8*)&As[(mh * 64 + j * 16 + col) * 72 + kc];
#pragma unroll
                for (int i = 0; i < 3; ++i)
                    acc[i][j] = __builtin_amdgcn_mfma_f32_16x16x32_bf16(pfr[i], bnfr, acc[i][j], 0, 0, 0);
            }
        }
        __syncthreads();
    }
    // store G[s][b][p][m]: lanes (col) -> consecutive m ==> coalesced
    int b = (bn0 >> 6) + mh;
#pragma unroll
    for (int i = 0; i < 3; ++i)
#pragma unroll
        for (int j = 0; j < 4; ++j)
#pragma unroll
            for (int r = 0; r < 4; ++r) {
                int p = ph * 48 + i * 16 + quad * 4 + r;
                int m = j * 16 + col;
                G[(((size_t)s * BATCH + b) * PRED + p) * NVAR + m] = acc[i][j][r];
            }
}

// ---------------- out partials over s-groups of 8 ---------------------------
// partial[sg][b][p][n] = sum_{s in sg} sum_m adj[b,s,n,m] * G[s,b,p,m]
__global__ __launch_bounds__(256) void out_partial(
    const float* __restrict__ adj, const float* __restrict__ G,
    float* __restrict__ partial) {
    __shared__ float adjn[64][65];
    __shared__ float Gs[96][65];
    int b = blockIdx.x, sg = blockIdx.y;
    int pg = threadIdx.x >> 4;   // p = pg*6 + j
    int ng = threadIdx.x & 15;   // n = ng*4 + i

    float acc[6][4];
#pragma unroll
    for (int j = 0; j < 6; ++j)
#pragma unroll
        for (int i = 0; i < 4; ++i) acc[j][i] = 0.0f;

    for (int ss = 0; ss < 8; ++ss) {
        int s = sg * 8 + ss;
#pragma unroll
        for (int i = 0; i < 4; ++i) {
            int q = threadIdx.x + 256 * i;
            int row = q >> 4, mq = (q & 15) * 4;
            float4 v = *reinterpret_cast<const float4*>(
                &adj[(((size_t)b * SEG + s) * NVAR + row) * NVAR + mq]);
            adjn[row][mq + 0] = v.x; adjn[row][mq + 1] = v.y;
            adjn[row][mq + 2] = v.z; adjn[row][mq + 3] = v.w;
        }
#pragma unroll
        for (int i = 0; i < 6; ++i) {
            int q = threadIdx.x + 256 * i;
            int row = q >> 4, mq = (q & 15) * 4;
            float4 v = *reinterpret_cast<const float4*>(
                &G[(((size_t)s * BATCH + b) * PRED + row) * NVAR + mq]);
            Gs[row][mq + 0] = v.x; Gs[row][mq + 1] = v.y;
            Gs[row][mq + 2] = v.z; Gs[row][mq + 3] = v.w;
        }
        __syncthreads();
#pragma unroll 4
        for (int m = 0; m < 64; ++m) {
            float av[4], gv[6];
#pragma unroll
            for (int i = 0; i < 4; ++i) av[i] = adjn[ng * 4 + i][m];
#pragma unroll
            for (int j = 0; j < 6; ++j) gv[j] = Gs[pg * 6 + j][m];
#pragma unroll
            for (int j = 0; j < 6; ++j)
#pragma unroll
                for (int i = 0; i < 4; ++i) acc[j][i] += gv[j] * av[i];
        }
        __syncthreads();
    }
#pragma unroll
    for (int j = 0; j < 6; ++j)
#pragma unroll
        for (int i = 0; i < 4; ++i) {
            int p = pg * 6 + j, n = ng * 4 + i;
            partial[(((size_t)sg * BATCH + b) * PRED + p) * NVAR + n] = acc[j][i];
        }
}

// ---------------- reduce partials + head_b; also write reg scalar -----------
__global__ __launch_bounds__(256) void out_reduce(
    const float* __restrict__ partial, const float* __restrict__ head_b,
    const float* __restrict__ regacc, float* __restrict__ out, int out_size) {
    int idx = blockIdx.x * 256 + threadIdx.x;  // covers 16*96*64 = 98304
    int p = (idx >> 6) % PRED;
    float a = head_b[p];
    const int stride = BATCH * PRED * NVAR;
#pragma unroll
    for (int sg = 0; sg < 4; ++sg) a += partial[sg * stride + idx];
    out[idx] = a;
    if (idx == 0) out[out_size - 1] = regacc[0] * (1.0f / 65536.0f);
}

extern "C" void kernel_launch(void* const* d_in, const int* in_sizes, int n_in,
                              void* d_out, int out_size, void* d_ws,
                              size_t ws_size, hipStream_t stream) {
    const float* x_enc  = (const float*)d_in[0];
    const float* w_emb  = (const float*)d_in[4];
    const float* b_emb  = (const float*)d_in[5];
    const float* conv_w = (const float*)d_in[6];
    const float* conv_b = (const float*)d_in[7];
    const float* gg_w1  = (const float*)d_in[8];
    const float* gg_b1  = (const float*)d_in[9];
    const float* gg_w2  = (const float*)d_in[10];
    const float* gg_b2  = (const float*)d_in[11];
    const float* head_w = (const float*)d_in[12];
    const float* head_b = (const float*)d_in[13];
    float* out = (float*)d_out;

    // workspace: 157,286,404 B total (proven). WTf overlaps adj (consumed by
    // tcn_mfma before softmax writes adj); partial overlaps e1/e2 (consumed
    // by softmax before out_partial writes).
    char* ws = (char*)d_ws;
    ushort_t* h2   = (ushort_t*)(ws);                   // 134,217,728
    float* G       = (float*)(ws + 134217728);          //  12,582,912
    float* e1      = (float*)(ws + 146800640);          //   1,048,576
    float* e2      = (float*)(ws + 147849216);          //   1,048,576
    float* partial = (float*)(ws + 146800640);          //   1,572,864 (overlaps e1/e2)
    float* adj     = (float*)(ws + 148897792);          //   8,388,608
    ushort_t* WTf  = (ushort_t*)(ws + 148897792);       //     196,608 (overlaps adj)
    float* regacc  = (float*)(ws + 157286400);          //           4

    wt_prep<<<dim3(6, 128), 128, 0, stream>>>(conv_w, WTf, regacc);
    tcn_mfma<<<dim3(BN, SEQ / 64), 256, 0, stream>>>(
        x_enc, w_emb, b_emb, WTf, conv_b,
        gg_w1, gg_b1, gg_w2, gg_b2, h2, e1, e2);
    softmax_kernel<<<BATCH * SEG * NVAR, 64, 0, stream>>>(e1, e2, adj);
    reg_kernel<<<512, 256, 0, stream>>>(adj, regacc);
    g_gemm<<<dim3(BN / 128, SEG), 256, 0, stream>>>(h2, head_w, G);
    out_partial<<<dim3(BATCH, 4), 256, 0, stream>>>(adj, G, partial);
    out_reduce<<<BATCH * PRED * NVAR / 256, 256, 0, stream>>>(
        partial, head_b, regacc, out, out_size);
}

// Round 9
// 420.819 us; speedup vs baseline: 21.9578x; 1.0264x over previous
//
#include <hip/hip_runtime.h>
#include <hip/hip_bf16.h>

// Model_81956565942963: TCN + low-rank dynamic graph + linear head.
// B=16, L=512, N=64, D=128, S=32 x 16, r=8, P=96. f32 in/out.
// R9: gelu rcp (kills f32 div sequence), softmax 4-rows/block, out_partial
// n-split (128 blocks), out_reduce float4, g_gemm grid transposed (s fastest)
// for per-XCD L2 reuse of head_w slices.
// Note: tcn's 1.9e7 SQ_LDS_BANK_CONFLICT is inherent ds_read_b128 overhead
// (b128 ~12cyc vs 8 ideal, m134); 136-stride already hits the 8-access/bank
// bandwidth minimum, so no padding change.

#define BATCH 16
#define SEQ 512
#define NVAR 64
#define DM 128
#define SEG 32
#define SCL 16
#define RNK 8
#define PRED 96
#define BN (BATCH * NVAR)   // 1024
#define ROWLEN (SEQ * DM)   // 65536

typedef unsigned short ushort_t;
typedef __attribute__((ext_vector_type(8))) short short8;   // 8 bf16
typedef __attribute__((ext_vector_type(4))) float f32x4;

__device__ inline float bf2f(ushort_t u) {
    union { unsigned int i; float f; } x;
    x.i = ((unsigned int)u) << 16;
    return x.f;
}
__device__ inline ushort_t f2bf(float f) {
    union { float f; unsigned int i; } u;
    u.f = f;
    unsigned int x = u.i;
    return (ushort_t)((x + 0x7fffu + ((x >> 16) & 1u)) >> 16);  // RNE
}
__device__ inline unsigned int pkbf(float a, float b) {  // packed bf16 pair
    __hip_bfloat162 h = __float22bfloat162_rn(make_float2(a, b));
    union { __hip_bfloat162 h2; unsigned int u; } c;
    c.h2 = h;
    return c.u;
}
__device__ inline float blo(unsigned int u) {
    union { unsigned int i; float f; } x;
    x.i = u << 16;
    return x.f;
}
__device__ inline float bhi(unsigned int u) {
    union { unsigned int i; float f; } x;
    x.i = u & 0xFFFF0000u;
    return x.f;
}
// gelu(x) = x * sigmoid(2t); rcp is v_rcp_f32 (1 inst) not the div sequence
__device__ inline float gelu_fast(float x) {
    float t = 0.7978845608028654f * x * (1.0f + 0.044715f * x * x);
    float e = __expf(-2.0f * t);
    return x * __builtin_amdgcn_rcpf(1.0f + e);
}

// ---------------- conv-weight prep: frag-major bf16 (+ regacc zero) ---------
__global__ __launch_bounds__(128) void wt_prep(
    const float* __restrict__ conv_w, ushort_t* __restrict__ WTf,
    float* __restrict__ regacc) {
    if (blockIdx.x == 0 && blockIdx.y == 0 && threadIdx.x == 0) regacc[0] = 0.f;
    int lt = blockIdx.x;    // 0..5 (layer*3+tap)
    int ci = blockIdx.y;    // 0..127
    int co = threadIdx.x;   // 0..127
    int kt = ci >> 5, quad = (ci >> 3) & 3, j = ci & 7;
    int ng = co >> 4, col = co & 15;
    int lane = quad * 16 + col;
    WTf[((((size_t)lt * 4 + kt) * 8 + ng) * 64 + lane) * 8 + j] =
        f2bf(conv_w[(size_t)lt * 16384 + (size_t)ci * 128 + co]);
}

// ---------------- fused TCN (MFMA) + segment means + e1/e2 ------------------
__global__ __launch_bounds__(256) void tcn_mfma(
    const float* __restrict__ x, const float* __restrict__ w_emb,
    const float* __restrict__ b_emb, const ushort_t* __restrict__ WTf,
    const float* __restrict__ conv_b,
    const float* __restrict__ gw1, const float* __restrict__ gb1,
    const float* __restrict__ gw2, const float* __restrict__ gb2,
    ushort_t* __restrict__ h2, float* __restrict__ e1, float* __restrict__ e2) {
    __shared__ __align__(16) ushort_t h0s[82 * 136];  // embed, row = li+18
    __shared__ __align__(16) ushort_t h1b[68 * 136];  // conv1 out, row = li+4
    float* zb = reinterpret_cast<float*>(h1b);        // alias: h1b dead by then

    int bn = blockIdx.x;
    int b = bn >> 6, n = bn & 63;
    int chunk = blockIdx.y;
    int l0 = chunk * 64;

    // ---- embed: 82 rows x 128 d (bf16), packed writes ----
    {
        const float* xb = x + (size_t)b * SEQ * NVAR + n;
#pragma unroll
        for (int i = 0; i < 21; ++i) {
            int q = threadIdx.x + 256 * i;
            if (q < 82 * 64) {
                int row = q >> 6, dp = (q & 63) * 2;
                int l = l0 + row - 18;
                unsigned int pk = 0;
                if (l >= 0) {
                    float xv = xb[(size_t)l * NVAR];
                    float2 wv2 = *reinterpret_cast<const float2*>(&w_emb[dp]);
                    float2 bv2 = *reinterpret_cast<const float2*>(&b_emb[dp]);
                    pk = pkbf(xv * wv2.x + bv2.x, xv * wv2.y + bv2.y);
                }
                *reinterpret_cast<unsigned int*>(&h0s[row * 136 + dp]) = pk;
            }
        }
    }
    __syncthreads();

    int lane = threadIdx.x & 63;
    int wv = threadIdx.x >> 6;
    int quad = lane >> 4;
    int col = lane & 15;
    int cobase = wv * 32;

    // ---- layer 1: D[m=co][n=li]; acc1[mt=li-tile][nt=co-tile] ----
    f32x4 acc1[5][2];
#pragma unroll
    for (int mt = 0; mt < 5; ++mt)
#pragma unroll
        for (int nt = 0; nt < 2; ++nt)
            acc1[mt][nt] = (f32x4){0.f, 0.f, 0.f, 0.f};

#pragma unroll
    for (int tap = 0; tap < 3; ++tap) {
#pragma unroll
        for (int kt = 0; kt < 4; ++kt) {
            const ushort_t* bp =
                WTf + ((((size_t)tap * 4 + kt) * 8 + wv * 2) * 64 + lane) * 8;
            short8 wf0 = *(const short8*)bp;
            short8 wf1 = *(const short8*)(bp + 512);
            int kc = kt * 32 + quad * 8;
#pragma unroll
            for (int mt = 0; mt < 5; ++mt) {
                short8 hf = *(const short8*)&h0s[(mt * 16 + col + tap) * 136 + kc];
                acc1[mt][0] = __builtin_amdgcn_mfma_f32_16x16x32_bf16(wf0, hf, acc1[mt][0], 0, 0, 0);
                acc1[mt][1] = __builtin_amdgcn_mfma_f32_16x16x32_bf16(wf1, hf, acc1[mt][1], 0, 0, 0);
            }
        }
    }
    // epilogue 1: lane holds li = mt*16+col-16, co = cobase+nt*16+quad*4+r
    {
        float4 bias[2];
        bias[0] = *reinterpret_cast<const float4*>(&conv_b[cobase + quad * 4]);
        bias[1] = *reinterpret_cast<const float4*>(&conv_b[cobase + 16 + quad * 4]);
#pragma unroll
        for (int mt = 0; mt < 5; ++mt) {
            int li = mt * 16 + col - 16;
            if (li >= -4) {
#pragma unroll
                for (int nt = 0; nt < 2; ++nt) {
                    int co = cobase + nt * 16 + quad * 4;
                    uint2 pk;
                    if (l0 + li < 0) {
                        pk.x = 0u; pk.y = 0u;
                    } else {
                        uint2 res = *reinterpret_cast<const uint2*>(
                            &h0s[(mt * 16 + col + 2) * 136 + co]);
                        float h0 = gelu_fast(acc1[mt][nt][0] + bias[nt].x) + blo(res.x);
                        float h1 = gelu_fast(acc1[mt][nt][1] + bias[nt].y) + bhi(res.x);
                        float h2v = gelu_fast(acc1[mt][nt][2] + bias[nt].z) + blo(res.y);
                        float h3 = gelu_fast(acc1[mt][nt][3] + bias[nt].w) + bhi(res.y);
                        pk.x = pkbf(h0, h1);
                        pk.y = pkbf(h2v, h3);
                    }
                    *reinterpret_cast<uint2*>(&h1b[(li + 4) * 136 + co]) = pk;
                }
            }
        }
    }
    __syncthreads();

    // ---- layer 2: li = mt*16+col; tap t reads h1b row li+2t ----
    f32x4 acc2[4][2];
#pragma unroll
    for (int mt = 0; mt < 4; ++mt)
#pragma unroll
        for (int nt = 0; nt < 2; ++nt)
            acc2[mt][nt] = (f32x4){0.f, 0.f, 0.f, 0.f};

#pragma unroll
    for (int tap = 0; tap < 3; ++tap) {
#pragma unroll
        for (int kt = 0; kt < 4; ++kt) {
            const ushort_t* bp =
                WTf + ((((size_t)(3 + tap) * 4 + kt) * 8 + wv * 2) * 64 + lane) * 8;
            short8 wf0 = *(const short8*)bp;
            short8 wf1 = *(const short8*)(bp + 512);
            int kc = kt * 32 + quad * 8;
#pragma unroll
            for (int mt = 0; mt < 4; ++mt) {
                short8 hf = *(const short8*)&h1b[(mt * 16 + col + 2 * tap) * 136 + kc];
                acc2[mt][0] = __builtin_amdgcn_mfma_f32_16x16x32_bf16(wf0, hf, acc2[mt][0], 0, 0, 0);
                acc2[mt][1] = __builtin_amdgcn_mfma_f32_16x16x32_bf16(wf1, hf, acc2[mt][1], 0, 0, 0);
            }
        }
    }
    // epilogue 2: h2 = gelu(y+bias)+h1 -> stage into h0s rows 0..63 (b64)
    {
        float4 bias[2];
        bias[0] = *reinterpret_cast<const float4*>(&conv_b[DM + cobase + quad * 4]);
        bias[1] = *reinterpret_cast<const float4*>(&conv_b[DM + cobase + 16 + quad * 4]);
#pragma unroll
        for (int mt = 0; mt < 4; ++mt) {
            int li = mt * 16 + col;
#pragma unroll
            for (int nt = 0; nt < 2; ++nt) {
                int co = cobase + nt * 16 + quad * 4;
                uint2 res = *reinterpret_cast<const uint2*>(
                    &h1b[(li + 4) * 136 + co]);
                float h0 = gelu_fast(acc2[mt][nt][0] + bias[nt].x) + blo(res.x);
                float h1 = gelu_fast(acc2[mt][nt][1] + bias[nt].y) + bhi(res.x);
                float h2v = gelu_fast(acc2[mt][nt][2] + bias[nt].z) + blo(res.y);
                float h3 = gelu_fast(acc2[mt][nt][3] + bias[nt].w) + bhi(res.y);
                uint2 pk;
                pk.x = pkbf(h0, h1);
                pk.y = pkbf(h2v, h3);
                *reinterpret_cast<uint2*>(&h0s[li * 136 + co]) = pk;
            }
        }
    }
    __syncthreads();

    // ---- coalesced h2 store ----
    {
        ushort_t* orow = h2 + (size_t)bn * ROWLEN + (size_t)l0 * 128;
#pragma unroll
        for (int i = 0; i < 4; ++i) {
            int q = threadIdx.x + 256 * i;
            int row = q >> 4, c8 = (q & 15) * 8;
            *(short8*)&orow[row * 128 + c8] = *(const short8*)&h0s[row * 136 + c8];
        }
    }
    // ---- z: 4 segment means over staged h2 tile (zb aliases h1b) ----
    {
        int d = threadIdx.x & 127, sg = threadIdx.x >> 7;
#pragma unroll
        for (int t = 0; t < 2; ++t) {
            int sl = sg + 2 * t;
            float a = 0.0f;
#pragma unroll
            for (int c = 0; c < SCL; ++c)
                a += bf2f(h0s[(sl * 16 + c) * 136 + d]);
            zb[sl * 128 + d] = a * (1.0f / 16.0f);
        }
    }
    __syncthreads();
    // ---- e1/e2: 4 segs x 2 mats x 8 ranks ----
    if (threadIdx.x < 64) {
        int sl = threadIdx.x >> 4;
        int which = (threadIdx.x >> 3) & 1;
        int r = threadIdx.x & 7;
        const float* w = which ? gw2 : gw1;
        float a = 0.0f;
        for (int d = 0; d < DM; ++d) a += zb[sl * 128 + d] * w[d * RNK + r];
        a += (which ? gb2 : gb1)[r];
        int s = chunk * 4 + sl;
        (which ? e2 : e1)[(((size_t)b * SEG + s) * NVAR + n) * RNK + r] = a;
    }
}

// ---------------- scores + softmax: 4 (b,s,n) rows per block ----------------
__global__ __launch_bounds__(256) void softmax_kernel(
    const float* __restrict__ e1, const float* __restrict__ e2,
    float* __restrict__ adj) {
    int gid = blockIdx.x * 4 + (threadIdx.x >> 6);  // row over B*S*N
    int m = threadIdx.x & 63;
    int n = gid & 63;
    int bs = gid >> 6;
    const float* e1p = e1 + ((size_t)bs * NVAR + n) * RNK;
    const float* e2p = e2 + ((size_t)bs * NVAR + m) * RNK;
    float sc = 0.0f;
#pragma unroll
    for (int r = 0; r < RNK; ++r) sc += e1p[r] * e2p[r];
    sc *= 0.35355339059327373f;  // 1/sqrt(8)
    float mx = sc;
    for (int off = 32; off; off >>= 1) mx = fmaxf(mx, __shfl_xor(mx, off, 64));
    float ex = __expf(sc - mx);
    float sm = ex;
    for (int off = 32; off; off >>= 1) sm += __shfl_xor(sm, off, 64);
    adj[((size_t)bs * NVAR + n) * NVAR + m] = ex * __builtin_amdgcn_rcpf(sm);
}

// ---------------- regularizer ----------------------------------------------
__global__ __launch_bounds__(256) void reg_kernel(
    const float* __restrict__ adj, float* __restrict__ regacc) {
    const int total = BATCH * (SEG - 1) * NVAR * NVAR;
    float sum = 0.0f;
    for (int idx = blockIdx.x * 256 + threadIdx.x; idx < total;
         idx += gridDim.x * 256) {
        int m = idx & 63;
        int n = (idx >> 6) & 63;
        int rest = idx >> 12;
        int sm1 = rest % 31;
        int b = rest / 31;
        int s = sm1 + 1;
        size_t i1 = (((size_t)b * SEG + s) * NVAR + n) * NVAR + m;
        sum += fabsf(adj[i1] - adj[i1 - NVAR * NVAR]);
    }
    for (int off = 32; off; off >>= 1) sum += __shfl_xor(sum, off, 64);
    __shared__ float wsum[4];
    int lane = threadIdx.x & 63, w = threadIdx.x >> 6;
    if (lane == 0) wsum[w] = sum;
    __syncthreads();
    if (threadIdx.x == 0)
        atomicAdd(regacc, wsum[0] + wsum[1] + wsum[2] + wsum[3]);
}

// ---------------- G GEMM (MFMA, swapped): G[s][b][p][m], coalesced ----------
// grid: x = s (fastest) -> round-robin XCD assignment keeps each XCD on a
// stable s-subset, so head_w slices re-hit per-XCD L2 across the bn sweep.
__global__ __launch_bounds__(256) void g_gemm(
    const ushort_t* __restrict__ h2, const float* __restrict__ head_w,
    float* __restrict__ G) {
    __shared__ __align__(16) ushort_t As[128 * 72];  // [bn][k]
    __shared__ __align__(16) ushort_t Bs[96 * 72];   // [p][k]
    int s = blockIdx.x;
    int bn0 = blockIdx.y * 128;
    int lane = threadIdx.x & 63, wv = threadIdx.x >> 6;
    int quad = lane >> 4, col = lane & 15;
    int mh = wv & 1;   // bn half (64)
    int ph = wv >> 1;  // p half (48)

    f32x4 acc[3][4];  // [p-tile][bn-tile]
#pragma unroll
    for (int i = 0; i < 3; ++i)
#pragma unroll
        for (int j = 0; j < 4; ++j) acc[i][j] = (f32x4){0.f, 0.f, 0.f, 0.f};

    for (int kt2 = 0; kt2 < 2048; kt2 += 64) {
        // stage A: 128 bn x 64 k bf16 (coalesced short8)
#pragma unroll
        for (int i = 0; i < 4; ++i) {
            int q = threadIdx.x + 256 * i;
            int row = q >> 3, kq = (q & 7) * 8;
            *(short8*)&As[row * 72 + kq] = *(const short8*)&h2[
                (size_t)(bn0 + row) * ROWLEN + (size_t)s * 2048 + kt2 + kq];
        }
        // stage B: 96 p x 64 k, f32->bf16 packed along k
#pragma unroll
        for (int i = 0; i < 3; ++i) {
            int q = threadIdx.x + 256 * i;
            int p0 = (q % 24) * 4, k2 = (q / 24) * 2;
            const float* src = &head_w[((size_t)s * 2048 + kt2 + k2) * PRED + p0];
            float4 v0 = *reinterpret_cast<const float4*>(src);
            float4 v1 = *reinterpret_cast<const float4*>(src + PRED);
            *reinterpret_cast<unsigned int*>(&Bs[(p0 + 0) * 72 + k2]) = pkbf(v0.x, v1.x);
            *reinterpret_cast<unsigned int*>(&Bs[(p0 + 1) * 72 + k2]) = pkbf(v0.y, v1.y);
            *reinterpret_cast<unsigned int*>(&Bs[(p0 + 2) * 72 + k2]) = pkbf(v0.z, v1.z);
            *reinterpret_cast<unsigned int*>(&Bs[(p0 + 3) * 72 + k2]) = pkbf(v0.w, v1.w);
        }
        __syncthreads();
#pragma unroll
        for (int kk = 0; kk < 2; ++kk) {
            int kc = kk * 32 + quad * 8;
            short8 pfr[3];
#pragma unroll
            for (int i = 0; i < 3; ++i)
                pfr[i] = *(const short8*)&Bs[(ph * 48 + i * 16 + col) * 72 + kc];
#pragma unroll
            for (int j = 0; j < 4; ++j) {
                short8 bnfr = *(const short8*)&As[(mh * 64 + j * 16 + col) * 72 + kc];
#pragma unroll
                for (int i = 0; i < 3; ++i)
                    acc[i][j] = __builtin_amdgcn_mfma_f32_16x16x32_bf16(pfr[i], bnfr, acc[i][j], 0, 0, 0);
            }
        }
        __syncthreads();
    }
    // store G[s][b][p][m]: lanes (col) -> consecutive m ==> coalesced
    int b = (bn0 >> 6) + mh;
#pragma unroll
    for (int i = 0; i < 3; ++i)
#pragma unroll
        for (int j = 0; j < 4; ++j)
#pragma unroll
            for (int r = 0; r < 4; ++r) {
                int p = ph * 48 + i * 16 + quad * 4 + r;
                int m = j * 16 + col;
                G[(((size_t)s * BATCH + b) * PRED + p) * NVAR + m] = acc[i][j][r];
            }
}

// ---------------- out partials: (b, sg of 8, n-half of 32) ------------------
__global__ __launch_bounds__(256) void out_partial(
    const float* __restrict__ adj, const float* __restrict__ G,
    float* __restrict__ partial) {
    __shared__ float adjn[32][65];
    __shared__ float Gs[96][65];
    int b = blockIdx.x, sg = blockIdx.y, nh = blockIdx.z;
    int pg = threadIdx.x >> 4;   // p = pg*6 + j
    int ng = threadIdx.x & 15;   // n = nh*32 + ng*2 + i

    float acc[6][2];
#pragma unroll
    for (int j = 0; j < 6; ++j) { acc[j][0] = 0.f; acc[j][1] = 0.f; }

    for (int ss = 0; ss < 8; ++ss) {
        int s = sg * 8 + ss;
#pragma unroll
        for (int i = 0; i < 2; ++i) {
            int q = threadIdx.x + 256 * i;  // 0..511 -> 32 rows x 16 m4
            int row = q >> 4, mq = (q & 15) * 4;
            float4 v = *reinterpret_cast<const float4*>(
                &adj[(((size_t)b * SEG + s) * NVAR + nh * 32 + row) * NVAR + mq]);
            adjn[row][mq + 0] = v.x; adjn[row][mq + 1] = v.y;
            adjn[row][mq + 2] = v.z; adjn[row][mq + 3] = v.w;
        }
#pragma unroll
        for (int i = 0; i < 6; ++i) {
            int q = threadIdx.x + 256 * i;
            int row = q >> 4, mq = (q & 15) * 4;
            float4 v = *reinterpret_cast<const float4*>(
                &G[(((size_t)s * BATCH + b) * PRED + row) * NVAR + mq]);
            Gs[row][mq + 0] = v.x; Gs[row][mq + 1] = v.y;
            Gs[row][mq + 2] = v.z; Gs[row][mq + 3] = v.w;
        }
        __syncthreads();
#pragma unroll 4
        for (int m = 0; m < 64; ++m) {
            float a0 = adjn[ng * 2 + 0][m];
            float a1 = adjn[ng * 2 + 1][m];
#pragma unroll
            for (int j = 0; j < 6; ++j) {
                float g = Gs[pg * 6 + j][m];
                acc[j][0] += g * a0;
                acc[j][1] += g * a1;
            }
        }
        __syncthreads();
    }
#pragma unroll
    for (int j = 0; j < 6; ++j)
#pragma unroll
        for (int i = 0; i < 2; ++i) {
            int p = pg * 6 + j, n = nh * 32 + ng * 2 + i;
            partial[(((size_t)sg * BATCH + b) * PRED + p) * NVAR + n] = acc[j][i];
        }
}

// ---------------- reduce partials + head_b (float4); write reg scalar -------
__global__ __launch_bounds__(256) void out_reduce(
    const float* __restrict__ partial, const float* __restrict__ head_b,
    const float* __restrict__ regacc, float* __restrict__ out, int out_size) {
    int i4 = blockIdx.x * 256 + threadIdx.x;  // 0..24575 float4s (98304 floats)
    int p = (i4 >> 4) % PRED;
    float hb = head_b[p];
    float4 a = make_float4(hb, hb, hb, hb);
    const int stride4 = BATCH * PRED * NVAR / 4;
    const float4* p4 = reinterpret_cast<const float4*>(partial);
#pragma unroll
    for (int sg = 0; sg < 4; ++sg) {
        float4 v = p4[sg * stride4 + i4];
        a.x += v.x; a.y += v.y; a.z += v.z; a.w += v.w;
    }
    reinterpret_cast<float4*>(out)[i4] = a;
    if (i4 == 0) out[out_size - 1] = regacc[0] * (1.0f / 65536.0f);
}

extern "C" void kernel_launch(void* const* d_in, const int* in_sizes, int n_in,
                              void* d_out, int out_size, void* d_ws,
                              size_t ws_size, hipStream_t stream) {
    const float* x_enc  = (const float*)d_in[0];
    const float* w_emb  = (const float*)d_in[4];
    const float* b_emb  = (const float*)d_in[5];
    const float* conv_w = (const float*)d_in[6];
    const float* conv_b = (const float*)d_in[7];
    const float* gg_w1  = (const float*)d_in[8];
    const float* gg_b1  = (const float*)d_in[9];
    const float* gg_w2  = (const float*)d_in[10];
    const float* gg_b2  = (const float*)d_in[11];
    const float* head_w = (const float*)d_in[12];
    const float* head_b = (const float*)d_in[13];
    float* out = (float*)d_out;

    // workspace: 157,286,404 B total (proven). WTf overlaps adj; partial
    // overlaps e1/e2 (each dead before the overlapper writes).
    char* ws = (char*)d_ws;
    ushort_t* h2   = (ushort_t*)(ws);                   // 134,217,728
    float* G       = (float*)(ws + 134217728);          //  12,582,912
    float* e1      = (float*)(ws + 146800640);          //   1,048,576
    float* e2      = (float*)(ws + 147849216);          //   1,048,576
    float* partial = (float*)(ws + 146800640);          //   1,572,864 (overlaps e1/e2)
    float* adj     = (float*)(ws + 148897792);          //   8,388,608
    ushort_t* WTf  = (ushort_t*)(ws + 148897792);       //     196,608 (overlaps adj)
    float* regacc  = (float*)(ws + 157286400);          //           4

    wt_prep<<<dim3(6, 128), 128, 0, stream>>>(conv_w, WTf, regacc);
    tcn_mfma<<<dim3(BN, SEQ / 64), 256, 0, stream>>>(
        x_enc, w_emb, b_emb, WTf, conv_b,
        gg_w1, gg_b1, gg_w2, gg_b2, h2, e1, e2);
    softmax_kernel<<<BATCH * SEG * NVAR / 4, 256, 0, stream>>>(e1, e2, adj);
    reg_kernel<<<512, 256, 0, stream>>>(adj, regacc);
    g_gemm<<<dim3(SEG, BN / 128), 256, 0, stream>>>(h2, head_w, G);
    out_partial<<<dim3(BATCH, 4, 2), 256, 0, stream>>>(adj, G, partial);
    out_reduce<<<BATCH * PRED * NVAR / 1024, 256, 0, stream>>>(
        partial, head_b, regacc, out, out_size);
}

// Round 10
// 412.877 us; speedup vs baseline: 22.3802x; 1.0192x over previous
//
#include <hip/hip_runtime.h>
#include <hip/hip_bf16.h>

// Model_81956565942963: TCN + low-rank dynamic graph + linear head.
// B=16, L=512, N=64, D=128, S=32 x 16, r=8, P=96. f32 in/out.
// R10: g_gemm restructured — bn-tile 64 (512 blocks = 2/CU), register
// double-buffer prefetch of A/B global loads across the K loop. tcn_mfma
// left byte-identical to R9 (243us, latency-bound; addressed separately).

#define BATCH 16
#define SEQ 512
#define NVAR 64
#define DM 128
#define SEG 32
#define SCL 16
#define RNK 8
#define PRED 96
#define BN (BATCH * NVAR)   // 1024
#define ROWLEN (SEQ * DM)   // 65536

typedef unsigned short ushort_t;
typedef __attribute__((ext_vector_type(8))) short short8;   // 8 bf16
typedef __attribute__((ext_vector_type(4))) float f32x4;

__device__ inline float bf2f(ushort_t u) {
    union { unsigned int i; float f; } x;
    x.i = ((unsigned int)u) << 16;
    return x.f;
}
__device__ inline ushort_t f2bf(float f) {
    union { float f; unsigned int i; } u;
    u.f = f;
    unsigned int x = u.i;
    return (ushort_t)((x + 0x7fffu + ((x >> 16) & 1u)) >> 16);  // RNE
}
__device__ inline unsigned int pkbf(float a, float b) {  // packed bf16 pair
    __hip_bfloat162 h = __float22bfloat162_rn(make_float2(a, b));
    union { __hip_bfloat162 h2; unsigned int u; } c;
    c.h2 = h;
    return c.u;
}
__device__ inline float blo(unsigned int u) {
    union { unsigned int i; float f; } x;
    x.i = u << 16;
    return x.f;
}
__device__ inline float bhi(unsigned int u) {
    union { unsigned int i; float f; } x;
    x.i = u & 0xFFFF0000u;
    return x.f;
}
// gelu(x) = x * sigmoid(2t); rcp is v_rcp_f32 (1 inst) not the div sequence
__device__ inline float gelu_fast(float x) {
    float t = 0.7978845608028654f * x * (1.0f + 0.044715f * x * x);
    float e = __expf(-2.0f * t);
    return x * __builtin_amdgcn_rcpf(1.0f + e);
}

// ---------------- conv-weight prep: frag-major bf16 (+ regacc zero) ---------
__global__ __launch_bounds__(128) void wt_prep(
    const float* __restrict__ conv_w, ushort_t* __restrict__ WTf,
    float* __restrict__ regacc) {
    if (blockIdx.x == 0 && blockIdx.y == 0 && threadIdx.x == 0) regacc[0] = 0.f;
    int lt = blockIdx.x;    // 0..5 (layer*3+tap)
    int ci = blockIdx.y;    // 0..127
    int co = threadIdx.x;   // 0..127
    int kt = ci >> 5, quad = (ci >> 3) & 3, j = ci & 7;
    int ng = co >> 4, col = co & 15;
    int lane = quad * 16 + col;
    WTf[((((size_t)lt * 4 + kt) * 8 + ng) * 64 + lane) * 8 + j] =
        f2bf(conv_w[(size_t)lt * 16384 + (size_t)ci * 128 + co]);
}

// ---------------- fused TCN (MFMA) + segment means + e1/e2 ------------------
__global__ __launch_bounds__(256) void tcn_mfma(
    const float* __restrict__ x, const float* __restrict__ w_emb,
    const float* __restrict__ b_emb, const ushort_t* __restrict__ WTf,
    const float* __restrict__ conv_b,
    const float* __restrict__ gw1, const float* __restrict__ gb1,
    const float* __restrict__ gw2, const float* __restrict__ gb2,
    ushort_t* __restrict__ h2, float* __restrict__ e1, float* __restrict__ e2) {
    __shared__ __align__(16) ushort_t h0s[82 * 136];  // embed, row = li+18
    __shared__ __align__(16) ushort_t h1b[68 * 136];  // conv1 out, row = li+4
    float* zb = reinterpret_cast<float*>(h1b);        // alias: h1b dead by then

    int bn = blockIdx.x;
    int b = bn >> 6, n = bn & 63;
    int chunk = blockIdx.y;
    int l0 = chunk * 64;

    // ---- embed: 82 rows x 128 d (bf16), packed writes ----
    {
        const float* xb = x + (size_t)b * SEQ * NVAR + n;
#pragma unroll
        for (int i = 0; i < 21; ++i) {
            int q = threadIdx.x + 256 * i;
            if (q < 82 * 64) {
                int row = q >> 6, dp = (q & 63) * 2;
                int l = l0 + row - 18;
                unsigned int pk = 0;
                if (l >= 0) {
                    float xv = xb[(size_t)l * NVAR];
                    float2 wv2 = *reinterpret_cast<const float2*>(&w_emb[dp]);
                    float2 bv2 = *reinterpret_cast<const float2*>(&b_emb[dp]);
                    pk = pkbf(xv * wv2.x + bv2.x, xv * wv2.y + bv2.y);
                }
                *reinterpret_cast<unsigned int*>(&h0s[row * 136 + dp]) = pk;
            }
        }
    }
    __syncthreads();

    int lane = threadIdx.x & 63;
    int wv = threadIdx.x >> 6;
    int quad = lane >> 4;
    int col = lane & 15;
    int cobase = wv * 32;

    // ---- layer 1: D[m=co][n=li]; acc1[mt=li-tile][nt=co-tile] ----
    f32x4 acc1[5][2];
#pragma unroll
    for (int mt = 0; mt < 5; ++mt)
#pragma unroll
        for (int nt = 0; nt < 2; ++nt)
            acc1[mt][nt] = (f32x4){0.f, 0.f, 0.f, 0.f};

#pragma unroll
    for (int tap = 0; tap < 3; ++tap) {
#pragma unroll
        for (int kt = 0; kt < 4; ++kt) {
            const ushort_t* bp =
                WTf + ((((size_t)tap * 4 + kt) * 8 + wv * 2) * 64 + lane) * 8;
            short8 wf0 = *(const short8*)bp;
            short8 wf1 = *(const short8*)(bp + 512);
            int kc = kt * 32 + quad * 8;
#pragma unroll
            for (int mt = 0; mt < 5; ++mt) {
                short8 hf = *(const short8*)&h0s[(mt * 16 + col + tap) * 136 + kc];
                acc1[mt][0] = __builtin_amdgcn_mfma_f32_16x16x32_bf16(wf0, hf, acc1[mt][0], 0, 0, 0);
                acc1[mt][1] = __builtin_amdgcn_mfma_f32_16x16x32_bf16(wf1, hf, acc1[mt][1], 0, 0, 0);
            }
        }
    }
    // epilogue 1: lane holds li = mt*16+col-16, co = cobase+nt*16+quad*4+r
    {
        float4 bias[2];
        bias[0] = *reinterpret_cast<const float4*>(&conv_b[cobase + quad * 4]);
        bias[1] = *reinterpret_cast<const float4*>(&conv_b[cobase + 16 + quad * 4]);
#pragma unroll
        for (int mt = 0; mt < 5; ++mt) {
            int li = mt * 16 + col - 16;
            if (li >= -4) {
#pragma unroll
                for (int nt = 0; nt < 2; ++nt) {
                    int co = cobase + nt * 16 + quad * 4;
                    uint2 pk;
                    if (l0 + li < 0) {
                        pk.x = 0u; pk.y = 0u;
                    } else {
                        uint2 res = *reinterpret_cast<const uint2*>(
                            &h0s[(mt * 16 + col + 2) * 136 + co]);
                        float h0 = gelu_fast(acc1[mt][nt][0] + bias[nt].x) + blo(res.x);
                        float h1 = gelu_fast(acc1[mt][nt][1] + bias[nt].y) + bhi(res.x);
                        float h2v = gelu_fast(acc1[mt][nt][2] + bias[nt].z) + blo(res.y);
                        float h3 = gelu_fast(acc1[mt][nt][3] + bias[nt].w) + bhi(res.y);
                        pk.x = pkbf(h0, h1);
                        pk.y = pkbf(h2v, h3);
                    }
                    *reinterpret_cast<uint2*>(&h1b[(li + 4) * 136 + co]) = pk;
                }
            }
        }
    }
    __syncthreads();

    // ---- layer 2: li = mt*16+col; tap t reads h1b row li+2t ----
    f32x4 acc2[4][2];
#pragma unroll
    for (int mt = 0; mt < 4; ++mt)
#pragma unroll
        for (int nt = 0; nt < 2; ++nt)
            acc2[mt][nt] = (f32x4){0.f, 0.f, 0.f, 0.f};

#pragma unroll
    for (int tap = 0; tap < 3; ++tap) {
#pragma unroll
        for (int kt = 0; kt < 4; ++kt) {
            const ushort_t* bp =
                WTf + ((((size_t)(3 + tap) * 4 + kt) * 8 + wv * 2) * 64 + lane) * 8;
            short8 wf0 = *(const short8*)bp;
            short8 wf1 = *(const short8*)(bp + 512);
            int kc = kt * 32 + quad * 8;
#pragma unroll
            for (int mt = 0; mt < 4; ++mt) {
                short8 hf = *(const short8*)&h1b[(mt * 16 + col + 2 * tap) * 136 + kc];
                acc2[mt][0] = __builtin_amdgcn_mfma_f32_16x16x32_bf16(wf0, hf, acc2[mt][0], 0, 0, 0);
                acc2[mt][1] = __builtin_amdgcn_mfma_f32_16x16x32_bf16(wf1, hf, acc2[mt][1], 0, 0, 0);
            }
        }
    }
    // epilogue 2: h2 = gelu(y+bias)+h1 -> stage into h0s rows 0..63 (b64)
    {
        float4 bias[2];
        bias[0] = *reinterpret_cast<const float4*>(&conv_b[DM + cobase + quad * 4]);
        bias[1] = *reinterpret_cast<const float4*>(&conv_b[DM + cobase + 16 + quad * 4]);
#pragma unroll
        for (int mt = 0; mt < 4; ++mt) {
            int li = mt * 16 + col;
#pragma unroll
            for (int nt = 0; nt < 2; ++nt) {
                int co = cobase + nt * 16 + quad * 4;
                uint2 res = *reinterpret_cast<const uint2*>(
                    &h1b[(li + 4) * 136 + co]);
                float h0 = gelu_fast(acc2[mt][nt][0] + bias[nt].x) + blo(res.x);
                float h1 = gelu_fast(acc2[mt][nt][1] + bias[nt].y) + bhi(res.x);
                float h2v = gelu_fast(acc2[mt][nt][2] + bias[nt].z) + blo(res.y);
                float h3 = gelu_fast(acc2[mt][nt][3] + bias[nt].w) + bhi(res.y);
                uint2 pk;
                pk.x = pkbf(h0, h1);
                pk.y = pkbf(h2v, h3);
                *reinterpret_cast<uint2*>(&h0s[li * 136 + co]) = pk;
            }
        }
    }
    __syncthreads();

    // ---- coalesced h2 store ----
    {
        ushort_t* orow = h2 + (size_t)bn * ROWLEN + (size_t)l0 * 128;
#pragma unroll
        for (int i = 0; i < 4; ++i) {
            int q = threadIdx.x + 256 * i;
            int row = q >> 4, c8 = (q & 15) * 8;
            *(short8*)&orow[row * 128 + c8] = *(const short8*)&h0s[row * 136 + c8];
        }
    }
    // ---- z: 4 segment means over staged h2 tile (zb aliases h1b) ----
    {
        int d = threadIdx.x & 127, sg = threadIdx.x >> 7;
#pragma unroll
        for (int t = 0; t < 2; ++t) {
            int sl = sg + 2 * t;
            float a = 0.0f;
#pragma unroll
            for (int c = 0; c < SCL; ++c)
                a += bf2f(h0s[(sl * 16 + c) * 136 + d]);
            zb[sl * 128 + d] = a * (1.0f / 16.0f);
        }
    }
    __syncthreads();
    // ---- e1/e2: 4 segs x 2 mats x 8 ranks ----
    if (threadIdx.x < 64) {
        int sl = threadIdx.x >> 4;
        int which = (threadIdx.x >> 3) & 1;
        int r = threadIdx.x & 7;
        const float* w = which ? gw2 : gw1;
        float a = 0.0f;
        for (int d = 0; d < DM; ++d) a += zb[sl * 128 + d] * w[d * RNK + r];
        a += (which ? gb2 : gb1)[r];
        int s = chunk * 4 + sl;
        (which ? e2 : e1)[(((size_t)b * SEG + s) * NVAR + n) * RNK + r] = a;
    }
}

// ---------------- scores + softmax: 4 (b,s,n) rows per block ----------------
__global__ __launch_bounds__(256) void softmax_kernel(
    const float* __restrict__ e1, const float* __restrict__ e2,
    float* __restrict__ adj) {
    int gid = blockIdx.x * 4 + (threadIdx.x >> 6);  // row over B*S*N
    int m = threadIdx.x & 63;
    int n = gid & 63;
    int bs = gid >> 6;
    const float* e1p = e1 + ((size_t)bs * NVAR + n) * RNK;
    const float* e2p = e2 + ((size_t)bs * NVAR + m) * RNK;
    float sc = 0.0f;
#pragma unroll
    for (int r = 0; r < RNK; ++r) sc += e1p[r] * e2p[r];
    sc *= 0.35355339059327373f;  // 1/sqrt(8)
    float mx = sc;
    for (int off = 32; off; off >>= 1) mx = fmaxf(mx, __shfl_xor(mx, off, 64));
    float ex = __expf(sc - mx);
    float sm = ex;
    for (int off = 32; off; off >>= 1) sm += __shfl_xor(sm, off, 64);
    adj[((size_t)bs * NVAR + n) * NVAR + m] = ex * __builtin_amdgcn_rcpf(sm);
}

// ---------------- regularizer ----------------------------------------------
__global__ __launch_bounds__(256) void reg_kernel(
    const float* __restrict__ adj, float* __restrict__ regacc) {
    const int total = BATCH * (SEG - 1) * NVAR * NVAR;
    float sum = 0.0f;
    for (int idx = blockIdx.x * 256 + threadIdx.x; idx < total;
         idx += gridDim.x * 256) {
        int m = idx & 63;
        int n = (idx >> 6) & 63;
        int rest = idx >> 12;
        int sm1 = rest % 31;
        int b = rest / 31;
        int s = sm1 + 1;
        size_t i1 = (((size_t)b * SEG + s) * NVAR + n) * NVAR + m;
        sum += fabsf(adj[i1] - adj[i1 - NVAR * NVAR]);
    }
    for (int off = 32; off; off >>= 1) sum += __shfl_xor(sum, off, 64);
    __shared__ float wsum[4];
    int lane = threadIdx.x & 63, w = threadIdx.x >> 6;
    if (lane == 0) wsum[w] = sum;
    __syncthreads();
    if (threadIdx.x == 0)
        atomicAdd(regacc, wsum[0] + wsum[1] + wsum[2] + wsum[3]);
}

// ---------------- G GEMM (MFMA): bn-tile 64, register-prefetch pipeline -----
// grid (s=32, bnt=16) = 512 blocks (2/CU). Per wave: M32(bn) x N48(p).
// G layout: [s][b][p][m], m stores coalesced over lanes.
__global__ __launch_bounds__(256) void g_gemm(
    const ushort_t* __restrict__ h2, const float* __restrict__ head_w,
    float* __restrict__ G) {
    __shared__ __align__(16) ushort_t As[64 * 72];  // [bn][k]
    __shared__ __align__(16) ushort_t Bs[96 * 72];  // [p][k]
    int s = blockIdx.x;
    int bnt = blockIdx.y;
    int bn0 = bnt * 64;
    int lane = threadIdx.x & 63, wv = threadIdx.x >> 6;
    int quad = lane >> 4, col = lane & 15;
    int mh = wv & 1;   // bn half (32)
    int ph = wv >> 1;  // p half (48)

    // A staging map: thread -> (row 0..63, kq = (tid&3)*16), loads 16 shorts
    int arow = threadIdx.x >> 2, akq = (threadIdx.x & 3) * 16;
    const ushort_t* aptr =
        h2 + (size_t)(bn0 + arow) * ROWLEN + (size_t)s * 2048 + akq;
    // B staging map: i=0..2: q=tid+256i -> p0=(q%24)*4, k2=(q/24)*2
    const float* bbase = head_w + (size_t)s * 2048 * PRED;
    int bp0[3], bk2[3];
#pragma unroll
    for (int i = 0; i < 3; ++i) {
        int q = threadIdx.x + 256 * i;
        bp0[i] = (q % 24) * 4;
        bk2[i] = (q / 24) * 2;
    }

    f32x4 acc[3][2];  // [p-tile][bn-tile]
#pragma unroll
    for (int i = 0; i < 3; ++i)
#pragma unroll
        for (int j = 0; j < 2; ++j) acc[i][j] = (f32x4){0.f, 0.f, 0.f, 0.f};

    // ---- prefetch chunk 0 into regs ----
    short8 pa0 = *(const short8*)aptr;
    short8 pa1 = *(const short8*)(aptr + 8);
    float4 pb0[3], pb1[3];
#pragma unroll
    for (int i = 0; i < 3; ++i) {
        const float* src = bbase + (size_t)bk2[i] * PRED + bp0[i];
        pb0[i] = *reinterpret_cast<const float4*>(src);
        pb1[i] = *reinterpret_cast<const float4*>(src + PRED);
    }
    // store chunk 0 to LDS
    *(short8*)&As[arow * 72 + akq] = pa0;
    *(short8*)&As[arow * 72 + akq + 8] = pa1;
#pragma unroll
    for (int i = 0; i < 3; ++i) {
        *reinterpret_cast<unsigned int*>(&Bs[(bp0[i] + 0) * 72 + bk2[i]]) = pkbf(pb0[i].x, pb1[i].x);
        *reinterpret_cast<unsigned int*>(&Bs[(bp0[i] + 1) * 72 + bk2[i]]) = pkbf(pb0[i].y, pb1[i].y);
        *reinterpret_cast<unsigned int*>(&Bs[(bp0[i] + 2) * 72 + bk2[i]]) = pkbf(pb0[i].z, pb1[i].z);
        *reinterpret_cast<unsigned int*>(&Bs[(bp0[i] + 3) * 72 + bk2[i]]) = pkbf(pb0[i].w, pb1[i].w);
    }
    __syncthreads();

    for (int kt = 0; kt < 32; ++kt) {
        // issue next chunk's global loads (in flight during MFMA stage)
        if (kt < 31) {
            const ushort_t* ap = aptr + (kt + 1) * 64;
            pa0 = *(const short8*)ap;
            pa1 = *(const short8*)(ap + 8);
#pragma unroll
            for (int i = 0; i < 3; ++i) {
                const float* src =
                    bbase + (size_t)((kt + 1) * 64 + bk2[i]) * PRED + bp0[i];
                pb0[i] = *reinterpret_cast<const float4*>(src);
                pb1[i] = *reinterpret_cast<const float4*>(src + PRED);
            }
        }
        // MFMA on current LDS chunk
#pragma unroll
        for (int kk = 0; kk < 2; ++kk) {
            int kc = kk * 32 + quad * 8;
            short8 pfr[3];
#pragma unroll
            for (int i = 0; i < 3; ++i)
                pfr[i] = *(const short8*)&Bs[(ph * 48 + i * 16 + col) * 72 + kc];
#pragma unroll
            for (int j = 0; j < 2; ++j) {
                short8 bnfr = *(const short8*)&As[(mh * 32 + j * 16 + col) * 72 + kc];
#pragma unroll
                for (int i = 0; i < 3; ++i)
                    acc[i][j] = __builtin_amdgcn_mfma_f32_16x16x32_bf16(pfr[i], bnfr, acc[i][j], 0, 0, 0);
            }
        }
        __syncthreads();
        if (kt < 31) {
            *(short8*)&As[arow * 72 + akq] = pa0;
            *(short8*)&As[arow * 72 + akq + 8] = pa1;
#pragma unroll
            for (int i = 0; i < 3; ++i) {
                *reinterpret_cast<unsigned int*>(&Bs[(bp0[i] + 0) * 72 + bk2[i]]) = pkbf(pb0[i].x, pb1[i].x);
                *reinterpret_cast<unsigned int*>(&Bs[(bp0[i] + 1) * 72 + bk2[i]]) = pkbf(pb0[i].y, pb1[i].y);
                *reinterpret_cast<unsigned int*>(&Bs[(bp0[i] + 2) * 72 + bk2[i]]) = pkbf(pb0[i].z, pb1[i].z);
                *reinterpret_cast<unsigned int*>(&Bs[(bp0[i] + 3) * 72 + bk2[i]]) = pkbf(pb0[i].w, pb1[i].w);
            }
            __syncthreads();
        }
    }
    // store G[s][b][p][m]: lanes (col) -> consecutive m ==> coalesced
    int b = bnt;
#pragma unroll
    for (int i = 0; i < 3; ++i)
#pragma unroll
        for (int j = 0; j < 2; ++j)
#pragma unroll
            for (int r = 0; r < 4; ++r) {
                int p = ph * 48 + i * 16 + quad * 4 + r;
                int m = mh * 32 + j * 16 + col;
                G[(((size_t)s * BATCH + b) * PRED + p) * NVAR + m] = acc[i][j][r];
            }
}

// ---------------- out partials: (b, sg of 8, n-half of 32) ------------------
__global__ __launch_bounds__(256) void out_partial(
    const float* __restrict__ adj, const float* __restrict__ G,
    float* __restrict__ partial) {
    __shared__ float adjn[32][65];
    __shared__ float Gs[96][65];
    int b = blockIdx.x, sg = blockIdx.y, nh = blockIdx.z;
    int pg = threadIdx.x >> 4;   // p = pg*6 + j
    int ng = threadIdx.x & 15;   // n = nh*32 + ng*2 + i

    float acc[6][2];
#pragma unroll
    for (int j = 0; j < 6; ++j) { acc[j][0] = 0.f; acc[j][1] = 0.f; }

    for (int ss = 0; ss < 8; ++ss) {
        int s = sg * 8 + ss;
#pragma unroll
        for (int i = 0; i < 2; ++i) {
            int q = threadIdx.x + 256 * i;  // 0..511 -> 32 rows x 16 m4
            int row = q >> 4, mq = (q & 15) * 4;
            float4 v = *reinterpret_cast<const float4*>(
                &adj[(((size_t)b * SEG + s) * NVAR + nh * 32 + row) * NVAR + mq]);
            adjn[row][mq + 0] = v.x; adjn[row][mq + 1] = v.y;
            adjn[row][mq + 2] = v.z; adjn[row][mq + 3] = v.w;
        }
#pragma unroll
        for (int i = 0; i < 6; ++i) {
            int q = threadIdx.x + 256 * i;
            int row = q >> 4, mq = (q & 15) * 4;
            float4 v = *reinterpret_cast<const float4*>(
                &G[(((size_t)s * BATCH + b) * PRED + row) * NVAR + mq]);
            Gs[row][mq + 0] = v.x; Gs[row][mq + 1] = v.y;
            Gs[row][mq + 2] = v.z; Gs[row][mq + 3] = v.w;
        }
        __syncthreads();
#pragma unroll 4
        for (int m = 0; m < 64; ++m) {
            float a0 = adjn[ng * 2 + 0][m];
            float a1 = adjn[ng * 2 + 1][m];
#pragma unroll
            for (int j = 0; j < 6; ++j) {
                float g = Gs[pg * 6 + j][m];
                acc[j][0] += g * a0;
                acc[j][1] += g * a1;
            }
        }
        __syncthreads();
    }
#pragma unroll
    for (int j = 0; j < 6; ++j)
#pragma unroll
        for (int i = 0; i < 2; ++i) {
            int p = pg * 6 + j, n = nh * 32 + ng * 2 + i;
            partial[(((size_t)sg * BATCH + b) * PRED + p) * NVAR + n] = acc[j][i];
        }
}

// ---------------- reduce partials + head_b (float4); write reg scalar -------
__global__ __launch_bounds__(256) void out_reduce(
    const float* __restrict__ partial, const float* __restrict__ head_b,
    const float* __restrict__ regacc, float* __restrict__ out, int out_size) {
    int i4 = blockIdx.x * 256 + threadIdx.x;  // 0..24575 float4s (98304 floats)
    int p = (i4 >> 4) % PRED;
    float hb = head_b[p];
    float4 a = make_float4(hb, hb, hb, hb);
    const int stride4 = BATCH * PRED * NVAR / 4;
    const float4* p4 = reinterpret_cast<const float4*>(partial);
#pragma unroll
    for (int sg = 0; sg < 4; ++sg) {
        float4 v = p4[sg * stride4 + i4];
        a.x += v.x; a.y += v.y; a.z += v.z; a.w += v.w;
    }
    reinterpret_cast<float4*>(out)[i4] = a;
    if (i4 == 0) out[out_size - 1] = regacc[0] * (1.0f / 65536.0f);
}

extern "C" void kernel_launch(void* const* d_in, const int* in_sizes, int n_in,
                              void* d_out, int out_size, void* d_ws,
                              size_t ws_size, hipStream_t stream) {
    const float* x_enc  = (const float*)d_in[0];
    const float* w_emb  = (const float*)d_in[4];
    const float* b_emb  = (const float*)d_in[5];
    const float* conv_w = (const float*)d_in[6];
    const float* conv_b = (const float*)d_in[7];
    const float* gg_w1  = (const float*)d_in[8];
    const float* gg_b1  = (const float*)d_in[9];
    const float* gg_w2  = (const float*)d_in[10];
    const float* gg_b2  = (const float*)d_in[11];
    const float* head_w = (const float*)d_in[12];
    const float* head_b = (const float*)d_in[13];
    float* out = (float*)d_out;

    // workspace: 157,286,404 B total (proven). WTf overlaps adj; partial
    // overlaps e1/e2 (each dead before the overlapper writes).
    char* ws = (char*)d_ws;
    ushort_t* h2   = (ushort_t*)(ws);                   // 134,217,728
    float* G       = (float*)(ws + 134217728);          //  12,582,912
    float* e1      = (float*)(ws + 146800640);          //   1,048,576
    float* e2      = (float*)(ws + 147849216);          //   1,048,576
    float* partial = (float*)(ws + 146800640);          //   1,572,864 (overlaps e1/e2)
    float* adj     = (float*)(ws + 148897792);          //   8,388,608
    ushort_t* WTf  = (ushort_t*)(ws + 148897792);       //     196,608 (overlaps adj)
    float* regacc  = (float*)(ws + 157286400);          //           4

    wt_prep<<<dim3(6, 128), 128, 0, stream>>>(conv_w, WTf, regacc);
    tcn_mfma<<<dim3(BN, SEQ / 64), 256, 0, stream>>>(
        x_enc, w_emb, b_emb, WTf, conv_b,
        gg_w1, gg_b1, gg_w2, gg_b2, h2, e1, e2);
    softmax_kernel<<<BATCH * SEG * NVAR / 4, 256, 0, stream>>>(e1, e2, adj);
    reg_kernel<<<512, 256, 0, stream>>>(adj, regacc);
    g_gemm<<<dim3(SEG, BN / 64), 256, 0, stream>>>(h2, head_w, G);
    out_partial<<<dim3(BATCH, 4, 2), 256, 0, stream>>>(adj, G, partial);
    out_reduce<<<BATCH * PRED * NVAR / 1024, 256, 0, stream>>>(
        partial, head_b, regacc, out, out_size);
}

// Round 11
// 383.102 us; speedup vs baseline: 24.1196x; 1.0777x over previous
//
#include <hip/hip_runtime.h>
#include <hip/hip_bf16.h>

// Model_81956565942963: TCN + low-rank dynamic graph + linear head.
// B=16, L=512, N=64, D=128, S=32 x 16, r=8, P=96. f32 in/out.
// R11 (tail round; tcn_mfma byte-identical to R9/R10):
//  - g_gemm split-K x2 -> 1024 blocks (4/CU) for 2x MLP on the 134MB h2
//    stream; atomicAdd into memset-zeroed G (hipMemsetAsync overlaps tcn).
//  - reg_kernel fused into out_partial (adj[s-1] read during staging).
//  - out_partial: 16 s-groups x 2 n-halves x 16 b = 512 blocks; partial
//    buffer (6.3MB) in the h2 slot (dead after g_gemm).

#define BATCH 16
#define SEQ 512
#define NVAR 64
#define DM 128
#define SEG 32
#define SCL 16
#define RNK 8
#define PRED 96
#define BN (BATCH * NVAR)   // 1024
#define ROWLEN (SEQ * DM)   // 65536

typedef unsigned short ushort_t;
typedef __attribute__((ext_vector_type(8))) short short8;   // 8 bf16
typedef __attribute__((ext_vector_type(4))) float f32x4;

__device__ inline float bf2f(ushort_t u) {
    union { unsigned int i; float f; } x;
    x.i = ((unsigned int)u) << 16;
    return x.f;
}
__device__ inline ushort_t f2bf(float f) {
    union { float f; unsigned int i; } u;
    u.f = f;
    unsigned int x = u.i;
    return (ushort_t)((x + 0x7fffu + ((x >> 16) & 1u)) >> 16);  // RNE
}
__device__ inline unsigned int pkbf(float a, float b) {  // packed bf16 pair
    __hip_bfloat162 h = __float22bfloat162_rn(make_float2(a, b));
    union { __hip_bfloat162 h2; unsigned int u; } c;
    c.h2 = h;
    return c.u;
}
__device__ inline float blo(unsigned int u) {
    union { unsigned int i; float f; } x;
    x.i = u << 16;
    return x.f;
}
__device__ inline float bhi(unsigned int u) {
    union { unsigned int i; float f; } x;
    x.i = u & 0xFFFF0000u;
    return x.f;
}
// gelu(x) = x * sigmoid(2t); rcp is v_rcp_f32 (1 inst) not the div sequence
__device__ inline float gelu_fast(float x) {
    float t = 0.7978845608028654f * x * (1.0f + 0.044715f * x * x);
    float e = __expf(-2.0f * t);
    return x * __builtin_amdgcn_rcpf(1.0f + e);
}

// ---------------- conv-weight prep: frag-major bf16 (+ regacc zero) ---------
__global__ __launch_bounds__(128) void wt_prep(
    const float* __restrict__ conv_w, ushort_t* __restrict__ WTf,
    float* __restrict__ regacc) {
    if (blockIdx.x == 0 && blockIdx.y == 0 && threadIdx.x == 0) regacc[0] = 0.f;
    int lt = blockIdx.x;    // 0..5 (layer*3+tap)
    int ci = blockIdx.y;    // 0..127
    int co = threadIdx.x;   // 0..127
    int kt = ci >> 5, quad = (ci >> 3) & 3, j = ci & 7;
    int ng = co >> 4, col = co & 15;
    int lane = quad * 16 + col;
    WTf[((((size_t)lt * 4 + kt) * 8 + ng) * 64 + lane) * 8 + j] =
        f2bf(conv_w[(size_t)lt * 16384 + (size_t)ci * 128 + co]);
}

// ---------------- fused TCN (MFMA) + segment means + e1/e2 ------------------
__global__ __launch_bounds__(256) void tcn_mfma(
    const float* __restrict__ x, const float* __restrict__ w_emb,
    const float* __restrict__ b_emb, const ushort_t* __restrict__ WTf,
    const float* __restrict__ conv_b,
    const float* __restrict__ gw1, const float* __restrict__ gb1,
    const float* __restrict__ gw2, const float* __restrict__ gb2,
    ushort_t* __restrict__ h2, float* __restrict__ e1, float* __restrict__ e2) {
    __shared__ __align__(16) ushort_t h0s[82 * 136];  // embed, row = li+18
    __shared__ __align__(16) ushort_t h1b[68 * 136];  // conv1 out, row = li+4
    float* zb = reinterpret_cast<float*>(h1b);        // alias: h1b dead by then

    int bn = blockIdx.x;
    int b = bn >> 6, n = bn & 63;
    int chunk = blockIdx.y;
    int l0 = chunk * 64;

    // ---- embed: 82 rows x 128 d (bf16), packed writes ----
    {
        const float* xb = x + (size_t)b * SEQ * NVAR + n;
#pragma unroll
        for (int i = 0; i < 21; ++i) {
            int q = threadIdx.x + 256 * i;
            if (q < 82 * 64) {
                int row = q >> 6, dp = (q & 63) * 2;
                int l = l0 + row - 18;
                unsigned int pk = 0;
                if (l >= 0) {
                    float xv = xb[(size_t)l * NVAR];
                    float2 wv2 = *reinterpret_cast<const float2*>(&w_emb[dp]);
                    float2 bv2 = *reinterpret_cast<const float2*>(&b_emb[dp]);
                    pk = pkbf(xv * wv2.x + bv2.x, xv * wv2.y + bv2.y);
                }
                *reinterpret_cast<unsigned int*>(&h0s[row * 136 + dp]) = pk;
            }
        }
    }
    __syncthreads();

    int lane = threadIdx.x & 63;
    int wv = threadIdx.x >> 6;
    int quad = lane >> 4;
    int col = lane & 15;
    int cobase = wv * 32;

    // ---- layer 1: D[m=co][n=li]; acc1[mt=li-tile][nt=co-tile] ----
    f32x4 acc1[5][2];
#pragma unroll
    for (int mt = 0; mt < 5; ++mt)
#pragma unroll
        for (int nt = 0; nt < 2; ++nt)
            acc1[mt][nt] = (f32x4){0.f, 0.f, 0.f, 0.f};

#pragma unroll
    for (int tap = 0; tap < 3; ++tap) {
#pragma unroll
        for (int kt = 0; kt < 4; ++kt) {
            const ushort_t* bp =
                WTf + ((((size_t)tap * 4 + kt) * 8 + wv * 2) * 64 + lane) * 8;
            short8 wf0 = *(const short8*)bp;
            short8 wf1 = *(const short8*)(bp + 512);
            int kc = kt * 32 + quad * 8;
#pragma unroll
            for (int mt = 0; mt < 5; ++mt) {
                short8 hf = *(const short8*)&h0s[(mt * 16 + col + tap) * 136 + kc];
                acc1[mt][0] = __builtin_amdgcn_mfma_f32_16x16x32_bf16(wf0, hf, acc1[mt][0], 0, 0, 0);
                acc1[mt][1] = __builtin_amdgcn_mfma_f32_16x16x32_bf16(wf1, hf, acc1[mt][1], 0, 0, 0);
            }
        }
    }
    // epilogue 1: lane holds li = mt*16+col-16, co = cobase+nt*16+quad*4+r
    {
        float4 bias[2];
        bias[0] = *reinterpret_cast<const float4*>(&conv_b[cobase + quad * 4]);
        bias[1] = *reinterpret_cast<const float4*>(&conv_b[cobase + 16 + quad * 4]);
#pragma unroll
        for (int mt = 0; mt < 5; ++mt) {
            int li = mt * 16 + col - 16;
            if (li >= -4) {
#pragma unroll
                for (int nt = 0; nt < 2; ++nt) {
                    int co = cobase + nt * 16 + quad * 4;
                    uint2 pk;
                    if (l0 + li < 0) {
                        pk.x = 0u; pk.y = 0u;
                    } else {
                        uint2 res = *reinterpret_cast<const uint2*>(
                            &h0s[(mt * 16 + col + 2) * 136 + co]);
                        float h0 = gelu_fast(acc1[mt][nt][0] + bias[nt].x) + blo(res.x);
                        float h1 = gelu_fast(acc1[mt][nt][1] + bias[nt].y) + bhi(res.x);
                        float h2v = gelu_fast(acc1[mt][nt][2] + bias[nt].z) + blo(res.y);
                        float h3 = gelu_fast(acc1[mt][nt][3] + bias[nt].w) + bhi(res.y);
                        pk.x = pkbf(h0, h1);
                        pk.y = pkbf(h2v, h3);
                    }
                    *reinterpret_cast<uint2*>(&h1b[(li + 4) * 136 + co]) = pk;
                }
            }
        }
    }
    __syncthreads();

    // ---- layer 2: li = mt*16+col; tap t reads h1b row li+2t ----
    f32x4 acc2[4][2];
#pragma unroll
    for (int mt = 0; mt < 4; ++mt)
#pragma unroll
        for (int nt = 0; nt < 2; ++nt)
            acc2[mt][nt] = (f32x4){0.f, 0.f, 0.f, 0.f};

#pragma unroll
    for (int tap = 0; tap < 3; ++tap) {
#pragma unroll
        for (int kt = 0; kt < 4; ++kt) {
            const ushort_t* bp =
                WTf + ((((size_t)(3 + tap) * 4 + kt) * 8 + wv * 2) * 64 + lane) * 8;
            short8 wf0 = *(const short8*)bp;
            short8 wf1 = *(const short8*)(bp + 512);
            int kc = kt * 32 + quad * 8;
#pragma unroll
            for (int mt = 0; mt < 4; ++mt) {
                short8 hf = *(const short8*)&h1b[(mt * 16 + col + 2 * tap) * 136 + kc];
                acc2[mt][0] = __builtin_amdgcn_mfma_f32_16x16x32_bf16(wf0, hf, acc2[mt][0], 0, 0, 0);
                acc2[mt][1] = __builtin_amdgcn_mfma_f32_16x16x32_bf16(wf1, hf, acc2[mt][1], 0, 0, 0);
            }
        }
    }
    // epilogue 2: h2 = gelu(y+bias)+h1 -> stage into h0s rows 0..63 (b64)
    {
        float4 bias[2];
        bias[0] = *reinterpret_cast<const float4*>(&conv_b[DM + cobase + quad * 4]);
        bias[1] = *reinterpret_cast<const float4*>(&conv_b[DM + cobase + 16 + quad * 4]);
#pragma unroll
        for (int mt = 0; mt < 4; ++mt) {
            int li = mt * 16 + col;
#pragma unroll
            for (int nt = 0; nt < 2; ++nt) {
                int co = cobase + nt * 16 + quad * 4;
                uint2 res = *reinterpret_cast<const uint2*>(
                    &h1b[(li + 4) * 136 + co]);
                float h0 = gelu_fast(acc2[mt][nt][0] + bias[nt].x) + blo(res.x);
                float h1 = gelu_fast(acc2[mt][nt][1] + bias[nt].y) + bhi(res.x);
                float h2v = gelu_fast(acc2[mt][nt][2] + bias[nt].z) + blo(res.y);
                float h3 = gelu_fast(acc2[mt][nt][3] + bias[nt].w) + bhi(res.y);
                uint2 pk;
                pk.x = pkbf(h0, h1);
                pk.y = pkbf(h2v, h3);
                *reinterpret_cast<uint2*>(&h0s[li * 136 + co]) = pk;
            }
        }
    }
    __syncthreads();

    // ---- coalesced h2 store ----
    {
        ushort_t* orow = h2 + (size_t)bn * ROWLEN + (size_t)l0 * 128;
#pragma unroll
        for (int i = 0; i < 4; ++i) {
            int q = threadIdx.x + 256 * i;
            int row = q >> 4, c8 = (q & 15) * 8;
            *(short8*)&orow[row * 128 + c8] = *(const short8*)&h0s[row * 136 + c8];
        }
    }
    // ---- z: 4 segment means over staged h2 tile (zb aliases h1b) ----
    {
        int d = threadIdx.x & 127, sg = threadIdx.x >> 7;
#pragma unroll
        for (int t = 0; t < 2; ++t) {
            int sl = sg + 2 * t;
            float a = 0.0f;
#pragma unroll
            for (int c = 0; c < SCL; ++c)
                a += bf2f(h0s[(sl * 16 + c) * 136 + d]);
            zb[sl * 128 + d] = a * (1.0f / 16.0f);
        }
    }
    __syncthreads();
    // ---- e1/e2: 4 segs x 2 mats x 8 ranks ----
    if (threadIdx.x < 64) {
        int sl = threadIdx.x >> 4;
        int which = (threadIdx.x >> 3) & 1;
        int r = threadIdx.x & 7;
        const float* w = which ? gw2 : gw1;
        float a = 0.0f;
        for (int d = 0; d < DM; ++d) a += zb[sl * 128 + d] * w[d * RNK + r];
        a += (which ? gb2 : gb1)[r];
        int s = chunk * 4 + sl;
        (which ? e2 : e1)[(((size_t)b * SEG + s) * NVAR + n) * RNK + r] = a;
    }
}

// ---------------- scores + softmax: 4 (b,s,n) rows per block ----------------
__global__ __launch_bounds__(256) void softmax_kernel(
    const float* __restrict__ e1, const float* __restrict__ e2,
    float* __restrict__ adj) {
    int gid = blockIdx.x * 4 + (threadIdx.x >> 6);  // row over B*S*N
    int m = threadIdx.x & 63;
    int n = gid & 63;
    int bs = gid >> 6;
    const float* e1p = e1 + ((size_t)bs * NVAR + n) * RNK;
    const float* e2p = e2 + ((size_t)bs * NVAR + m) * RNK;
    float sc = 0.0f;
#pragma unroll
    for (int r = 0; r < RNK; ++r) sc += e1p[r] * e2p[r];
    sc *= 0.35355339059327373f;  // 1/sqrt(8)
    float mx = sc;
    for (int off = 32; off; off >>= 1) mx = fmaxf(mx, __shfl_xor(mx, off, 64));
    float ex = __expf(sc - mx);
    float sm = ex;
    for (int off = 32; off; off >>= 1) sm += __shfl_xor(sm, off, 64);
    adj[((size_t)bs * NVAR + n) * NVAR + m] = ex * __builtin_amdgcn_rcpf(sm);
}

// ---------------- G GEMM (MFMA): split-K x2, register-prefetch pipeline -----
// grid (s=32, b=16, kh=2) = 1024 blocks (4/CU). Per wave: M32(bn) x N48(p).
// Accumulates into zeroed G via atomicAdd. G layout: [s][b][p][m].
__global__ __launch_bounds__(256) void g_gemm(
    const ushort_t* __restrict__ h2, const float* __restrict__ head_w,
    float* __restrict__ G) {
    __shared__ __align__(16) ushort_t As[64 * 72];  // [bn][k]
    __shared__ __align__(16) ushort_t Bs[96 * 72];  // [p][k]
    int s = blockIdx.x;
    int bnt = blockIdx.y;
    int kh = blockIdx.z;
    int bn0 = bnt * 64;
    int kbase = kh * 1024;
    int lane = threadIdx.x & 63, wv = threadIdx.x >> 6;
    int quad = lane >> 4, col = lane & 15;
    int mh = wv & 1;   // bn half (32)
    int ph = wv >> 1;  // p half (48)

    int arow = threadIdx.x >> 2, akq = (threadIdx.x & 3) * 16;
    const ushort_t* aptr =
        h2 + (size_t)(bn0 + arow) * ROWLEN + (size_t)s * 2048 + kbase + akq;
    const float* bbase = head_w + ((size_t)s * 2048 + kbase) * PRED;
    int bp0[3], bk2[3];
#pragma unroll
    for (int i = 0; i < 3; ++i) {
        int q = threadIdx.x + 256 * i;
        bp0[i] = (q % 24) * 4;
        bk2[i] = (q / 24) * 2;
    }

    f32x4 acc[3][2];  // [p-tile][bn-tile]
#pragma unroll
    for (int i = 0; i < 3; ++i)
#pragma unroll
        for (int j = 0; j < 2; ++j) acc[i][j] = (f32x4){0.f, 0.f, 0.f, 0.f};

    // ---- prefetch chunk 0 ----
    short8 pa0 = *(const short8*)aptr;
    short8 pa1 = *(const short8*)(aptr + 8);
    float4 pb0[3], pb1[3];
#pragma unroll
    for (int i = 0; i < 3; ++i) {
        const float* src = bbase + (size_t)bk2[i] * PRED + bp0[i];
        pb0[i] = *reinterpret_cast<const float4*>(src);
        pb1[i] = *reinterpret_cast<const float4*>(src + PRED);
    }
    *(short8*)&As[arow * 72 + akq] = pa0;
    *(short8*)&As[arow * 72 + akq + 8] = pa1;
#pragma unroll
    for (int i = 0; i < 3; ++i) {
        *reinterpret_cast<unsigned int*>(&Bs[(bp0[i] + 0) * 72 + bk2[i]]) = pkbf(pb0[i].x, pb1[i].x);
        *reinterpret_cast<unsigned int*>(&Bs[(bp0[i] + 1) * 72 + bk2[i]]) = pkbf(pb0[i].y, pb1[i].y);
        *reinterpret_cast<unsigned int*>(&Bs[(bp0[i] + 2) * 72 + bk2[i]]) = pkbf(pb0[i].z, pb1[i].z);
        *reinterpret_cast<unsigned int*>(&Bs[(bp0[i] + 3) * 72 + bk2[i]]) = pkbf(pb0[i].w, pb1[i].w);
    }
    __syncthreads();

    for (int kt = 0; kt < 16; ++kt) {
        if (kt < 15) {
            const ushort_t* ap = aptr + (kt + 1) * 64;
            pa0 = *(const short8*)ap;
            pa1 = *(const short8*)(ap + 8);
#pragma unroll
            for (int i = 0; i < 3; ++i) {
                const float* src =
                    bbase + (size_t)((kt + 1) * 64 + bk2[i]) * PRED + bp0[i];
                pb0[i] = *reinterpret_cast<const float4*>(src);
                pb1[i] = *reinterpret_cast<const float4*>(src + PRED);
            }
        }
#pragma unroll
        for (int kk = 0; kk < 2; ++kk) {
            int kc = kk * 32 + quad * 8;
            short8 pfr[3];
#pragma unroll
            for (int i = 0; i < 3; ++i)
                pfr[i] = *(const short8*)&Bs[(ph * 48 + i * 16 + col) * 72 + kc];
#pragma unroll
            for (int j = 0; j < 2; ++j) {
                short8 bnfr = *(const short8*)&As[(mh * 32 + j * 16 + col) * 72 + kc];
#pragma unroll
                for (int i = 0; i < 3; ++i)
                    acc[i][j] = __builtin_amdgcn_mfma_f32_16x16x32_bf16(pfr[i], bnfr, acc[i][j], 0, 0, 0);
            }
        }
        __syncthreads();
        if (kt < 15) {
            *(short8*)&As[arow * 72 + akq] = pa0;
            *(short8*)&As[arow * 72 + akq + 8] = pa1;
#pragma unroll
            for (int i = 0; i < 3; ++i) {
                *reinterpret_cast<unsigned int*>(&Bs[(bp0[i] + 0) * 72 + bk2[i]]) = pkbf(pb0[i].x, pb1[i].x);
                *reinterpret_cast<unsigned int*>(&Bs[(bp0[i] + 1) * 72 + bk2[i]]) = pkbf(pb0[i].y, pb1[i].y);
                *reinterpret_cast<unsigned int*>(&Bs[(bp0[i] + 2) * 72 + bk2[i]]) = pkbf(pb0[i].z, pb1[i].z);
                *reinterpret_cast<unsigned int*>(&Bs[(bp0[i] + 3) * 72 + bk2[i]]) = pkbf(pb0[i].w, pb1[i].w);
            }
            __syncthreads();
        }
    }
    // atomic accumulate G[s][b][p][m] (two kh blocks per output)
    int b = bnt;
#pragma unroll
    for (int i = 0; i < 3; ++i)
#pragma unroll
        for (int j = 0; j < 2; ++j)
#pragma unroll
            for (int r = 0; r < 4; ++r) {
                int p = ph * 48 + i * 16 + quad * 4 + r;
                int m = mh * 32 + j * 16 + col;
                atomicAdd(&G[(((size_t)s * BATCH + b) * PRED + p) * NVAR + m],
                          acc[i][j][r]);
            }
}

// ---------------- out partials (+ fused adjacency regularizer) --------------
// grid (b=16, sg=16, nh=2); each block: 2 s values, 32 n rows, all m.
// partial[sg][b][p][n] = sum_{s in sg} sum_m adj[b,s,n,m] * G[s,b,p,m]
__global__ __launch_bounds__(256) void out_partial(
    const float* __restrict__ adj, const float* __restrict__ G,
    float* __restrict__ partial, float* __restrict__ regacc) {
    __shared__ float adjn[32][65];
    __shared__ float Gs[96][65];
    __shared__ float wsum[4];
    int b = blockIdx.x, sg = blockIdx.y, nh = blockIdx.z;
    int pg = threadIdx.x >> 4;   // p = pg*6 + j
    int ng = threadIdx.x & 15;   // n = nh*32 + ng*2 + i

    float acc[6][2];
#pragma unroll
    for (int j = 0; j < 6; ++j) { acc[j][0] = 0.f; acc[j][1] = 0.f; }
    float regsum = 0.0f;

#pragma unroll
    for (int ss = 0; ss < 2; ++ss) {
        int s = sg * 2 + ss;
#pragma unroll
        for (int i = 0; i < 2; ++i) {
            int q = threadIdx.x + 256 * i;  // 0..511 -> 32 rows x 16 m4
            int row = q >> 4, mq = (q & 15) * 4;
            const float* ap =
                &adj[(((size_t)b * SEG + s) * NVAR + nh * 32 + row) * NVAR + mq];
            float4 v = *reinterpret_cast<const float4*>(ap);
            adjn[row][mq + 0] = v.x; adjn[row][mq + 1] = v.y;
            adjn[row][mq + 2] = v.z; adjn[row][mq + 3] = v.w;
            if (s > 0) {  // fused regularizer term |adj_s - adj_{s-1}|
                float4 pv = *reinterpret_cast<const float4*>(ap - NVAR * NVAR);
                regsum += fabsf(v.x - pv.x) + fabsf(v.y - pv.y) +
                          fabsf(v.z - pv.z) + fabsf(v.w - pv.w);
            }
        }
#pragma unroll
        for (int i = 0; i < 6; ++i) {
            int q = threadIdx.x + 256 * i;
            int row = q >> 4, mq = (q & 15) * 4;
            float4 v = *reinterpret_cast<const float4*>(
                &G[(((size_t)s * BATCH + b) * PRED + row) * NVAR + mq]);
            Gs[row][mq + 0] = v.x; Gs[row][mq + 1] = v.y;
            Gs[row][mq + 2] = v.z; Gs[row][mq + 3] = v.w;
        }
        __syncthreads();
#pragma unroll 4
        for (int m = 0; m < 64; ++m) {
            float a0 = adjn[ng * 2 + 0][m];
            float a1 = adjn[ng * 2 + 1][m];
#pragma unroll
            for (int j = 0; j < 6; ++j) {
                float g = Gs[pg * 6 + j][m];
                acc[j][0] += g * a0;
                acc[j][1] += g * a1;
            }
        }
        __syncthreads();
    }
#pragma unroll
    for (int j = 0; j < 6; ++j)
#pragma unroll
        for (int i = 0; i < 2; ++i) {
            int p = pg * 6 + j, n = nh * 32 + ng * 2 + i;
            partial[(((size_t)sg * BATCH + b) * PRED + p) * NVAR + n] = acc[j][i];
        }
    // block-reduce regsum -> one atomic
    for (int off = 32; off; off >>= 1) regsum += __shfl_xor(regsum, off, 64);
    int lane = threadIdx.x & 63, w = threadIdx.x >> 6;
    if (lane == 0) wsum[w] = regsum;
    __syncthreads();
    if (threadIdx.x == 0)
        atomicAdd(regacc, wsum[0] + wsum[1] + wsum[2] + wsum[3]);
}

// ---------------- reduce 16 partials + head_b (float4); write reg -----------
__global__ __launch_bounds__(256) void out_reduce(
    const float* __restrict__ partial, const float* __restrict__ head_b,
    const float* __restrict__ regacc, float* __restrict__ out, int out_size) {
    int i4 = blockIdx.x * 256 + threadIdx.x;  // 0..24575 float4s
    int p = (i4 >> 4) % PRED;
    float hb = head_b[p];
    float4 a = make_float4(hb, hb, hb, hb);
    const int stride4 = BATCH * PRED * NVAR / 4;
    const float4* p4 = reinterpret_cast<const float4*>(partial);
#pragma unroll
    for (int sg = 0; sg < 16; ++sg) {
        float4 v = p4[sg * stride4 + i4];
        a.x += v.x; a.y += v.y; a.z += v.z; a.w += v.w;
    }
    reinterpret_cast<float4*>(out)[i4] = a;
    if (i4 == 0) out[out_size - 1] = regacc[0] * (1.0f / 65536.0f);
}

extern "C" void kernel_launch(void* const* d_in, const int* in_sizes, int n_in,
                              void* d_out, int out_size, void* d_ws,
                              size_t ws_size, hipStream_t stream) {
    const float* x_enc  = (const float*)d_in[0];
    const float* w_emb  = (const float*)d_in[4];
    const float* b_emb  = (const float*)d_in[5];
    const float* conv_w = (const float*)d_in[6];
    const float* conv_b = (const float*)d_in[7];
    const float* gg_w1  = (const float*)d_in[8];
    const float* gg_b1  = (const float*)d_in[9];
    const float* gg_w2  = (const float*)d_in[10];
    const float* gg_b2  = (const float*)d_in[11];
    const float* head_w = (const float*)d_in[12];
    const float* head_b = (const float*)d_in[13];
    float* out = (float*)d_out;

    // workspace: 157,286,404 B total (proven). WTf overlaps adj (dead before
    // softmax); partial overlaps h2 (dead after g_gemm).
    char* ws = (char*)d_ws;
    ushort_t* h2   = (ushort_t*)(ws);                   // 134,217,728
    float* partial = (float*)(ws);                      //   6,291,456 (overlaps h2)
    float* G       = (float*)(ws + 134217728);          //  12,582,912
    float* e1      = (float*)(ws + 146800640);          //   1,048,576
    float* e2      = (float*)(ws + 147849216);          //   1,048,576
    float* adj     = (float*)(ws + 148897792);          //   8,388,608
    ushort_t* WTf  = (ushort_t*)(ws + 148897792);       //     196,608 (overlaps adj)
    float* regacc  = (float*)(ws + 157286400);          //           4

    hipMemsetAsync(G, 0, 12582912, stream);  // zero G for split-K atomics
    wt_prep<<<dim3(6, 128), 128, 0, stream>>>(conv_w, WTf, regacc);
    tcn_mfma<<<dim3(BN, SEQ / 64), 256, 0, stream>>>(
        x_enc, w_emb, b_emb, WTf, conv_b,
        gg_w1, gg_b1, gg_w2, gg_b2, h2, e1, e2);
    softmax_kernel<<<BATCH * SEG * NVAR / 4, 256, 0, stream>>>(e1, e2, adj);
    g_gemm<<<dim3(SEG, BATCH, 2), 256, 0, stream>>>(h2, head_w, G);
    out_partial<<<dim3(BATCH, 16, 2), 256, 0, stream>>>(adj, G, partial, regacc);
    out_reduce<<<BATCH * PRED * NVAR / 1024, 256, 0, stream>>>(
        partial, head_b, regacc, out, out_size);
}

// Round 12
// 364.147 us; speedup vs baseline: 25.3751x; 1.0521x over previous
//
#include <hip/hip_runtime.h>
#include <hip/hip_bf16.h>

// Model_81956565942963: TCN + low-rank dynamic graph + linear head.
// B=16, L=512, N=64, D=128, S=32 x 16, r=8, P=96. f32 in/out.
// R12:
//  - tcn_mfma: __launch_bounds__(256,4) (LDS already caps at 4 blk/CU so the
//    56-VGPR allocation bought nothing); WTf frag loads hoisted per-tap into
//    registers -> pure LDS->MFMA inner loop.
//  - softmax fused into out_partial (adj rows computed in-block from e1/e2;
//    s-1 row feeds the regularizer). adj buffer + softmax launch eliminated.

#define BATCH 16
#define SEQ 512
#define NVAR 64
#define DM 128
#define SEG 32
#define SCL 16
#define RNK 8
#define PRED 96
#define BN (BATCH * NVAR)   // 1024
#define ROWLEN (SEQ * DM)   // 65536

typedef unsigned short ushort_t;
typedef __attribute__((ext_vector_type(8))) short short8;   // 8 bf16
typedef __attribute__((ext_vector_type(4))) float f32x4;

__device__ inline float bf2f(ushort_t u) {
    union { unsigned int i; float f; } x;
    x.i = ((unsigned int)u) << 16;
    return x.f;
}
__device__ inline ushort_t f2bf(float f) {
    union { float f; unsigned int i; } u;
    u.f = f;
    unsigned int x = u.i;
    return (ushort_t)((x + 0x7fffu + ((x >> 16) & 1u)) >> 16);  // RNE
}
__device__ inline unsigned int pkbf(float a, float b) {  // packed bf16 pair
    __hip_bfloat162 h = __float22bfloat162_rn(make_float2(a, b));
    union { __hip_bfloat162 h2; unsigned int u; } c;
    c.h2 = h;
    return c.u;
}
__device__ inline float blo(unsigned int u) {
    union { unsigned int i; float f; } x;
    x.i = u << 16;
    return x.f;
}
__device__ inline float bhi(unsigned int u) {
    union { unsigned int i; float f; } x;
    x.i = u & 0xFFFF0000u;
    return x.f;
}
// gelu(x) = x * sigmoid(2t); rcp is v_rcp_f32 (1 inst) not the div sequence
__device__ inline float gelu_fast(float x) {
    float t = 0.7978845608028654f * x * (1.0f + 0.044715f * x * x);
    float e = __expf(-2.0f * t);
    return x * __builtin_amdgcn_rcpf(1.0f + e);
}

// ---------------- conv-weight prep: frag-major bf16 (+ regacc zero) ---------
__global__ __launch_bounds__(128) void wt_prep(
    const float* __restrict__ conv_w, ushort_t* __restrict__ WTf,
    float* __restrict__ regacc) {
    if (blockIdx.x == 0 && blockIdx.y == 0 && threadIdx.x == 0) regacc[0] = 0.f;
    int lt = blockIdx.x;    // 0..5 (layer*3+tap)
    int ci = blockIdx.y;    // 0..127
    int co = threadIdx.x;   // 0..127
    int kt = ci >> 5, quad = (ci >> 3) & 3, j = ci & 7;
    int ng = co >> 4, col = co & 15;
    int lane = quad * 16 + col;
    WTf[((((size_t)lt * 4 + kt) * 8 + ng) * 64 + lane) * 8 + j] =
        f2bf(conv_w[(size_t)lt * 16384 + (size_t)ci * 128 + co]);
}

// ---------------- fused TCN (MFMA) + segment means + e1/e2 ------------------
__global__ __launch_bounds__(256, 4) void tcn_mfma(
    const float* __restrict__ x, const float* __restrict__ w_emb,
    const float* __restrict__ b_emb, const ushort_t* __restrict__ WTf,
    const float* __restrict__ conv_b,
    const float* __restrict__ gw1, const float* __restrict__ gb1,
    const float* __restrict__ gw2, const float* __restrict__ gb2,
    ushort_t* __restrict__ h2, float* __restrict__ e1, float* __restrict__ e2) {
    __shared__ __align__(16) ushort_t h0s[82 * 136];  // embed, row = li+18
    __shared__ __align__(16) ushort_t h1b[68 * 136];  // conv1 out, row = li+4
    float* zb = reinterpret_cast<float*>(h1b);        // alias: h1b dead by then

    int bn = blockIdx.x;
    int b = bn >> 6, n = bn & 63;
    int chunk = blockIdx.y;
    int l0 = chunk * 64;

    // ---- embed: 82 rows x 128 d (bf16), packed writes ----
    {
        const float* xb = x + (size_t)b * SEQ * NVAR + n;
#pragma unroll
        for (int i = 0; i < 21; ++i) {
            int q = threadIdx.x + 256 * i;
            if (q < 82 * 64) {
                int row = q >> 6, dp = (q & 63) * 2;
                int l = l0 + row - 18;
                unsigned int pk = 0;
                if (l >= 0) {
                    float xv = xb[(size_t)l * NVAR];
                    float2 wv2 = *reinterpret_cast<const float2*>(&w_emb[dp]);
                    float2 bv2 = *reinterpret_cast<const float2*>(&b_emb[dp]);
                    pk = pkbf(xv * wv2.x + bv2.x, xv * wv2.y + bv2.y);
                }
                *reinterpret_cast<unsigned int*>(&h0s[row * 136 + dp]) = pk;
            }
        }
    }
    __syncthreads();

    int lane = threadIdx.x & 63;
    int wv = threadIdx.x >> 6;
    int quad = lane >> 4;
    int col = lane & 15;
    int cobase = wv * 32;

    // ---- layer 1: D[m=co][n=li]; acc1[mt=li-tile][nt=co-tile] ----
    f32x4 acc1[5][2];
#pragma unroll
    for (int mt = 0; mt < 5; ++mt)
#pragma unroll
        for (int nt = 0; nt < 2; ++nt)
            acc1[mt][nt] = (f32x4){0.f, 0.f, 0.f, 0.f};

#pragma unroll
    for (int tap = 0; tap < 3; ++tap) {
        // hoisted weight fragments for this tap (8 short8 = 32 VGPR)
        short8 wf0[4], wf1[4];
#pragma unroll
        for (int kt = 0; kt < 4; ++kt) {
            const ushort_t* bp =
                WTf + ((((size_t)tap * 4 + kt) * 8 + wv * 2) * 64 + lane) * 8;
            wf0[kt] = *(const short8*)bp;
            wf1[kt] = *(const short8*)(bp + 512);
        }
#pragma unroll
        for (int kt = 0; kt < 4; ++kt) {
            int kc = kt * 32 + quad * 8;
#pragma unroll
            for (int mt = 0; mt < 5; ++mt) {
                short8 hf = *(const short8*)&h0s[(mt * 16 + col + tap) * 136 + kc];
                acc1[mt][0] = __builtin_amdgcn_mfma_f32_16x16x32_bf16(wf0[kt], hf, acc1[mt][0], 0, 0, 0);
                acc1[mt][1] = __builtin_amdgcn_mfma_f32_16x16x32_bf16(wf1[kt], hf, acc1[mt][1], 0, 0, 0);
            }
        }
    }
    // epilogue 1: lane holds li = mt*16+col-16, co = cobase+nt*16+quad*4+r
    {
        float4 bias[2];
        bias[0] = *reinterpret_cast<const float4*>(&conv_b[cobase + quad * 4]);
        bias[1] = *reinterpret_cast<const float4*>(&conv_b[cobase + 16 + quad * 4]);
#pragma unroll
        for (int mt = 0; mt < 5; ++mt) {
            int li = mt * 16 + col - 16;
            if (li >= -4) {
#pragma unroll
                for (int nt = 0; nt < 2; ++nt) {
                    int co = cobase + nt * 16 + quad * 4;
                    uint2 pk;
                    if (l0 + li < 0) {
                        pk.x = 0u; pk.y = 0u;
                    } else {
                        uint2 res = *reinterpret_cast<const uint2*>(
                            &h0s[(mt * 16 + col + 2) * 136 + co]);
                        float h0 = gelu_fast(acc1[mt][nt][0] + bias[nt].x) + blo(res.x);
                        float h1 = gelu_fast(acc1[mt][nt][1] + bias[nt].y) + bhi(res.x);
                        float h2v = gelu_fast(acc1[mt][nt][2] + bias[nt].z) + blo(res.y);
                        float h3 = gelu_fast(acc1[mt][nt][3] + bias[nt].w) + bhi(res.y);
                        pk.x = pkbf(h0, h1);
                        pk.y = pkbf(h2v, h3);
                    }
                    *reinterpret_cast<uint2*>(&h1b[(li + 4) * 136 + co]) = pk;
                }
            }
        }
    }
    __syncthreads();

    // ---- layer 2: li = mt*16+col; tap t reads h1b row li+2t ----
    f32x4 acc2[4][2];
#pragma unroll
    for (int mt = 0; mt < 4; ++mt)
#pragma unroll
        for (int nt = 0; nt < 2; ++nt)
            acc2[mt][nt] = (f32x4){0.f, 0.f, 0.f, 0.f};

#pragma unroll
    for (int tap = 0; tap < 3; ++tap) {
        short8 wf0[4], wf1[4];
#pragma unroll
        for (int kt = 0; kt < 4; ++kt) {
            const ushort_t* bp =
                WTf + ((((size_t)(3 + tap) * 4 + kt) * 8 + wv * 2) * 64 + lane) * 8;
            wf0[kt] = *(const short8*)bp;
            wf1[kt] = *(const short8*)(bp + 512);
        }
#pragma unroll
        for (int kt = 0; kt < 4; ++kt) {
            int kc = kt * 32 + quad * 8;
#pragma unroll
            for (int mt = 0; mt < 4; ++mt) {
                short8 hf = *(const short8*)&h1b[(mt * 16 + col + 2 * tap) * 136 + kc];
                acc2[mt][0] = __builtin_amdgcn_mfma_f32_16x16x32_bf16(wf0[kt], hf, acc2[mt][0], 0, 0, 0);
                acc2[mt][1] = __builtin_amdgcn_mfma_f32_16x16x32_bf16(wf1[kt], hf, acc2[mt][1], 0, 0, 0);
            }
        }
    }
    // epilogue 2: h2 = gelu(y+bias)+h1 -> stage into h0s rows 0..63 (b64)
    {
        float4 bias[2];
        bias[0] = *reinterpret_cast<const float4*>(&conv_b[DM + cobase + quad * 4]);
        bias[1] = *reinterpret_cast<const float4*>(&conv_b[DM + cobase + 16 + quad * 4]);
#pragma unroll
        for (int mt = 0; mt < 4; ++mt) {
            int li = mt * 16 + col;
#pragma unroll
            for (int nt = 0; nt < 2; ++nt) {
                int co = cobase + nt * 16 + quad * 4;
                uint2 res = *reinterpret_cast<const uint2*>(
                    &h1b[(li + 4) * 136 + co]);
                float h0 = gelu_fast(acc2[mt][nt][0] + bias[nt].x) + blo(res.x);
                float h1 = gelu_fast(acc2[mt][nt][1] + bias[nt].y) + bhi(res.x);
                float h2v = gelu_fast(acc2[mt][nt][2] + bias[nt].z) + blo(res.y);
                float h3 = gelu_fast(acc2[mt][nt][3] + bias[nt].w) + bhi(res.y);
                uint2 pk;
                pk.x = pkbf(h0, h1);
                pk.y = pkbf(h2v, h3);
                *reinterpret_cast<uint2*>(&h0s[li * 136 + co]) = pk;
            }
        }
    }
    __syncthreads();

    // ---- coalesced h2 store ----
    {
        ushort_t* orow = h2 + (size_t)bn * ROWLEN + (size_t)l0 * 128;
#pragma unroll
        for (int i = 0; i < 4; ++i) {
            int q = threadIdx.x + 256 * i;
            int row = q >> 4, c8 = (q & 15) * 8;
            *(short8*)&orow[row * 128 + c8] = *(const short8*)&h0s[row * 136 + c8];
        }
    }
    // ---- z: 4 segment means over staged h2 tile (zb aliases h1b) ----
    {
        int d = threadIdx.x & 127, sg = threadIdx.x >> 7;
#pragma unroll
        for (int t = 0; t < 2; ++t) {
            int sl = sg + 2 * t;
            float a = 0.0f;
#pragma unroll
            for (int c = 0; c < SCL; ++c)
                a += bf2f(h0s[(sl * 16 + c) * 136 + d]);
            zb[sl * 128 + d] = a * (1.0f / 16.0f);
        }
    }
    __syncthreads();
    // ---- e1/e2: 4 segs x 2 mats x 8 ranks ----
    if (threadIdx.x < 64) {
        int sl = threadIdx.x >> 4;
        int which = (threadIdx.x >> 3) & 1;
        int r = threadIdx.x & 7;
        const float* w = which ? gw2 : gw1;
        float a = 0.0f;
        for (int d = 0; d < DM; ++d) a += zb[sl * 128 + d] * w[d * RNK + r];
        a += (which ? gb2 : gb1)[r];
        int s = chunk * 4 + sl;
        (which ? e2 : e1)[(((size_t)b * SEG + s) * NVAR + n) * RNK + r] = a;
    }
}

// ---------------- G GEMM (MFMA): split-K x2, register-prefetch pipeline -----
__global__ __launch_bounds__(256) void g_gemm(
    const ushort_t* __restrict__ h2, const float* __restrict__ head_w,
    float* __restrict__ G) {
    __shared__ __align__(16) ushort_t As[64 * 72];  // [bn][k]
    __shared__ __align__(16) ushort_t Bs[96 * 72];  // [p][k]
    int s = blockIdx.x;
    int bnt = blockIdx.y;
    int kh = blockIdx.z;
    int bn0 = bnt * 64;
    int kbase = kh * 1024;
    int lane = threadIdx.x & 63, wv = threadIdx.x >> 6;
    int quad = lane >> 4, col = lane & 15;
    int mh = wv & 1;   // bn half (32)
    int ph = wv >> 1;  // p half (48)

    int arow = threadIdx.x >> 2, akq = (threadIdx.x & 3) * 16;
    const ushort_t* aptr =
        h2 + (size_t)(bn0 + arow) * ROWLEN + (size_t)s * 2048 + kbase + akq;
    const float* bbase = head_w + ((size_t)s * 2048 + kbase) * PRED;
    int bp0[3], bk2[3];
#pragma unroll
    for (int i = 0; i < 3; ++i) {
        int q = threadIdx.x + 256 * i;
        bp0[i] = (q % 24) * 4;
        bk2[i] = (q / 24) * 2;
    }

    f32x4 acc[3][2];  // [p-tile][bn-tile]
#pragma unroll
    for (int i = 0; i < 3; ++i)
#pragma unroll
        for (int j = 0; j < 2; ++j) acc[i][j] = (f32x4){0.f, 0.f, 0.f, 0.f};

    // ---- prefetch chunk 0 ----
    short8 pa0 = *(const short8*)aptr;
    short8 pa1 = *(const short8*)(aptr + 8);
    float4 pb0[3], pb1[3];
#pragma unroll
    for (int i = 0; i < 3; ++i) {
        const float* src = bbase + (size_t)bk2[i] * PRED + bp0[i];
        pb0[i] = *reinterpret_cast<const float4*>(src);
        pb1[i] = *reinterpret_cast<const float4*>(src + PRED);
    }
    *(short8*)&As[arow * 72 + akq] = pa0;
    *(short8*)&As[arow * 72 + akq + 8] = pa1;
#pragma unroll
    for (int i = 0; i < 3; ++i) {
        *reinterpret_cast<unsigned int*>(&Bs[(bp0[i] + 0) * 72 + bk2[i]]) = pkbf(pb0[i].x, pb1[i].x);
        *reinterpret_cast<unsigned int*>(&Bs[(bp0[i] + 1) * 72 + bk2[i]]) = pkbf(pb0[i].y, pb1[i].y);
        *reinterpret_cast<unsigned int*>(&Bs[(bp0[i] + 2) * 72 + bk2[i]]) = pkbf(pb0[i].z, pb1[i].z);
        *reinterpret_cast<unsigned int*>(&Bs[(bp0[i] + 3) * 72 + bk2[i]]) = pkbf(pb0[i].w, pb1[i].w);
    }
    __syncthreads();

    for (int kt = 0; kt < 16; ++kt) {
        if (kt < 15) {
            const ushort_t* ap = aptr + (kt + 1) * 64;
            pa0 = *(const short8*)ap;
            pa1 = *(const short8*)(ap + 8);
#pragma unroll
            for (int i = 0; i < 3; ++i) {
                const float* src =
                    bbase + (size_t)((kt + 1) * 64 + bk2[i]) * PRED + bp0[i];
                pb0[i] = *reinterpret_cast<const float4*>(src);
                pb1[i] = *reinterpret_cast<const float4*>(src + PRED);
            }
        }
#pragma unroll
        for (int kk = 0; kk < 2; ++kk) {
            int kc = kk * 32 + quad * 8;
            short8 pfr[3];
#pragma unroll
            for (int i = 0; i < 3; ++i)
                pfr[i] = *(const short8*)&Bs[(ph * 48 + i * 16 + col) * 72 + kc];
#pragma unroll
            for (int j = 0; j < 2; ++j) {
                short8 bnfr = *(const short8*)&As[(mh * 32 + j * 16 + col) * 72 + kc];
#pragma unroll
                for (int i = 0; i < 3; ++i)
                    acc[i][j] = __builtin_amdgcn_mfma_f32_16x16x32_bf16(pfr[i], bnfr, acc[i][j], 0, 0, 0);
            }
        }
        __syncthreads();
        if (kt < 15) {
            *(short8*)&As[arow * 72 + akq] = pa0;
            *(short8*)&As[arow * 72 + akq + 8] = pa1;
#pragma unroll
            for (int i = 0; i < 3; ++i) {
                *reinterpret_cast<unsigned int*>(&Bs[(bp0[i] + 0) * 72 + bk2[i]]) = pkbf(pb0[i].x, pb1[i].x);
                *reinterpret_cast<unsigned int*>(&Bs[(bp0[i] + 1) * 72 + bk2[i]]) = pkbf(pb0[i].y, pb1[i].y);
                *reinterpret_cast<unsigned int*>(&Bs[(bp0[i] + 2) * 72 + bk2[i]]) = pkbf(pb0[i].z, pb1[i].z);
                *reinterpret_cast<unsigned int*>(&Bs[(bp0[i] + 3) * 72 + bk2[i]]) = pkbf(pb0[i].w, pb1[i].w);
            }
            __syncthreads();
        }
    }
    // atomic accumulate G[s][b][p][m] (two kh blocks per output)
    int b = bnt;
#pragma unroll
    for (int i = 0; i < 3; ++i)
#pragma unroll
        for (int j = 0; j < 2; ++j)
#pragma unroll
            for (int r = 0; r < 4; ++r) {
                int p = ph * 48 + i * 16 + quad * 4 + r;
                int m = mh * 32 + j * 16 + col;
                atomicAdd(&G[(((size_t)s * BATCH + b) * PRED + p) * NVAR + m],
                          acc[i][j][r]);
            }
}

// ---------------- out partials (+ fused softmax + regularizer) --------------
// grid (b=16, sg=16, nh=2). Block computes adj rows for s=2sg-1,2sg,2sg+1
// from e1/e2 (no adj buffer), accumulates reg diffs, then the GEMM part.
__global__ __launch_bounds__(256) void out_partial(
    const float* __restrict__ e1, const float* __restrict__ e2,
    const float* __restrict__ G, float* __restrict__ partial,
    float* __restrict__ regacc) {
    __shared__ float adjn[2][32][65];
    __shared__ float Gs[96][65];
    __shared__ float e2s[3][64][8];
    __shared__ float e1s[3][32][8];
    __shared__ float wsum[4];
    int b = blockIdx.x, sg = blockIdx.y, nh = blockIdx.z;
    int s0 = sg * 2;
    int wv = threadIdx.x >> 6, lane = threadIdx.x & 63;

    // stage e1/e2 slices for s = s0-1, s0, s0+1 (zero-fill s<0)
    for (int idx = threadIdx.x; idx < 3 * 64 * 8; idx += 256) {
        int j = idx >> 9, m = (idx >> 3) & 63, r = idx & 7;
        int s = s0 - 1 + j;
        e2s[j][m][r] = (s >= 0)
            ? e2[(((size_t)b * SEG + s) * NVAR + m) * RNK + r] : 0.0f;
    }
    for (int idx = threadIdx.x; idx < 3 * 32 * 8; idx += 256) {
        int j = idx >> 8, nl = (idx >> 3) & 31, r = idx & 7;
        int s = s0 - 1 + j;
        e1s[j][nl][r] = (s >= 0)
            ? e1[(((size_t)b * SEG + s) * NVAR + nh * 32 + nl) * RNK + r] : 0.0f;
    }
    __syncthreads();

    // compute adj rows (lane = m); wave wv handles rows wv*8..wv*8+7
    float regsum = 0.0f;
    for (int t = 0; t < 8; ++t) {
        int nl = wv * 8 + t;
        float a[3];
#pragma unroll
        for (int j = 0; j < 3; ++j) {
            float sc = 0.0f;
#pragma unroll
            for (int r = 0; r < 8; ++r) sc += e1s[j][nl][r] * e2s[j][lane][r];
            sc *= 0.35355339059327373f;  // 1/sqrt(8)
            float mx = sc;
            for (int off = 32; off; off >>= 1)
                mx = fmaxf(mx, __shfl_xor(mx, off, 64));
            float ex = __expf(sc - mx);
            float sm = ex;
            for (int off = 32; off; off >>= 1) sm += __shfl_xor(sm, off, 64);
            a[j] = ex * __builtin_amdgcn_rcpf(sm);
        }
        if (s0 > 0) regsum += fabsf(a[1] - a[0]);  // diff at s0 (vs s0-1)
        regsum += fabsf(a[2] - a[1]);              // diff at s0+1 (vs s0)
        adjn[0][nl][lane] = a[1];
        adjn[1][nl][lane] = a[2];
    }
    __syncthreads();

    int pg = threadIdx.x >> 4;   // p = pg*6 + j
    int ng = threadIdx.x & 15;   // n = nh*32 + ng*2 + i
    float acc[6][2];
#pragma unroll
    for (int j = 0; j < 6; ++j) { acc[j][0] = 0.f; acc[j][1] = 0.f; }

#pragma unroll
    for (int ss = 0; ss < 2; ++ss) {
        int s = s0 + ss;
#pragma unroll
        for (int i = 0; i < 6; ++i) {
            int q = threadIdx.x + 256 * i;
            int row = q >> 4, mq = (q & 15) * 4;
            float4 v = *reinterpret_cast<const float4*>(
                &G[(((size_t)s * BATCH + b) * PRED + row) * NVAR + mq]);
            Gs[row][mq + 0] = v.x; Gs[row][mq + 1] = v.y;
            Gs[row][mq + 2] = v.z; Gs[row][mq + 3] = v.w;
        }
        __syncthreads();
#pragma unroll 4
        for (int m = 0; m < 64; ++m) {
            float a0 = adjn[ss][ng * 2 + 0][m];
            float a1 = adjn[ss][ng * 2 + 1][m];
#pragma unroll
            for (int j = 0; j < 6; ++j) {
                float g = Gs[pg * 6 + j][m];
                acc[j][0] += g * a0;
                acc[j][1] += g * a1;
            }
        }
        __syncthreads();
    }
#pragma unroll
    for (int j = 0; j < 6; ++j)
#pragma unroll
        for (int i = 0; i < 2; ++i) {
            int p = pg * 6 + j, n = nh * 32 + ng * 2 + i;
            partial[(((size_t)sg * BATCH + b) * PRED + p) * NVAR + n] = acc[j][i];
        }
    // block-reduce regsum -> one atomic
    for (int off = 32; off; off >>= 1) regsum += __shfl_xor(regsum, off, 64);
    if (lane == 0) wsum[wv] = regsum;
    __syncthreads();
    if (threadIdx.x == 0)
        atomicAdd(regacc, wsum[0] + wsum[1] + wsum[2] + wsum[3]);
}

// ---------------- reduce 16 partials + head_b (float4); write reg -----------
__global__ __launch_bounds__(256) void out_reduce(
    const float* __restrict__ partial, const float* __restrict__ head_b,
    const float* __restrict__ regacc, float* __restrict__ out, int out_size) {
    int i4 = blockIdx.x * 256 + threadIdx.x;  // 0..24575 float4s
    int p = (i4 >> 4) % PRED;
    float hb = head_b[p];
    float4 a = make_float4(hb, hb, hb, hb);
    const int stride4 = BATCH * PRED * NVAR / 4;
    const float4* p4 = reinterpret_cast<const float4*>(partial);
#pragma unroll
    for (int sg = 0; sg < 16; ++sg) {
        float4 v = p4[sg * stride4 + i4];
        a.x += v.x; a.y += v.y; a.z += v.z; a.w += v.w;
    }
    reinterpret_cast<float4*>(out)[i4] = a;
    if (i4 == 0) out[out_size - 1] = regacc[0] * (1.0f / 65536.0f);
}

extern "C" void kernel_launch(void* const* d_in, const int* in_sizes, int n_in,
                              void* d_out, int out_size, void* d_ws,
                              size_t ws_size, hipStream_t stream) {
    const float* x_enc  = (const float*)d_in[0];
    const float* w_emb  = (const float*)d_in[4];
    const float* b_emb  = (const float*)d_in[5];
    const float* conv_w = (const float*)d_in[6];
    const float* conv_b = (const float*)d_in[7];
    const float* gg_w1  = (const float*)d_in[8];
    const float* gg_b1  = (const float*)d_in[9];
    const float* gg_w2  = (const float*)d_in[10];
    const float* gg_b2  = (const float*)d_in[11];
    const float* head_w = (const float*)d_in[12];
    const float* head_b = (const float*)d_in[13];
    float* out = (float*)d_out;

    // workspace: 157,286,404 B total (proven). WTf lives in the former adj
    // slot; partial overlaps h2 (dead after g_gemm).
    char* ws = (char*)d_ws;
    ushort_t* h2   = (ushort_t*)(ws);                   // 134,217,728
    float* partial = (float*)(ws);                      //   6,291,456 (overlaps h2)
    float* G       = (float*)(ws + 134217728);          //  12,582,912
    float* e1      = (float*)(ws + 146800640);          //   1,048,576
    float* e2      = (float*)(ws + 147849216);          //   1,048,576
    ushort_t* WTf  = (ushort_t*)(ws + 148897792);       //     196,608
    float* regacc  = (float*)(ws + 157286400);          //           4

    hipMemsetAsync(G, 0, 12582912, stream);  // zero G for split-K atomics
    wt_prep<<<dim3(6, 128), 128, 0, stream>>>(conv_w, WTf, regacc);
    tcn_mfma<<<dim3(BN, SEQ / 64), 256, 0, stream>>>(
        x_enc, w_emb, b_emb, WTf, conv_b,
        gg_w1, gg_b1, gg_w2, gg_b2, h2, e1, e2);
    g_gemm<<<dim3(SEG, BATCH, 2), 256, 0, stream>>>(h2, head_w, G);
    out_partial<<<dim3(BATCH, 16, 2), 256, 0, stream>>>(
        e1, e2, G, partial, regacc);
    out_reduce<<<BATCH * PRED * NVAR / 1024, 256, 0, stream>>>(
        partial, head_b, regacc, out, out_size);
}